// Round 1
// baseline (1894.750 us; speedup 1.0000x reference)
//
#include <hip/hip_runtime.h>
#include <math.h>

#define C_    768
#define H_    12
#define D_    64
#define B_    8
#define T_    512
#define TM1   511
#define R_    8
#define KN_   4
#define KC5   5
#define SCALE_ 0.5f
#define EPS_  1e-12f
#define NEG_  -1000000000.0f
#define INV_  0.125f   /* 1/sqrt(64) */

// ---------------------------------------------------------------------------
// Generic fp32 GEMM: C = A(MxK) @ W(KxN) + bias(N), row-major everywhere.
// 64x64 tile, BK=16, 256 threads, 4x4 outputs/thread.
// ---------------------------------------------------------------------------
#define BM 64
#define BN 64
#define BK 16

__global__ __launch_bounds__(256) void gemm_bias(
    const float* __restrict__ A, const float* __restrict__ W,
    const float* __restrict__ bias, float* __restrict__ Cmat,
    int M, int K, int N)
{
  __shared__ float As[BK][BM + 4];   // transposed tile: As[k][m], stride 68 (16B aligned)
  __shared__ float Bs[BK][BN];
  const int tid  = threadIdx.x;
  const int row0 = blockIdx.y * BM;
  const int col0 = blockIdx.x * BN;
  const int m0 = (tid >> 4) << 2;
  const int n0 = (tid & 15) << 2;
  const int la_r = tid >> 2;
  const int la_k = (tid & 3) << 2;
  const int lb_k = tid >> 4;
  const int lb_n = (tid & 15) << 2;

  float acc[4][4] = {};

  for (int k0 = 0; k0 < K; k0 += BK) {
    // ---- load A tile (transposed into LDS) ----
    float a0 = 0.f, a1 = 0.f, a2 = 0.f, a3 = 0.f;
    {
      int ar = row0 + la_r;
      int ak = k0 + la_k;
      if (ar < M) {
        const float* ap = A + (size_t)ar * K + ak;
        if (ak + 3 < K) {
          float4 t = *(const float4*)ap;
          a0 = t.x; a1 = t.y; a2 = t.z; a3 = t.w;
        } else {
          if (ak + 0 < K) a0 = ap[0];
          if (ak + 1 < K) a1 = ap[1];
          if (ak + 2 < K) a2 = ap[2];
          if (ak + 3 < K) a3 = ap[3];
        }
      }
    }
    As[la_k + 0][la_r] = a0;
    As[la_k + 1][la_r] = a1;
    As[la_k + 2][la_r] = a2;
    As[la_k + 3][la_r] = a3;
    // ---- load B tile ----
    {
      float4 bv = {0.f, 0.f, 0.f, 0.f};
      int bk = k0 + lb_k;
      int bn = col0 + lb_n;
      if (bk < K) {
        const float* bp = W + (size_t)bk * N + bn;
        if (bn + 3 < N) bv = *(const float4*)bp;
        else {
          if (bn + 0 < N) bv.x = bp[0];
          if (bn + 1 < N) bv.y = bp[1];
          if (bn + 2 < N) bv.z = bp[2];
          if (bn + 3 < N) bv.w = bp[3];
        }
      }
      *(float4*)&Bs[lb_k][lb_n] = bv;
    }
    __syncthreads();
    #pragma unroll
    for (int kk = 0; kk < BK; ++kk) {
      float4 av = *(const float4*)&As[kk][m0];
      float4 bv = *(const float4*)&Bs[kk][n0];
      float am[4] = {av.x, av.y, av.z, av.w};
      float bn4[4] = {bv.x, bv.y, bv.z, bv.w};
      #pragma unroll
      for (int i = 0; i < 4; ++i)
        #pragma unroll
        for (int j = 0; j < 4; ++j)
          acc[i][j] += am[i] * bn4[j];
    }
    __syncthreads();
  }

  if (col0 + n0 < N) {   // N is always a multiple of 4
    float4 b4 = *(const float4*)&bias[col0 + n0];
    #pragma unroll
    for (int i = 0; i < 4; ++i) {
      int r = row0 + m0 + i;
      if (r < M) {
        float4 o;
        o.x = acc[i][0] + b4.x;
        o.y = acc[i][1] + b4.y;
        o.z = acc[i][2] + b4.z;
        o.w = acc[i][3] + b4.w;
        *(float4*)&Cmat[(size_t)r * N + col0 + n0] = o;
      }
    }
  }
}

// ---------------------------------------------------------------------------
// Flash-style self attention.  Q rows 1..511 vs K/V rows 0..511 per (b,h).
// Block: 256 threads = 32 q-rows x 8 d-slice threads.  Grid: (16, H, B).
// ---------------------------------------------------------------------------
__global__ __launch_bounds__(256) void self_attn(
    const float* __restrict__ Q, const float* __restrict__ Km,
    const float* __restrict__ Vm, const int* __restrict__ mask,
    float* __restrict__ yout /* (B,511,768) head-concat */)
{
  __shared__ float Ks[64][68];
  __shared__ float Vs[64][68];
  __shared__ int   msk[64];

  const int b = blockIdx.z, h = blockIdx.y;
  const int qt0 = blockIdx.x * 32;
  const int tid = threadIdx.x;
  const int r = tid >> 3;
  const int s = tid & 7;
  const int ds = s << 3;
  const int qi = qt0 + r;           // 0..510 valid
  const bool vq = (qi < TM1);
  const int qtok = qi + 1;

  float q[8];
  if (vq) {
    const float* qp = Q + ((size_t)(b * T_) + qtok) * C_ + h * D_ + ds;
    float4 t0 = *(const float4*)qp;
    float4 t1 = *(const float4*)(qp + 4);
    q[0] = t0.x; q[1] = t0.y; q[2] = t0.z; q[3] = t0.w;
    q[4] = t1.x; q[5] = t1.y; q[6] = t1.z; q[7] = t1.w;
  } else {
    #pragma unroll
    for (int j = 0; j < 8; ++j) q[j] = 0.f;
  }

  float acc[8] = {};
  float m = -INFINITY, l = 0.f;

  for (int kt = 0; kt < T_; kt += 64) {
    #pragma unroll
    for (int it = 0; it < 4; ++it) {
      int idx = tid + it * 256;
      int rr = idx >> 4;
      int cc = (idx & 15) << 2;
      size_t gro = ((size_t)(b * T_) + kt + rr) * C_ + h * D_ + cc;
      *(float4*)&Ks[rr][cc] = *(const float4*)(Km + gro);
      *(float4*)&Vs[rr][cc] = *(const float4*)(Vm + gro);
    }
    if (tid < 64) msk[tid] = mask[b * T_ + kt + tid];
    __syncthreads();

    float p[64];
    #pragma unroll
    for (int j = 0; j < 64; ++j) {
      float4 k0 = *(const float4*)&Ks[j][ds];
      float4 k1 = *(const float4*)&Ks[j][ds + 4];
      float part = q[0]*k0.x + q[1]*k0.y + q[2]*k0.z + q[3]*k0.w
                 + q[4]*k1.x + q[5]*k1.y + q[6]*k1.z + q[7]*k1.w;
      part += __shfl_xor(part, 1);
      part += __shfl_xor(part, 2);
      part += __shfl_xor(part, 4);
      float sc = part * INV_;
      p[j] = msk[j] ? sc : NEG_;
    }
    float mt = p[0];
    #pragma unroll
    for (int j = 1; j < 64; ++j) mt = fmaxf(mt, p[j]);
    float mnew = fmaxf(m, mt);
    float fac = __expf(m - mnew);
    l *= fac;
    #pragma unroll
    for (int jj = 0; jj < 8; ++jj) acc[jj] *= fac;
    float ps = 0.f;
    #pragma unroll
    for (int j = 0; j < 64; ++j) {
      float e = __expf(p[j] - mnew);
      p[j] = e;
      ps += e;
    }
    l += ps;
    #pragma unroll
    for (int j = 0; j < 64; ++j) {
      float4 v0 = *(const float4*)&Vs[j][ds];
      float4 v1 = *(const float4*)&Vs[j][ds + 4];
      acc[0] += p[j]*v0.x; acc[1] += p[j]*v0.y; acc[2] += p[j]*v0.z; acc[3] += p[j]*v0.w;
      acc[4] += p[j]*v1.x; acc[5] += p[j]*v1.y; acc[6] += p[j]*v1.z; acc[7] += p[j]*v1.w;
    }
    m = mnew;
    __syncthreads();
  }

  if (vq) {
    float rl = 1.f / l;
    float* op = yout + ((size_t)(b * TM1) + qi) * C_ + h * D_ + ds;
    float4 o0 = {acc[0]*rl, acc[1]*rl, acc[2]*rl, acc[3]*rl};
    float4 o1 = {acc[4]*rl, acc[5]*rl, acc[6]*rl, acc[7]*rl};
    *(float4*)op = o0;
    *(float4*)(op + 4) = o1;
  }
}

// ---------------------------------------------------------------------------
// cls attention: q = Q[b,0,h,:], keys = kc (low-rank proj), values = Vm.
// One 64-thread block per (b,h).
// ---------------------------------------------------------------------------
__global__ __launch_bounds__(64) void cls_attn(
    const float* __restrict__ Q, const float* __restrict__ kc,
    const float* __restrict__ Vm, const int* __restrict__ mask,
    float* __restrict__ yout /* (B,768) */)
{
  __shared__ float qs[64];
  __shared__ float Ks[64][65];
  __shared__ float Vs[64][65];
  __shared__ float Ps[64];

  const int b = blockIdx.x / H_, h = blockIdx.x % H_;
  const int lane = threadIdx.x;

  qs[lane] = Q[(size_t)(b * T_) * C_ + h * D_ + lane];
  __syncthreads();

  float m = -INFINITY, l = 0.f, acc = 0.f;
  for (int kt = 0; kt < T_; kt += 64) {
    for (int rr = 0; rr < 64; ++rr) {
      size_t gro = ((size_t)(b * T_) + kt + rr) * C_ + h * D_ + lane;
      Ks[rr][lane] = kc[gro];
      Vs[rr][lane] = Vm[gro];
    }
    __syncthreads();
    float sc = 0.f;
    #pragma unroll
    for (int d = 0; d < 64; ++d) sc += qs[d] * Ks[lane][d];
    sc *= INV_;
    if (!mask[b * T_ + kt + lane]) sc = NEG_;
    float mt = sc;
    #pragma unroll
    for (int off = 32; off > 0; off >>= 1) mt = fmaxf(mt, __shfl_xor(mt, off));
    float mnew = fmaxf(m, mt);
    float e = __expf(sc - mnew);
    float ssum = e;
    #pragma unroll
    for (int off = 32; off > 0; off >>= 1) ssum += __shfl_xor(ssum, off);
    float fac = __expf(m - mnew);
    acc *= fac;
    l = l * fac + ssum;
    Ps[lane] = e;
    __syncthreads();
    #pragma unroll
    for (int j = 0; j < 64; ++j) acc += Ps[j] * Vs[j][lane];
    m = mnew;
    __syncthreads();
  }
  yout[(size_t)b * C_ + h * D_ + lane] = acc / l;
}

// ---------------------------------------------------------------------------
// Neighbour attention (5 candidates per token).  i=0 rows come from the
// already-computed Q/kc/Vm; i>=1 rows from the neighbour_rep projections.
// One 256-thread block per (b,t).
// ---------------------------------------------------------------------------
__global__ __launch_bounds__(256) void neigh_attn(
    const float* __restrict__ Q, const float* __restrict__ kcmat,
    const float* __restrict__ Vm,
    const float* __restrict__ qn_r, const float* __restrict__ kn_r,
    const float* __restrict__ vn_r,
    int b0, float* __restrict__ outn /* (nb*511*5, 768) */)
{
  __shared__ float qs[KC5 * C_];
  __shared__ float ks[KC5 * C_];
  __shared__ float vs[KC5 * C_];
  __shared__ float Ps[H_ * 25];

  const int bt = blockIdx.x;
  const int bb = bt / TM1, t = bt % TM1;
  const int b = b0 + bb;
  const int tid = threadIdx.x;
  const size_t tok = (size_t)(b * T_) + t + 1;
  const size_t nrow = ((size_t)(bb * TM1) + t) * KN_;

  for (int idx = tid; idx < KC5 * C_ / 4; idx += 256) {
    int i = idx / (C_ / 4);
    int d4 = (idx % (C_ / 4)) * 4;
    const float *qp, *kp, *vp;
    if (i == 0) {
      qp = Q + tok * C_ + d4;
      kp = kcmat + tok * C_ + d4;
      vp = Vm + tok * C_ + d4;
    } else {
      size_t rr = (nrow + i - 1) * C_ + d4;
      qp = qn_r + rr; kp = kn_r + rr; vp = vn_r + rr;
    }
    *(float4*)&qs[i * C_ + d4] = *(const float4*)qp;
    *(float4*)&ks[i * C_ + d4] = *(const float4*)kp;
    *(float4*)&vs[i * C_ + d4] = *(const float4*)vp;
  }
  __syncthreads();

  if (tid < H_ * KC5) {
    int h = tid / KC5, i = tid % KC5;
    float sc[KC5];
    #pragma unroll
    for (int j = 0; j < KC5; ++j) {
      float sum = 0.f;
      #pragma unroll
      for (int d = 0; d < D_; ++d)
        sum += qs[i * C_ + h * D_ + d] * ks[j * C_ + h * D_ + d];
      sc[j] = sum * INV_;
    }
    float mt = sc[0];
    #pragma unroll
    for (int j = 1; j < KC5; ++j) mt = fmaxf(mt, sc[j]);
    float e[KC5], ssum = 0.f;
    #pragma unroll
    for (int j = 0; j < KC5; ++j) { e[j] = __expf(sc[j] - mt); ssum += e[j]; }
    float rs = 1.f / ssum;
    #pragma unroll
    for (int j = 0; j < KC5; ++j) Ps[h * 25 + i * KC5 + j] = e[j] * rs;
  }
  __syncthreads();

  for (int idx = tid; idx < KC5 * C_; idx += 256) {
    int i = idx / C_, c = idx % C_;
    int h = c / D_;
    float sum = 0.f;
    #pragma unroll
    for (int j = 0; j < KC5; ++j)
      sum += Ps[h * 25 + i * KC5 + j] * vs[j * C_ + c];
    outn[(((size_t)(bb * TM1) + t) * KC5 + i) * C_ + c] = sum;
  }
}

// ---------------------------------------------------------------------------
// Residual + LayerNorm combine kernels (one 256-thread block per row of 768).
// ---------------------------------------------------------------------------
__device__ __forceinline__ void block_reduce2(float& s, float& ss, float* red) {
  #pragma unroll
  for (int off = 32; off > 0; off >>= 1) {
    s += __shfl_down(s, off);
    ss += __shfl_down(ss, off);
  }
  int wid = threadIdx.x >> 6;
  if ((threadIdx.x & 63) == 0) { red[wid * 2] = s; red[wid * 2 + 1] = ss; }
  __syncthreads();
  s  = red[0] + red[2] + red[4] + red[6];
  ss = red[1] + red[3] + red[5] + red[7];
}

__device__ __forceinline__ void ln_row(const float vals[3], float s, float ss,
                                       const float* __restrict__ g,
                                       const float* __restrict__ bb,
                                       float* __restrict__ orow, float* red) {
  block_reduce2(s, ss, red);
  float mean = s * (1.f / (float)C_);
  float var = ss * (1.f / (float)C_) - mean * mean;
  var = fmaxf(var, 0.f);
  float rs = rsqrtf(var + EPS_);
  #pragma unroll
  for (int ii = 0; ii < 3; ++ii) {
    int c = threadIdx.x + ii * 256;
    orow[c] = (vals[ii] - mean) * rs * g[c] + bb[c];
  }
}

__global__ __launch_bounds__(256) void combine_main(
    const float* __restrict__ yselfP, const float* __restrict__ poutn,
    const float* __restrict__ x, const float* __restrict__ g,
    const float* __restrict__ bln, int b0, float* __restrict__ dout)
{
  __shared__ float red[8];
  const int bt = blockIdx.x;
  const int bbb = bt / TM1, t = bt % TM1;
  const int b = b0 + bbb;
  const float* ys = yselfP + ((size_t)(b * TM1) + t) * C_;
  const float* pn = poutn + (((size_t)(bbb * TM1) + t) * KC5 + 0) * C_;
  const float* xr = x + ((size_t)(b * T_) + t + 1) * C_;
  float* orow = dout + ((size_t)(b * T_) + t + 1) * C_;
  float vals[3], s = 0.f, ss = 0.f;
  #pragma unroll
  for (int ii = 0; ii < 3; ++ii) {
    int c = threadIdx.x + ii * 256;
    float v = SCALE_ * pn[c] + (1.f - SCALE_) * ys[c] + xr[c];
    vals[ii] = v; s += v; ss += v * v;
  }
  ln_row(vals, s, ss, g, bln, orow, red);
}

__global__ __launch_bounds__(256) void combine_neigh(
    const float* __restrict__ poutn, const float* __restrict__ nrc,
    const float* __restrict__ g, const float* __restrict__ bln,
    int b0, float* __restrict__ dout /* at OUT1 offset already added by host */)
{
  __shared__ float red[8];
  const int idx = blockIdx.x;
  const int i1 = idx % KN_;
  const int bt = idx / KN_;           // local bbb*TM1 + t
  const int bbb = bt / TM1, t = bt % TM1;
  const int b = b0 + bbb;
  const float* pn = poutn + ((size_t)bt * KC5 + 1 + i1) * C_;
  const float* nr = nrc + ((size_t)bt * KN_ + i1) * C_;
  float* orow = dout + (((size_t)(b * TM1) + t) * KN_ + i1) * C_;
  float vals[3], s = 0.f, ss = 0.f;
  #pragma unroll
  for (int ii = 0; ii < 3; ++ii) {
    int c = threadIdx.x + ii * 256;
    float v = pn[c] + nr[c];
    vals[ii] = v; s += v; ss += v * v;
  }
  ln_row(vals, s, ss, g, bln, orow, red);
}

__global__ __launch_bounds__(256) void combine_cls(
    const float* __restrict__ yclsP, const float* __restrict__ x,
    const float* __restrict__ g, const float* __restrict__ bln,
    float* __restrict__ dout)
{
  __shared__ float red[8];
  const int b = blockIdx.x;
  const float* yc = yclsP + (size_t)b * C_;
  const float* xr = x + (size_t)(b * T_) * C_;
  float* orow = dout + (size_t)(b * T_) * C_;
  float vals[3], s = 0.f, ss = 0.f;
  #pragma unroll
  for (int ii = 0; ii < 3; ++ii) {
    int c = threadIdx.x + ii * 256;
    float v = yc[c] + xr[c];
    vals[ii] = v; s += v; ss += v * v;
  }
  ln_row(vals, s, ss, g, bln, orow, red);
}

// ---------------------------------------------------------------------------
extern "C" void kernel_launch(void* const* d_in, const int* in_sizes, int n_in,
                              void* d_out, int out_size, void* d_ws, size_t ws_size,
                              hipStream_t stream) {
  (void)in_sizes; (void)n_in; (void)out_size;
  const float* x    = (const float*)d_in[0];
  const int*   mask = (const int*)d_in[1];
  const float* nrep = (const float*)d_in[2];
  const float* Wq = (const float*)d_in[3];  const float* bq = (const float*)d_in[4];
  const float* Wk = (const float*)d_in[5];  const float* bk = (const float*)d_in[6];
  const float* Wv = (const float*)d_in[7];  const float* bv = (const float*)d_in[8];
  const float* Wp = (const float*)d_in[9];  const float* bp = (const float*)d_in[10];
  const float* Wd = (const float*)d_in[11]; const float* bd = (const float*)d_in[12];
  const float* Wu = (const float*)d_in[13]; const float* bu = (const float*)d_in[14];
  const float* lng = (const float*)d_in[15];
  const float* lnb = (const float*)d_in[16];
  float* dout = (float*)d_out;
  const size_t OUT1 = (size_t)B_ * T_ * C_;   // start of neighbour_out

  float* ws = (float*)d_ws;
  size_t off = 0;
  auto alloc = [&](size_t n) { float* p = ws + off; off += n; return p; };
  const size_t NT = (size_t)B_ * T_;      // 4096
  float* Q   = alloc(NT * C_);
  float* Km  = alloc(NT * C_);
  float* Vm  = alloc(NT * C_);
  float* t1  = alloc(NT * R_);
  float* kc  = alloc(NT * C_);
  float* ysh = alloc((size_t)B_ * TM1 * C_);
  float* ysp = alloc((size_t)B_ * TM1 * C_);
  float* ych = alloc((size_t)B_ * C_);
  float* ycp = alloc((size_t)B_ * C_);
  const size_t fixed = off;
  const size_t perb = (size_t)TM1 * KN_ * C_ * 3 + (size_t)TM1 * KN_ * R_
                    + (size_t)TM1 * KC5 * C_ * 2;
  const size_t wsf = ws_size / sizeof(float);
  int nb = 1;
  for (int cand : {8, 4, 2, 1}) {
    if (fixed + perb * (size_t)cand <= wsf) { nb = cand; break; }
  }
  float* qn   = alloc((size_t)nb * TM1 * KN_ * C_);
  float* vn   = alloc((size_t)nb * TM1 * KN_ * C_);
  float* t2   = alloc((size_t)nb * TM1 * KN_ * R_);
  float* kn   = alloc((size_t)nb * TM1 * KN_ * C_);
  float* outn = alloc((size_t)nb * TM1 * KC5 * C_);
  float* poutn= alloc((size_t)nb * TM1 * KC5 * C_);

  dim3 blk(256);
  auto g2 = [](int M, int N) { return dim3((N + BN - 1) / BN, (M + BM - 1) / BM); };

  // QKV / low-rank projections over all B*T tokens
  gemm_bias<<<g2((int)NT, C_), blk, 0, stream>>>(x, Wq, bq, Q, (int)NT, C_, C_);
  gemm_bias<<<g2((int)NT, C_), blk, 0, stream>>>(x, Wk, bk, Km, (int)NT, C_, C_);
  gemm_bias<<<g2((int)NT, C_), blk, 0, stream>>>(x, Wv, bv, Vm, (int)NT, C_, C_);
  gemm_bias<<<g2((int)NT, R_), blk, 0, stream>>>(x, Wd, bd, t1, (int)NT, C_, R_);
  gemm_bias<<<g2((int)NT, C_), blk, 0, stream>>>(t1, Wu, bu, kc, (int)NT, R_, C_);

  // self attention + projection
  self_attn<<<dim3(16, H_, B_), blk, 0, stream>>>(Q, Km, Vm, mask, ysh);
  gemm_bias<<<g2(B_ * TM1, C_), blk, 0, stream>>>(ysh, Wp, bp, ysp, B_ * TM1, C_, C_);

  // cls attention + projection + combine
  cls_attn<<<B_ * H_, 64, 0, stream>>>(Q, kc, Vm, mask, ych);
  gemm_bias<<<g2(B_, C_), blk, 0, stream>>>(ych, Wp, bp, ycp, B_, C_, C_);
  combine_cls<<<B_, blk, 0, stream>>>(ycp, x, lng, lnb, dout);

  // neighbour pipeline, chunked over b
  for (int b0 = 0; b0 < B_; b0 += nb) {
    const int Mn = nb * TM1 * KN_;
    const int Mo = nb * TM1 * KC5;
    const float* nrc = nrep + (size_t)b0 * TM1 * KN_ * C_;
    gemm_bias<<<g2(Mn, C_), blk, 0, stream>>>(nrc, Wq, bq, qn, Mn, C_, C_);
    gemm_bias<<<g2(Mn, C_), blk, 0, stream>>>(nrc, Wv, bv, vn, Mn, C_, C_);
    gemm_bias<<<g2(Mn, R_), blk, 0, stream>>>(nrc, Wd, bd, t2, Mn, C_, R_);
    gemm_bias<<<g2(Mn, C_), blk, 0, stream>>>(t2, Wu, bu, kn, Mn, R_, C_);
    neigh_attn<<<nb * TM1, blk, 0, stream>>>(Q, kc, Vm, qn, kn, vn, b0, outn);
    gemm_bias<<<g2(Mo, C_), blk, 0, stream>>>(outn, Wp, bp, poutn, Mo, C_, C_);
    combine_main<<<nb * TM1, blk, 0, stream>>>(ysp, poutn, x, lng, lnb, b0, dout);
    combine_neigh<<<nb * TM1 * KN_, blk, 0, stream>>>(poutn, nrc, lng, lnb, b0,
                                                      dout + OUT1);
  }
}

// Round 2
// 1030.156 us; speedup vs baseline: 1.8393x; 1.8393x over previous
//
#include <hip/hip_runtime.h>
#include <math.h>

#define C_    768
#define H_    12
#define D_    64
#define B_    8
#define T_    512
#define TM1   511
#define R_    8
#define KN_   4
#define KC5   5
#define SCALE_ 0.5f
#define EPS_  1e-12f
#define NEG_  -1000000000.0f
#define INV_  0.125f   /* 1/sqrt(64) */

typedef __bf16 bf16_t;
typedef __bf16 bf16x4_t __attribute__((ext_vector_type(4)));
typedef __bf16 bf16x8_t __attribute__((ext_vector_type(8)));
typedef float  f32x4_t  __attribute__((ext_vector_type(4)));
typedef const void __attribute__((address_space(1)))* gas_t;
typedef void       __attribute__((address_space(3)))* las_t;

__device__ __forceinline__ void gl_lds16(const bf16_t* g, bf16_t* l) {
  __builtin_amdgcn_global_load_lds((gas_t)g, (las_t)l, 16, 0, 0);
}

// ---------------------------------------------------------------------------
// fp32 -> bf16 flat convert (n % 4 == 0)
// ---------------------------------------------------------------------------
__global__ __launch_bounds__(256) void cvt_bf16(const float* __restrict__ in,
                                                bf16_t* __restrict__ out, long n) {
  long i = ((long)blockIdx.x * 256 + threadIdx.x) * 4;
  const long stride = (long)gridDim.x * 256 * 4;
  for (; i < n; i += stride) {
    float4 v = *(const float4*)(in + i);
    bf16x4_t o = { (bf16_t)v.x, (bf16_t)v.y, (bf16_t)v.z, (bf16_t)v.w };
    *(bf16x4_t*)(out + i) = o;
  }
}

// ---------------------------------------------------------------------------
// Weight transpose + convert: Wt[n][k] = (bf16) W[k][n], 768x768.
// ---------------------------------------------------------------------------
__global__ __launch_bounds__(256) void wtrans(const float* __restrict__ W,
                                              bf16_t* __restrict__ Wt) {
  __shared__ float tile[32][33];
  const int n0 = blockIdx.x * 32, k0 = blockIdx.y * 32;
  const int tx = threadIdx.x & 31, ty = threadIdx.x >> 5;
  #pragma unroll
  for (int r = ty; r < 32; r += 8)
    tile[r][tx] = W[(size_t)(k0 + r) * C_ + n0 + tx];
  __syncthreads();
  #pragma unroll
  for (int r = ty; r < 32; r += 8)
    Wt[(size_t)(n0 + r) * C_ + k0 + tx] = (bf16_t)tile[tx][r];
}

// ---------------------------------------------------------------------------
// bf16 MFMA GEMM (m97 structure): C(MxN,f32) = A(MxK,bf16) @ Bt(NxK,bf16)^T + bias
// 128x128 tile, BK=32, 256 threads (4 waves, 2x2), 16x16x32 MFMA, 4x4 frags/wave.
// Staging via global_load_lds width=16, linear LDS [row][32k].
// ---------------------------------------------------------------------------
__global__ __launch_bounds__(256) void gemm_mfma(
    const bf16_t* __restrict__ A, const bf16_t* __restrict__ Bt,
    const float* __restrict__ bias, float* __restrict__ Cmat,
    int M, int K, int N)
{
  __shared__ bf16_t As[128 * 32];
  __shared__ bf16_t Bs[128 * 32];
  const int tid = threadIdx.x;
  const int lane = tid & 63;
  const int wv = tid >> 6;
  const int row0 = blockIdx.y * 128;
  const int col0 = blockIdx.x * 128;
  const int wr = (wv >> 1) * 64;
  const int wc = (wv & 1) * 64;
  const int sr = tid >> 2;            // staging row 0..63
  const int sk = (tid & 3) * 8;       // staging k-element offset

  int ra0 = row0 + sr;       if (ra0 > M - 1) ra0 = M - 1;
  int ra1 = row0 + 64 + sr;  if (ra1 > M - 1) ra1 = M - 1;
  const bf16_t* ga0 = A + (size_t)ra0 * K + sk;
  const bf16_t* ga1 = A + (size_t)ra1 * K + sk;
  const bf16_t* gb0 = Bt + (size_t)(col0 + sr) * K + sk;
  const bf16_t* gb1 = Bt + (size_t)(col0 + 64 + sr) * K + sk;
  bf16_t* lA = As + wv * 512;         // wave-uniform base (wv*1024 bytes)
  bf16_t* lB = Bs + wv * 512;

  f32x4_t acc[4][4];
  #pragma unroll
  for (int i = 0; i < 4; ++i)
    #pragma unroll
    for (int j = 0; j < 4; ++j) acc[i][j] = (f32x4_t){0.f, 0.f, 0.f, 0.f};

  const int fm = lane & 15;
  const int kb = (lane >> 4) * 8;     // k-element offset of this lane's k-group

  for (int k0 = 0; k0 < K; k0 += 32) {
    gl_lds16(ga0 + k0, lA);
    gl_lds16(ga1 + k0, lA + 2048);
    gl_lds16(gb0 + k0, lB);
    gl_lds16(gb1 + k0, lB + 2048);
    __syncthreads();
    bf16x8_t af[4], bfr[4];
    #pragma unroll
    for (int mi = 0; mi < 4; ++mi)
      af[mi] = *(const bf16x8_t*)(As + (wr + mi * 16 + fm) * 32 + kb);
    #pragma unroll
    for (int ni = 0; ni < 4; ++ni)
      bfr[ni] = *(const bf16x8_t*)(Bs + (wc + ni * 16 + fm) * 32 + kb);
    #pragma unroll
    for (int mi = 0; mi < 4; ++mi)
      #pragma unroll
      for (int ni = 0; ni < 4; ++ni)
        acc[mi][ni] = __builtin_amdgcn_mfma_f32_16x16x32_bf16(af[mi], bfr[ni],
                                                              acc[mi][ni], 0, 0, 0);
    __syncthreads();
  }

  const int r4 = (lane >> 4) * 4;
  #pragma unroll
  for (int ni = 0; ni < 4; ++ni) {
    const int col = col0 + wc + ni * 16 + fm;
    const float bv = bias[col];
    #pragma unroll
    for (int mi = 0; mi < 4; ++mi) {
      const int rb = row0 + wr + mi * 16 + r4;
      #pragma unroll
      for (int r = 0; r < 4; ++r) {
        if (rb + r < M)
          Cmat[(size_t)(rb + r) * N + col] = acc[mi][ni][r] + bv;
      }
    }
  }
}

// ---------------------------------------------------------------------------
// Generic fp32 GEMM (kept for K=8 / N=8 / tiny paths)
// ---------------------------------------------------------------------------
#define BM 64
#define BN 64
#define BK 16

__global__ __launch_bounds__(256) void gemm_bias(
    const float* __restrict__ A, const float* __restrict__ W,
    const float* __restrict__ bias, float* __restrict__ Cmat,
    int M, int K, int N)
{
  __shared__ float As[BK][BM + 4];
  __shared__ float Bs[BK][BN];
  const int tid  = threadIdx.x;
  const int row0 = blockIdx.y * BM;
  const int col0 = blockIdx.x * BN;
  const int m0 = (tid >> 4) << 2;
  const int n0 = (tid & 15) << 2;
  const int la_r = tid >> 2;
  const int la_k = (tid & 3) << 2;
  const int lb_k = tid >> 4;
  const int lb_n = (tid & 15) << 2;

  float acc[4][4] = {};

  for (int k0 = 0; k0 < K; k0 += BK) {
    float a0 = 0.f, a1 = 0.f, a2 = 0.f, a3 = 0.f;
    {
      int ar = row0 + la_r;
      int ak = k0 + la_k;
      if (ar < M) {
        const float* ap = A + (size_t)ar * K + ak;
        if (ak + 3 < K) {
          float4 t = *(const float4*)ap;
          a0 = t.x; a1 = t.y; a2 = t.z; a3 = t.w;
        } else {
          if (ak + 0 < K) a0 = ap[0];
          if (ak + 1 < K) a1 = ap[1];
          if (ak + 2 < K) a2 = ap[2];
          if (ak + 3 < K) a3 = ap[3];
        }
      }
    }
    As[la_k + 0][la_r] = a0;
    As[la_k + 1][la_r] = a1;
    As[la_k + 2][la_r] = a2;
    As[la_k + 3][la_r] = a3;
    {
      float4 bv = {0.f, 0.f, 0.f, 0.f};
      int bk = k0 + lb_k;
      int bn = col0 + lb_n;
      if (bk < K) {
        const float* bp = W + (size_t)bk * N + bn;
        if (bn + 3 < N) bv = *(const float4*)bp;
        else {
          if (bn + 0 < N) bv.x = bp[0];
          if (bn + 1 < N) bv.y = bp[1];
          if (bn + 2 < N) bv.z = bp[2];
          if (bn + 3 < N) bv.w = bp[3];
        }
      }
      *(float4*)&Bs[lb_k][lb_n] = bv;
    }
    __syncthreads();
    #pragma unroll
    for (int kk = 0; kk < BK; ++kk) {
      float4 av = *(const float4*)&As[kk][m0];
      float4 bv = *(const float4*)&Bs[kk][n0];
      float am[4] = {av.x, av.y, av.z, av.w};
      float bn4[4] = {bv.x, bv.y, bv.z, bv.w};
      #pragma unroll
      for (int i = 0; i < 4; ++i)
        #pragma unroll
        for (int j = 0; j < 4; ++j)
          acc[i][j] += am[i] * bn4[j];
    }
    __syncthreads();
  }

  if (col0 + n0 < N) {
    float4 b4 = *(const float4*)&bias[col0 + n0];
    #pragma unroll
    for (int i = 0; i < 4; ++i) {
      int r = row0 + m0 + i;
      if (r < M) {
        float4 o;
        o.x = acc[i][0] + b4.x;
        o.y = acc[i][1] + b4.y;
        o.z = acc[i][2] + b4.z;
        o.w = acc[i][3] + b4.w;
        *(float4*)&Cmat[(size_t)r * N + col0 + n0] = o;
      }
    }
  }
}

// ---------------------------------------------------------------------------
// Flash-style self attention (fp32 compute, bf16 output for the Wp GEMM).
// ---------------------------------------------------------------------------
__global__ __launch_bounds__(256) void self_attn(
    const float* __restrict__ Q, const float* __restrict__ Km,
    const float* __restrict__ Vm, const int* __restrict__ mask,
    bf16_t* __restrict__ yout /* (B,511,768) bf16 */)
{
  __shared__ float Ks[64][68];
  __shared__ float Vs[64][68];
  __shared__ int   msk[64];

  const int b = blockIdx.z, h = blockIdx.y;
  const int qt0 = blockIdx.x * 32;
  const int tid = threadIdx.x;
  const int r = tid >> 3;
  const int s = tid & 7;
  const int ds = s << 3;
  const int qi = qt0 + r;
  const bool vq = (qi < TM1);
  const int qtok = qi + 1;

  float q[8];
  if (vq) {
    const float* qp = Q + ((size_t)(b * T_) + qtok) * C_ + h * D_ + ds;
    float4 t0 = *(const float4*)qp;
    float4 t1 = *(const float4*)(qp + 4);
    q[0] = t0.x; q[1] = t0.y; q[2] = t0.z; q[3] = t0.w;
    q[4] = t1.x; q[5] = t1.y; q[6] = t1.z; q[7] = t1.w;
  } else {
    #pragma unroll
    for (int j = 0; j < 8; ++j) q[j] = 0.f;
  }

  float acc[8] = {};
  float m = -INFINITY, l = 0.f;

  for (int kt = 0; kt < T_; kt += 64) {
    #pragma unroll
    for (int it = 0; it < 4; ++it) {
      int idx = tid + it * 256;
      int rr = idx >> 4;
      int cc = (idx & 15) << 2;
      size_t gro = ((size_t)(b * T_) + kt + rr) * C_ + h * D_ + cc;
      *(float4*)&Ks[rr][cc] = *(const float4*)(Km + gro);
      *(float4*)&Vs[rr][cc] = *(const float4*)(Vm + gro);
    }
    if (tid < 64) msk[tid] = mask[b * T_ + kt + tid];
    __syncthreads();

    float p[64];
    #pragma unroll
    for (int j = 0; j < 64; ++j) {
      float4 k0 = *(const float4*)&Ks[j][ds];
      float4 k1 = *(const float4*)&Ks[j][ds + 4];
      float part = q[0]*k0.x + q[1]*k0.y + q[2]*k0.z + q[3]*k0.w
                 + q[4]*k1.x + q[5]*k1.y + q[6]*k1.z + q[7]*k1.w;
      part += __shfl_xor(part, 1);
      part += __shfl_xor(part, 2);
      part += __shfl_xor(part, 4);
      float sc = part * INV_;
      p[j] = msk[j] ? sc : NEG_;
    }
    float mt = p[0];
    #pragma unroll
    for (int j = 1; j < 64; ++j) mt = fmaxf(mt, p[j]);
    float mnew = fmaxf(m, mt);
    float fac = __expf(m - mnew);
    l *= fac;
    #pragma unroll
    for (int jj = 0; jj < 8; ++jj) acc[jj] *= fac;
    float ps = 0.f;
    #pragma unroll
    for (int j = 0; j < 64; ++j) {
      float e = __expf(p[j] - mnew);
      p[j] = e;
      ps += e;
    }
    l += ps;
    #pragma unroll
    for (int j = 0; j < 64; ++j) {
      float4 v0 = *(const float4*)&Vs[j][ds];
      float4 v1 = *(const float4*)&Vs[j][ds + 4];
      acc[0] += p[j]*v0.x; acc[1] += p[j]*v0.y; acc[2] += p[j]*v0.z; acc[3] += p[j]*v0.w;
      acc[4] += p[j]*v1.x; acc[5] += p[j]*v1.y; acc[6] += p[j]*v1.z; acc[7] += p[j]*v1.w;
    }
    m = mnew;
    __syncthreads();
  }

  if (vq) {
    float rl = 1.f / l;
    bf16_t* op = yout + ((size_t)(b * TM1) + qi) * C_ + h * D_ + ds;
    bf16x8_t o;
    #pragma unroll
    for (int j = 0; j < 8; ++j) o[j] = (bf16_t)(acc[j] * rl);
    *(bf16x8_t*)op = o;
  }
}

// ---------------------------------------------------------------------------
// cls attention (unchanged, fp32)
// ---------------------------------------------------------------------------
__global__ __launch_bounds__(64) void cls_attn(
    const float* __restrict__ Q, const float* __restrict__ kc,
    const float* __restrict__ Vm, const int* __restrict__ mask,
    float* __restrict__ yout /* (B,768) */)
{
  __shared__ float qs[64];
  __shared__ float Ks[64][65];
  __shared__ float Vs[64][65];
  __shared__ float Ps[64];

  const int b = blockIdx.x / H_, h = blockIdx.x % H_;
  const int lane = threadIdx.x;

  qs[lane] = Q[(size_t)(b * T_) * C_ + h * D_ + lane];
  __syncthreads();

  float m = -INFINITY, l = 0.f, acc = 0.f;
  for (int kt = 0; kt < T_; kt += 64) {
    for (int rr = 0; rr < 64; ++rr) {
      size_t gro = ((size_t)(b * T_) + kt + rr) * C_ + h * D_ + lane;
      Ks[rr][lane] = kc[gro];
      Vs[rr][lane] = Vm[gro];
    }
    __syncthreads();
    float sc = 0.f;
    #pragma unroll
    for (int d = 0; d < 64; ++d) sc += qs[d] * Ks[lane][d];
    sc *= INV_;
    if (!mask[b * T_ + kt + lane]) sc = NEG_;
    float mt = sc;
    #pragma unroll
    for (int off = 32; off > 0; off >>= 1) mt = fmaxf(mt, __shfl_xor(mt, off));
    float mnew = fmaxf(m, mt);
    float e = __expf(sc - mnew);
    float ssum = e;
    #pragma unroll
    for (int off = 32; off > 0; off >>= 1) ssum += __shfl_xor(ssum, off);
    float fac = __expf(m - mnew);
    acc *= fac;
    l = l * fac + ssum;
    Ps[lane] = e;
    __syncthreads();
    #pragma unroll
    for (int j = 0; j < 64; ++j) acc += Ps[j] * Vs[j][lane];
    m = mnew;
    __syncthreads();
  }
  yout[(size_t)b * C_ + h * D_ + lane] = acc / l;
}

// ---------------------------------------------------------------------------
// Neighbour attention (fp32 compute, bf16 output for the Wp GEMM).
// ---------------------------------------------------------------------------
__global__ __launch_bounds__(256) void neigh_attn(
    const float* __restrict__ Q, const float* __restrict__ kcmat,
    const float* __restrict__ Vm,
    const float* __restrict__ qn_r, const float* __restrict__ kn_r,
    const float* __restrict__ vn_r,
    int b0, bf16_t* __restrict__ outn /* (nb*511*5, 768) bf16 */)
{
  __shared__ float qs[KC5 * C_];
  __shared__ float ks[KC5 * C_];
  __shared__ float vs[KC5 * C_];
  __shared__ float Ps[H_ * 25];

  const int bt = blockIdx.x;
  const int bb = bt / TM1, t = bt % TM1;
  const int b = b0 + bb;
  const int tid = threadIdx.x;
  const size_t tok = (size_t)(b * T_) + t + 1;
  const size_t nrow = ((size_t)(bb * TM1) + t) * KN_;

  for (int idx = tid; idx < KC5 * C_ / 4; idx += 256) {
    int i = idx / (C_ / 4);
    int d4 = (idx % (C_ / 4)) * 4;
    const float *qp, *kp, *vp;
    if (i == 0) {
      qp = Q + tok * C_ + d4;
      kp = kcmat + tok * C_ + d4;
      vp = Vm + tok * C_ + d4;
    } else {
      size_t rr = (nrow + i - 1) * C_ + d4;
      qp = qn_r + rr; kp = kn_r + rr; vp = vn_r + rr;
    }
    *(float4*)&qs[i * C_ + d4] = *(const float4*)qp;
    *(float4*)&ks[i * C_ + d4] = *(const float4*)kp;
    *(float4*)&vs[i * C_ + d4] = *(const float4*)vp;
  }
  __syncthreads();

  if (tid < H_ * KC5) {
    int h = tid / KC5, i = tid % KC5;
    float sc[KC5];
    #pragma unroll
    for (int j = 0; j < KC5; ++j) {
      float sum = 0.f;
      #pragma unroll
      for (int d = 0; d < D_; ++d)
        sum += qs[i * C_ + h * D_ + d] * ks[j * C_ + h * D_ + d];
      sc[j] = sum * INV_;
    }
    float mt = sc[0];
    #pragma unroll
    for (int j = 1; j < KC5; ++j) mt = fmaxf(mt, sc[j]);
    float e[KC5], ssum = 0.f;
    #pragma unroll
    for (int j = 0; j < KC5; ++j) { e[j] = __expf(sc[j] - mt); ssum += e[j]; }
    float rs = 1.f / ssum;
    #pragma unroll
    for (int j = 0; j < KC5; ++j) Ps[h * 25 + i * KC5 + j] = e[j] * rs;
  }
  __syncthreads();

  for (int idx = tid; idx < KC5 * C_; idx += 256) {
    int i = idx / C_, c = idx % C_;
    int h = c / D_;
    float sum = 0.f;
    #pragma unroll
    for (int j = 0; j < KC5; ++j)
      sum += Ps[h * 25 + i * KC5 + j] * vs[j * C_ + c];
    outn[(((size_t)(bb * TM1) + t) * KC5 + i) * C_ + c] = (bf16_t)sum;
  }
}

// ---------------------------------------------------------------------------
// Residual + LayerNorm combine kernels
// ---------------------------------------------------------------------------
__device__ __forceinline__ void block_reduce2(float& s, float& ss, float* red) {
  #pragma unroll
  for (int off = 32; off > 0; off >>= 1) {
    s += __shfl_down(s, off);
    ss += __shfl_down(ss, off);
  }
  int wid = threadIdx.x >> 6;
  if ((threadIdx.x & 63) == 0) { red[wid * 2] = s; red[wid * 2 + 1] = ss; }
  __syncthreads();
  s  = red[0] + red[2] + red[4] + red[6];
  ss = red[1] + red[3] + red[5] + red[7];
}

__device__ __forceinline__ void ln_row(const float vals[3], float s, float ss,
                                       const float* __restrict__ g,
                                       const float* __restrict__ bb,
                                       float* __restrict__ orow, float* red) {
  block_reduce2(s, ss, red);
  float mean = s * (1.f / (float)C_);
  float var = ss * (1.f / (float)C_) - mean * mean;
  var = fmaxf(var, 0.f);
  float rs = rsqrtf(var + EPS_);
  #pragma unroll
  for (int ii = 0; ii < 3; ++ii) {
    int c = threadIdx.x + ii * 256;
    orow[c] = (vals[ii] - mean) * rs * g[c] + bb[c];
  }
}

__global__ __launch_bounds__(256) void combine_main(
    const float* __restrict__ yselfP, const float* __restrict__ poutn,
    const float* __restrict__ x, const float* __restrict__ g,
    const float* __restrict__ bln, int b0, float* __restrict__ dout)
{
  __shared__ float red[8];
  const int bt = blockIdx.x;
  const int bbb = bt / TM1, t = bt % TM1;
  const int b = b0 + bbb;
  const float* ys = yselfP + ((size_t)(b * TM1) + t) * C_;
  const float* pn = poutn + (((size_t)(bbb * TM1) + t) * KC5 + 0) * C_;
  const float* xr = x + ((size_t)(b * T_) + t + 1) * C_;
  float* orow = dout + ((size_t)(b * T_) + t + 1) * C_;
  float vals[3], s = 0.f, ss = 0.f;
  #pragma unroll
  for (int ii = 0; ii < 3; ++ii) {
    int c = threadIdx.x + ii * 256;
    float v = SCALE_ * pn[c] + (1.f - SCALE_) * ys[c] + xr[c];
    vals[ii] = v; s += v; ss += v * v;
  }
  ln_row(vals, s, ss, g, bln, orow, red);
}

__global__ __launch_bounds__(256) void combine_neigh(
    const float* __restrict__ poutn, const float* __restrict__ nrc,
    const float* __restrict__ g, const float* __restrict__ bln,
    int b0, float* __restrict__ dout)
{
  __shared__ float red[8];
  const int idx = blockIdx.x;
  const int i1 = idx % KN_;
  const int bt = idx / KN_;
  const int bbb = bt / TM1, t = bt % TM1;
  const int b = b0 + bbb;
  const float* pn = poutn + ((size_t)bt * KC5 + 1 + i1) * C_;
  const float* nr = nrc + ((size_t)bt * KN_ + i1) * C_;
  float* orow = dout + (((size_t)(b * TM1) + t) * KN_ + i1) * C_;
  float vals[3], s = 0.f, ss = 0.f;
  #pragma unroll
  for (int ii = 0; ii < 3; ++ii) {
    int c = threadIdx.x + ii * 256;
    float v = pn[c] + nr[c];
    vals[ii] = v; s += v; ss += v * v;
  }
  ln_row(vals, s, ss, g, bln, orow, red);
}

__global__ __launch_bounds__(256) void combine_cls(
    const float* __restrict__ yclsP, const float* __restrict__ x,
    const float* __restrict__ g, const float* __restrict__ bln,
    float* __restrict__ dout)
{
  __shared__ float red[8];
  const int b = blockIdx.x;
  const float* yc = yclsP + (size_t)b * C_;
  const float* xr = x + (size_t)(b * T_) * C_;
  float* orow = dout + (size_t)(b * T_) * C_;
  float vals[3], s = 0.f, ss = 0.f;
  #pragma unroll
  for (int ii = 0; ii < 3; ++ii) {
    int c = threadIdx.x + ii * 256;
    float v = yc[c] + xr[c];
    vals[ii] = v; s += v; ss += v * v;
  }
  ln_row(vals, s, ss, g, bln, orow, red);
}

// ---------------------------------------------------------------------------
extern "C" void kernel_launch(void* const* d_in, const int* in_sizes, int n_in,
                              void* d_out, int out_size, void* d_ws, size_t ws_size,
                              hipStream_t stream) {
  (void)in_sizes; (void)n_in; (void)out_size;
  const float* x    = (const float*)d_in[0];
  const int*   mask = (const int*)d_in[1];
  const float* nrep = (const float*)d_in[2];
  const float* Wq = (const float*)d_in[3];  const float* bq = (const float*)d_in[4];
  const float* Wk = (const float*)d_in[5];  const float* bk = (const float*)d_in[6];
  const float* Wv = (const float*)d_in[7];  const float* bv = (const float*)d_in[8];
  const float* Wp = (const float*)d_in[9];  const float* bp = (const float*)d_in[10];
  const float* Wd = (const float*)d_in[11]; const float* bd = (const float*)d_in[12];
  const float* Wu = (const float*)d_in[13]; const float* bu = (const float*)d_in[14];
  const float* lng = (const float*)d_in[15];
  const float* lnb = (const float*)d_in[16];
  float* dout = (float*)d_out;
  const size_t OUT1 = (size_t)B_ * T_ * C_;

  char* ws = (char*)d_ws;
  size_t off = 0;
  auto alloc = [&](size_t bytes) -> void* {
    void* p = ws + off; off += (bytes + 255) & ~(size_t)255; return p;
  };
  const size_t NT = (size_t)B_ * T_;      // 4096
  const size_t NR = (size_t)B_ * TM1 * KN_;  // neighbour rows total

  bf16_t* xbf  = (bf16_t*)alloc(NT * C_ * 2);
  bf16_t* nrbf = (bf16_t*)alloc(NR * C_ * 2);
  bf16_t* Wtq  = (bf16_t*)alloc((size_t)C_ * C_ * 2);
  bf16_t* Wtk  = (bf16_t*)alloc((size_t)C_ * C_ * 2);
  bf16_t* Wtv  = (bf16_t*)alloc((size_t)C_ * C_ * 2);
  bf16_t* Wtp  = (bf16_t*)alloc((size_t)C_ * C_ * 2);
  float* Q   = (float*)alloc(NT * C_ * 4);
  float* Km  = (float*)alloc(NT * C_ * 4);
  float* Vm  = (float*)alloc(NT * C_ * 4);
  float* t1  = (float*)alloc(NT * R_ * 4);
  float* kc  = (float*)alloc(NT * C_ * 4);
  bf16_t* ysh = (bf16_t*)alloc((size_t)B_ * TM1 * C_ * 2);
  float* ysp = (float*)alloc((size_t)B_ * TM1 * C_ * 4);
  float* ych = (float*)alloc((size_t)B_ * C_ * 4);
  float* ycp = (float*)alloc((size_t)B_ * C_ * 4);
  const size_t fixed = off;
  // per-batch chunk bytes: qn,vn,kn (f32) + t2 (f32) + outn (bf16) + poutn (f32)
  const size_t perb = (size_t)TM1 * KN_ * C_ * 4 * 3 + (size_t)TM1 * KN_ * R_ * 4
                    + (size_t)TM1 * KC5 * C_ * 2 + (size_t)TM1 * KC5 * C_ * 4
                    + 6 * 256;
  int nb = 1;
  for (int cand : {8, 4, 2, 1}) {
    if (fixed + perb * (size_t)cand <= ws_size) { nb = cand; break; }
  }
  float*  qn    = (float*)alloc((size_t)nb * TM1 * KN_ * C_ * 4);
  float*  vn    = (float*)alloc((size_t)nb * TM1 * KN_ * C_ * 4);
  float*  t2    = (float*)alloc((size_t)nb * TM1 * KN_ * R_ * 4);
  float*  kn    = (float*)alloc((size_t)nb * TM1 * KN_ * C_ * 4);
  bf16_t* outn  = (bf16_t*)alloc((size_t)nb * TM1 * KC5 * C_ * 2);
  float*  poutn = (float*)alloc((size_t)nb * TM1 * KC5 * C_ * 4);

  dim3 blk(256);
  auto g2 = [](int M, int N) { return dim3((N + BN - 1) / BN, (M + BM - 1) / BM); };
  auto gm = [](int M) { return dim3(C_ / 128, (M + 127) / 128); };

  // conversions
  cvt_bf16<<<1024, blk, 0, stream>>>(x, xbf, (long)(NT * C_));
  cvt_bf16<<<2048, blk, 0, stream>>>(nrep, nrbf, (long)(NR * C_));
  dim3 tg(C_ / 32, C_ / 32);
  wtrans<<<tg, blk, 0, stream>>>(Wq, Wtq);
  wtrans<<<tg, blk, 0, stream>>>(Wk, Wtk);
  wtrans<<<tg, blk, 0, stream>>>(Wv, Wtv);
  wtrans<<<tg, blk, 0, stream>>>(Wp, Wtp);

  // QKV / low-rank projections
  gemm_mfma<<<gm((int)NT), blk, 0, stream>>>(xbf, Wtq, bq, Q, (int)NT, C_, C_);
  gemm_mfma<<<gm((int)NT), blk, 0, stream>>>(xbf, Wtk, bk, Km, (int)NT, C_, C_);
  gemm_mfma<<<gm((int)NT), blk, 0, stream>>>(xbf, Wtv, bv, Vm, (int)NT, C_, C_);
  gemm_bias<<<g2((int)NT, R_), blk, 0, stream>>>(x, Wd, bd, t1, (int)NT, C_, R_);
  gemm_bias<<<g2((int)NT, C_), blk, 0, stream>>>(t1, Wu, bu, kc, (int)NT, R_, C_);

  // self attention + projection
  self_attn<<<dim3(16, H_, B_), blk, 0, stream>>>(Q, Km, Vm, mask, ysh);
  gemm_mfma<<<gm(B_ * TM1), blk, 0, stream>>>(ysh, Wtp, bp, ysp, B_ * TM1, C_, C_);

  // cls attention + projection + combine
  cls_attn<<<B_ * H_, 64, 0, stream>>>(Q, kc, Vm, mask, ych);
  gemm_bias<<<g2(B_, C_), blk, 0, stream>>>(ych, Wp, bp, ycp, B_, C_, C_);
  combine_cls<<<B_, blk, 0, stream>>>(ycp, x, lng, lnb, dout);

  // neighbour pipeline, chunked over b
  for (int b0 = 0; b0 < B_; b0 += nb) {
    const int Mn = nb * TM1 * KN_;
    const int Mo = nb * TM1 * KC5;
    const float*  nrc   = nrep + (size_t)b0 * TM1 * KN_ * C_;
    const bf16_t* nrcbf = nrbf + (size_t)b0 * TM1 * KN_ * C_;
    gemm_mfma<<<gm(Mn), blk, 0, stream>>>(nrcbf, Wtq, bq, qn, Mn, C_, C_);
    gemm_mfma<<<gm(Mn), blk, 0, stream>>>(nrcbf, Wtv, bv, vn, Mn, C_, C_);
    gemm_bias<<<g2(Mn, R_), blk, 0, stream>>>(nrc, Wd, bd, t2, Mn, C_, R_);
    gemm_bias<<<g2(Mn, C_), blk, 0, stream>>>(t2, Wu, bu, kn, Mn, R_, C_);
    neigh_attn<<<nb * TM1, blk, 0, stream>>>(Q, kc, Vm, qn, kn, vn, b0, outn);
    gemm_mfma<<<gm(Mo), blk, 0, stream>>>(outn, Wtp, bp, poutn, Mo, C_, C_);
    combine_main<<<nb * TM1, blk, 0, stream>>>(ysp, poutn, x, lng, lnb, b0, dout);
    combine_neigh<<<nb * TM1 * KN_, blk, 0, stream>>>(poutn, nrc, lng, lnb, b0,
                                                      dout + OUT1);
  }
}

// Round 3
// 752.470 us; speedup vs baseline: 2.5180x; 1.3690x over previous
//
#include <hip/hip_runtime.h>
#include <math.h>

#define C_    768
#define H_    12
#define D_    64
#define B_    8
#define T_    512
#define TM1   511
#define R_    8
#define KN_   4
#define KC5   5
#define SCALE_ 0.5f
#define EPS_  1e-12f
#define NEG_  -1000000000.0f
#define INV_  0.125f   /* 1/sqrt(64) */

typedef __bf16 bf16_t;
typedef __bf16 bf16x4_t __attribute__((ext_vector_type(4)));
typedef __bf16 bf16x8_t __attribute__((ext_vector_type(8)));
typedef float  f32x4_t  __attribute__((ext_vector_type(4)));
typedef const void __attribute__((address_space(1)))* gas_t;
typedef void       __attribute__((address_space(3)))* las_t;

__device__ __forceinline__ void gl_lds16(const bf16_t* g, bf16_t* l) {
  __builtin_amdgcn_global_load_lds((gas_t)g, (las_t)l, 16, 0, 0);
}

// ---------------------------------------------------------------------------
// fp32 -> bf16 flat convert (n % 4 == 0)
// ---------------------------------------------------------------------------
__global__ __launch_bounds__(256) void cvt_bf16(const float* __restrict__ in,
                                                bf16_t* __restrict__ out, long n) {
  long i = ((long)blockIdx.x * 256 + threadIdx.x) * 4;
  const long stride = (long)gridDim.x * 256 * 4;
  for (; i < n; i += stride) {
    float4 v = *(const float4*)(in + i);
    bf16x4_t o = { (bf16_t)v.x, (bf16_t)v.y, (bf16_t)v.z, (bf16_t)v.w };
    *(bf16x4_t*)(out + i) = o;
  }
}

// ---------------------------------------------------------------------------
// Weight transpose + convert: Wt[n][k] = (bf16) W[k][n], 768x768.
// ---------------------------------------------------------------------------
__global__ __launch_bounds__(256) void wtrans(const float* __restrict__ W,
                                              bf16_t* __restrict__ Wt) {
  __shared__ float tile[32][33];
  const int n0 = blockIdx.x * 32, k0 = blockIdx.y * 32;
  const int tx = threadIdx.x & 31, ty = threadIdx.x >> 5;
  #pragma unroll
  for (int r = ty; r < 32; r += 8)
    tile[r][tx] = W[(size_t)(k0 + r) * C_ + n0 + tx];
  __syncthreads();
  #pragma unroll
  for (int r = ty; r < 32; r += 8)
    Wt[(size_t)(n0 + r) * C_ + k0 + tx] = (bf16_t)tile[tx][r];
}

// ---------------------------------------------------------------------------
// bf16 MFMA GEMM (m97 structure): C(MxN,f32) = A(MxK,bf16) @ Bt(NxK,bf16)^T + bias
// mode 0: f32 out only.  mode 1: + linear bf16 copy.  mode 2: + transposed-V
// bf16 copy laid out [b][h][d=64][T=512] (requires M==4096, N==768).
// ---------------------------------------------------------------------------
__global__ __launch_bounds__(256) void gemm_mfma(
    const bf16_t* __restrict__ A, const bf16_t* __restrict__ Bt,
    const float* __restrict__ bias, float* __restrict__ Cmat,
    bf16_t* __restrict__ Cbf, int mode,
    int M, int K, int N)
{
  __shared__ bf16_t As[128 * 32];
  __shared__ bf16_t Bs[128 * 32];
  const int tid = threadIdx.x;
  const int lane = tid & 63;
  const int wv = tid >> 6;
  const int row0 = blockIdx.y * 128;
  const int col0 = blockIdx.x * 128;
  const int wr = (wv >> 1) * 64;
  const int wc = (wv & 1) * 64;
  const int sr = tid >> 2;
  const int sk = (tid & 3) * 8;

  int ra0 = row0 + sr;       if (ra0 > M - 1) ra0 = M - 1;
  int ra1 = row0 + 64 + sr;  if (ra1 > M - 1) ra1 = M - 1;
  const bf16_t* ga0 = A + (size_t)ra0 * K + sk;
  const bf16_t* ga1 = A + (size_t)ra1 * K + sk;
  const bf16_t* gb0 = Bt + (size_t)(col0 + sr) * K + sk;
  const bf16_t* gb1 = Bt + (size_t)(col0 + 64 + sr) * K + sk;
  bf16_t* lA = As + wv * 512;
  bf16_t* lB = Bs + wv * 512;

  f32x4_t acc[4][4];
  #pragma unroll
  for (int i = 0; i < 4; ++i)
    #pragma unroll
    for (int j = 0; j < 4; ++j) acc[i][j] = (f32x4_t){0.f, 0.f, 0.f, 0.f};

  const int fm = lane & 15;
  const int kb = (lane >> 4) * 8;

  for (int k0 = 0; k0 < K; k0 += 32) {
    gl_lds16(ga0 + k0, lA);
    gl_lds16(ga1 + k0, lA + 2048);
    gl_lds16(gb0 + k0, lB);
    gl_lds16(gb1 + k0, lB + 2048);
    __syncthreads();
    bf16x8_t af[4], bfr[4];
    #pragma unroll
    for (int mi = 0; mi < 4; ++mi)
      af[mi] = *(const bf16x8_t*)(As + (wr + mi * 16 + fm) * 32 + kb);
    #pragma unroll
    for (int ni = 0; ni < 4; ++ni)
      bfr[ni] = *(const bf16x8_t*)(Bs + (wc + ni * 16 + fm) * 32 + kb);
    #pragma unroll
    for (int mi = 0; mi < 4; ++mi)
      #pragma unroll
      for (int ni = 0; ni < 4; ++ni)
        acc[mi][ni] = __builtin_amdgcn_mfma_f32_16x16x32_bf16(af[mi], bfr[ni],
                                                              acc[mi][ni], 0, 0, 0);
    __syncthreads();
  }

  const int r4 = (lane >> 4) * 4;
  #pragma unroll
  for (int ni = 0; ni < 4; ++ni) {
    const int col = col0 + wc + ni * 16 + fm;
    const float bv = bias[col];
    #pragma unroll
    for (int mi = 0; mi < 4; ++mi) {
      const int rb = row0 + wr + mi * 16 + r4;
      float v[4];
      #pragma unroll
      for (int r = 0; r < 4; ++r) v[r] = acc[mi][ni][r] + bv;
      #pragma unroll
      for (int r = 0; r < 4; ++r)
        if (rb + r < M) Cmat[(size_t)(rb + r) * N + col] = v[r];
      if (mode == 1) {
        #pragma unroll
        for (int r = 0; r < 4; ++r)
          if (rb + r < M) Cbf[(size_t)(rb + r) * N + col] = (bf16_t)v[r];
      } else if (mode == 2) {
        bf16x4_t o4 = {(bf16_t)v[0], (bf16_t)v[1], (bf16_t)v[2], (bf16_t)v[3]};
        size_t idx = ((size_t)(rb >> 9) * H_ + (size_t)(col >> 6)) * ((size_t)D_ * T_)
                   + (size_t)(col & 63) * T_ + (size_t)(rb & 511);
        *(bf16x4_t*)(Cbf + idx) = o4;
      }
    }
  }
}

// ---------------------------------------------------------------------------
// Generic fp32 GEMM (K=8 / N=8 / tiny paths)
// ---------------------------------------------------------------------------
#define BM 64
#define BN 64
#define BK 16

__global__ __launch_bounds__(256) void gemm_bias(
    const float* __restrict__ A, const float* __restrict__ W,
    const float* __restrict__ bias, float* __restrict__ Cmat,
    int M, int K, int N)
{
  __shared__ float As[BK][BM + 4];
  __shared__ float Bs[BK][BN];
  const int tid  = threadIdx.x;
  const int row0 = blockIdx.y * BM;
  const int col0 = blockIdx.x * BN;
  const int m0 = (tid >> 4) << 2;
  const int n0 = (tid & 15) << 2;
  const int la_r = tid >> 2;
  const int la_k = (tid & 3) << 2;
  const int lb_k = tid >> 4;
  const int lb_n = (tid & 15) << 2;

  float acc[4][4] = {};

  for (int k0 = 0; k0 < K; k0 += BK) {
    float a0 = 0.f, a1 = 0.f, a2 = 0.f, a3 = 0.f;
    {
      int ar = row0 + la_r;
      int ak = k0 + la_k;
      if (ar < M) {
        const float* ap = A + (size_t)ar * K + ak;
        if (ak + 3 < K) {
          float4 t = *(const float4*)ap;
          a0 = t.x; a1 = t.y; a2 = t.z; a3 = t.w;
        } else {
          if (ak + 0 < K) a0 = ap[0];
          if (ak + 1 < K) a1 = ap[1];
          if (ak + 2 < K) a2 = ap[2];
          if (ak + 3 < K) a3 = ap[3];
        }
      }
    }
    As[la_k + 0][la_r] = a0;
    As[la_k + 1][la_r] = a1;
    As[la_k + 2][la_r] = a2;
    As[la_k + 3][la_r] = a3;
    {
      float4 bv = {0.f, 0.f, 0.f, 0.f};
      int bk = k0 + lb_k;
      int bn = col0 + lb_n;
      if (bk < K) {
        const float* bp = W + (size_t)bk * N + bn;
        if (bn + 3 < N) bv = *(const float4*)bp;
        else {
          if (bn + 0 < N) bv.x = bp[0];
          if (bn + 1 < N) bv.y = bp[1];
          if (bn + 2 < N) bv.z = bp[2];
          if (bn + 3 < N) bv.w = bp[3];
        }
      }
      *(float4*)&Bs[lb_k][lb_n] = bv;
    }
    __syncthreads();
    #pragma unroll
    for (int kk = 0; kk < BK; ++kk) {
      float4 av = *(const float4*)&As[kk][m0];
      float4 bv = *(const float4*)&Bs[kk][n0];
      float am[4] = {av.x, av.y, av.z, av.w};
      float bn4[4] = {bv.x, bv.y, bv.z, bv.w};
      #pragma unroll
      for (int i = 0; i < 4; ++i)
        #pragma unroll
        for (int j = 0; j < 4; ++j)
          acc[i][j] += am[i] * bn4[j];
    }
    __syncthreads();
  }

  if (col0 + n0 < N) {
    float4 b4 = *(const float4*)&bias[col0 + n0];
    #pragma unroll
    for (int i = 0; i < 4; ++i) {
      int r = row0 + m0 + i;
      if (r < M) {
        float4 o;
        o.x = acc[i][0] + b4.x;
        o.y = acc[i][1] + b4.y;
        o.z = acc[i][2] + b4.z;
        o.w = acc[i][3] + b4.w;
        *(float4*)&Cmat[(size_t)r * N + col0 + n0] = o;
      }
    }
  }
}

// ---------------------------------------------------------------------------
// MFMA flash self-attention.  Block = 256 thr (4 waves), wave owns 16 q rows.
// Grid (8 qtiles, H, B).  KV step = 64.  S^T = mfma(K,Q); softmax per q-col;
// P via per-wave LDS; O = mfma(P, V) with V staged from the transposed
// global copy Vtg[b][h][d][T].  All LDS tiles slot-XOR swizzled.
// ---------------------------------------------------------------------------
__global__ __launch_bounds__(256) void attn_mfma(
    const bf16_t* __restrict__ Qb, const bf16_t* __restrict__ Kb,
    const bf16_t* __restrict__ Vtg, const int* __restrict__ mask,
    bf16_t* __restrict__ yout /* (B,511,768) bf16 */)
{
  __shared__ bf16_t Ks[64 * 64];      // row k (0..63), 64 d, swizzled slots
  __shared__ bf16_t Vs[64 * 64];      // row d (0..63), 64 k, swizzled slots
  __shared__ bf16_t Pl[4][16 * 64];   // per-wave: row q (16), 64 k, swizzled
  __shared__ float  fac_s[4][16];
  __shared__ float  l_s[4][16];
  __shared__ int    msk_s[64];

  const int b = blockIdx.z, h = blockIdx.y;
  const int qt0 = blockIdx.x * 64;
  const int tid = threadIdx.x;
  const int lane = tid & 63;
  const int w = tid >> 6;
  const int lq = lane & 15;
  const int g = lane >> 4;

  // Q fragments (B-operand: lane holds q=lq, d = dh*32 + 8g + j)
  const int qi_frag = qt0 + w * 16 + lq;
  const int qtok = (qi_frag < TM1 ? qi_frag : TM1 - 1) + 1;
  bf16x8_t qf[2];
  {
    const bf16_t* qp = Qb + ((size_t)(b * T_) + qtok) * C_ + h * D_ + 8 * g;
    qf[0] = *(const bf16x8_t*)qp;
    qf[1] = *(const bf16x8_t*)(qp + 32);
  }

  const bf16_t* kbase = Kb + (size_t)(b * T_) * C_ + h * D_;
  const bf16_t* vbase = Vtg + ((size_t)(b * H_) + h) * ((size_t)D_ * T_);

  f32x4_t o[4];
  #pragma unroll
  for (int i = 0; i < 4; ++i) o[i] = (f32x4_t){0.f, 0.f, 0.f, 0.f};
  float m = -INFINITY, l = 0.f;

  for (int kt = 0; kt < T_; kt += 64) {
    // stage K (64x64) and V^T (64x64) with pre-swizzled global source
    #pragma unroll
    for (int i = 0; i < 2; ++i) {
      const int tp = tid + i * 256;
      const int kr = tp >> 3;          // LDS row (k for Ks, d for Vs)
      const int sl = tp & 7;           // 16B slot
      const int ss = sl ^ (kr & 7);    // swizzled source slot
      gl_lds16(kbase + (size_t)(kt + kr) * C_ + 8 * ss,
               Ks + (size_t)(i * 4 + w) * 512);
      gl_lds16(vbase + (size_t)kr * T_ + kt + 8 * ss,
               Vs + (size_t)(i * 4 + w) * 512);
    }
    if (tid < 64) msk_s[tid] = mask[b * T_ + kt + tid];
    __syncthreads();

    // QK^T: S^T tiles (col q = lq, row k = t*16 + 4g + r)
    f32x4_t st[4];
    #pragma unroll
    for (int t = 0; t < 4; ++t) {
      st[t] = (f32x4_t){0.f, 0.f, 0.f, 0.f};
      const int kk = t * 16 + lq;
      const bf16_t* krow = Ks + kk * 64;
      bf16x8_t kf0 = *(const bf16x8_t*)(krow + 8 * ((g)     ^ (kk & 7)));
      bf16x8_t kf1 = *(const bf16x8_t*)(krow + 8 * ((4 + g) ^ (kk & 7)));
      st[t] = __builtin_amdgcn_mfma_f32_16x16x32_bf16(kf0, qf[0], st[t], 0, 0, 0);
      st[t] = __builtin_amdgcn_mfma_f32_16x16x32_bf16(kf1, qf[1], st[t], 0, 0, 0);
    }

    // online softmax (state per q-col, replicated across the 4 g-groups)
    float p[16];
    float mt = -INFINITY;
    #pragma unroll
    for (int t = 0; t < 4; ++t) {
      const int4 mk = *(const int4*)&msk_s[t * 16 + 4 * g];
      p[4*t+0] = mk.x ? st[t][0] * INV_ : NEG_;
      p[4*t+1] = mk.y ? st[t][1] * INV_ : NEG_;
      p[4*t+2] = mk.z ? st[t][2] * INV_ : NEG_;
      p[4*t+3] = mk.w ? st[t][3] * INV_ : NEG_;
      mt = fmaxf(mt, fmaxf(fmaxf(p[4*t], p[4*t+1]), fmaxf(p[4*t+2], p[4*t+3])));
    }
    mt = fmaxf(mt, __shfl_xor(mt, 16));
    mt = fmaxf(mt, __shfl_xor(mt, 32));
    const float mnew = fmaxf(m, mt);
    const float fac = __expf(m - mnew);
    float ps = 0.f;
    #pragma unroll
    for (int i = 0; i < 16; ++i) { p[i] = __expf(p[i] - mnew); ps += p[i]; }
    ps += __shfl_xor(ps, 16);
    ps += __shfl_xor(ps, 32);
    l = l * fac + ps;
    m = mnew;
    if (lane < 16) fac_s[w][lane] = fac;

    // P -> per-wave LDS (row q = lq, cols k = t*16 + 4g + r), swizzled
    bf16_t* prow = Pl[w] + lq * 64;
    #pragma unroll
    for (int t = 0; t < 4; ++t) {
      bf16x4_t pb = {(bf16_t)p[4*t], (bf16_t)p[4*t+1],
                     (bf16_t)p[4*t+2], (bf16_t)p[4*t+3]};
      *(bf16x4_t*)(prow + 8 * ((2*t + (g >> 1)) ^ (lq & 7)) + 4 * (g & 1)) = pb;
    }
    // P A-fragments (lane: row q = lq, k = kh*32 + 8g + j)
    bf16x8_t pa0 = *(const bf16x8_t*)(prow + 8 * ((g)     ^ (lq & 7)));
    bf16x8_t pa1 = *(const bf16x8_t*)(prow + 8 * ((4 + g) ^ (lq & 7)));

    // rescale O and accumulate PV
    const float4 fc = *(const float4*)&fac_s[w][4 * g];
    #pragma unroll
    for (int db = 0; db < 4; ++db) {
      const int dr = db * 16 + lq;
      const bf16_t* vrow = Vs + dr * 64;
      bf16x8_t vf0 = *(const bf16x8_t*)(vrow + 8 * ((g)     ^ (dr & 7)));
      bf16x8_t vf1 = *(const bf16x8_t*)(vrow + 8 * ((4 + g) ^ (dr & 7)));
      o[db][0] *= fc.x; o[db][1] *= fc.y; o[db][2] *= fc.z; o[db][3] *= fc.w;
      o[db] = __builtin_amdgcn_mfma_f32_16x16x32_bf16(pa0, vf0, o[db], 0, 0, 0);
      o[db] = __builtin_amdgcn_mfma_f32_16x16x32_bf16(pa1, vf1, o[db], 0, 0, 0);
    }
    __syncthreads();
  }

  if (lane < 16) l_s[w][lane] = l;
  const float4 lv = *(const float4*)&l_s[w][4 * g];
  const float rl0 = 1.f / lv.x, rl1 = 1.f / lv.y;
  const float rl2 = 1.f / lv.z, rl3 = 1.f / lv.w;
  const int qr0 = qt0 + w * 16 + 4 * g;
  #pragma unroll
  for (int db = 0; db < 4; ++db) {
    const int col = h * D_ + db * 16 + lq;
    bf16_t* yp = yout + ((size_t)(b * TM1) + qr0) * C_ + col;
    if (qr0 + 0 < TM1) yp[0 * (size_t)C_] = (bf16_t)(o[db][0] * rl0);
    if (qr0 + 1 < TM1) yp[1 * (size_t)C_] = (bf16_t)(o[db][1] * rl1);
    if (qr0 + 2 < TM1) yp[2 * (size_t)C_] = (bf16_t)(o[db][2] * rl2);
    if (qr0 + 3 < TM1) yp[3 * (size_t)C_] = (bf16_t)(o[db][3] * rl3);
  }
}

// ---------------------------------------------------------------------------
// cls attention (fp32, tiny)
// ---------------------------------------------------------------------------
__global__ __launch_bounds__(64) void cls_attn(
    const float* __restrict__ Q, const float* __restrict__ kc,
    const float* __restrict__ Vm, const int* __restrict__ mask,
    float* __restrict__ yout /* (B,768) */)
{
  __shared__ float qs[64];
  __shared__ float Ks[64][65];
  __shared__ float Vs[64][65];
  __shared__ float Ps[64];

  const int b = blockIdx.x / H_, h = blockIdx.x % H_;
  const int lane = threadIdx.x;

  qs[lane] = Q[(size_t)(b * T_) * C_ + h * D_ + lane];
  __syncthreads();

  float m = -INFINITY, l = 0.f, acc = 0.f;
  for (int kt = 0; kt < T_; kt += 64) {
    for (int rr = 0; rr < 64; ++rr) {
      size_t gro = ((size_t)(b * T_) + kt + rr) * C_ + h * D_ + lane;
      Ks[rr][lane] = kc[gro];
      Vs[rr][lane] = Vm[gro];
    }
    __syncthreads();
    float sc = 0.f;
    #pragma unroll
    for (int d = 0; d < 64; ++d) sc += qs[d] * Ks[lane][d];
    sc *= INV_;
    if (!mask[b * T_ + kt + lane]) sc = NEG_;
    float mt = sc;
    #pragma unroll
    for (int off = 32; off > 0; off >>= 1) mt = fmaxf(mt, __shfl_xor(mt, off));
    float mnew = fmaxf(m, mt);
    float e = __expf(sc - mnew);
    float ssum = e;
    #pragma unroll
    for (int off = 32; off > 0; off >>= 1) ssum += __shfl_xor(ssum, off);
    float fac = __expf(m - mnew);
    acc *= fac;
    l = l * fac + ssum;
    Ps[lane] = e;
    __syncthreads();
    #pragma unroll
    for (int j = 0; j < 64; ++j) acc += Ps[j] * Vs[j][lane];
    m = mnew;
    __syncthreads();
  }
  yout[(size_t)b * C_ + h * D_ + lane] = acc / l;
}

// ---------------------------------------------------------------------------
// Neighbour attention (fp32 compute, bf16 output for the Wp GEMM).
// ---------------------------------------------------------------------------
__global__ __launch_bounds__(256) void neigh_attn(
    const float* __restrict__ Q, const float* __restrict__ kcmat,
    const float* __restrict__ Vm,
    const float* __restrict__ qn_r, const float* __restrict__ kn_r,
    const float* __restrict__ vn_r,
    int b0, bf16_t* __restrict__ outn /* (nb*511*5, 768) bf16 */)
{
  __shared__ float qs[KC5 * C_];
  __shared__ float ks[KC5 * C_];
  __shared__ float vs[KC5 * C_];
  __shared__ float Ps[H_ * 25];

  const int bt = blockIdx.x;
  const int bb = bt / TM1, t = bt % TM1;
  const int b = b0 + bb;
  const int tid = threadIdx.x;
  const size_t tok = (size_t)(b * T_) + t + 1;
  const size_t nrow = ((size_t)(bb * TM1) + t) * KN_;

  for (int idx = tid; idx < KC5 * C_ / 4; idx += 256) {
    int i = idx / (C_ / 4);
    int d4 = (idx % (C_ / 4)) * 4;
    const float *qp, *kp, *vp;
    if (i == 0) {
      qp = Q + tok * C_ + d4;
      kp = kcmat + tok * C_ + d4;
      vp = Vm + tok * C_ + d4;
    } else {
      size_t rr = (nrow + i - 1) * C_ + d4;
      qp = qn_r + rr; kp = kn_r + rr; vp = vn_r + rr;
    }
    *(float4*)&qs[i * C_ + d4] = *(const float4*)qp;
    *(float4*)&ks[i * C_ + d4] = *(const float4*)kp;
    *(float4*)&vs[i * C_ + d4] = *(const float4*)vp;
  }
  __syncthreads();

  if (tid < H_ * KC5) {
    int h = tid / KC5, i = tid % KC5;
    float sc[KC5];
    #pragma unroll
    for (int j = 0; j < KC5; ++j) {
      float sum = 0.f;
      #pragma unroll
      for (int d = 0; d < D_; ++d)
        sum += qs[i * C_ + h * D_ + d] * ks[j * C_ + h * D_ + d];
      sc[j] = sum * INV_;
    }
    float mt = sc[0];
    #pragma unroll
    for (int j = 1; j < KC5; ++j) mt = fmaxf(mt, sc[j]);
    float e[KC5], ssum = 0.f;
    #pragma unroll
    for (int j = 0; j < KC5; ++j) { e[j] = __expf(sc[j] - mt); ssum += e[j]; }
    float rs = 1.f / ssum;
    #pragma unroll
    for (int j = 0; j < KC5; ++j) Ps[h * 25 + i * KC5 + j] = e[j] * rs;
  }
  __syncthreads();

  for (int idx = tid; idx < KC5 * C_; idx += 256) {
    int i = idx / C_, c = idx % C_;
    int h = c / D_;
    float sum = 0.f;
    #pragma unroll
    for (int j = 0; j < KC5; ++j)
      sum += Ps[h * 25 + i * KC5 + j] * vs[j * C_ + c];
    outn[(((size_t)(bb * TM1) + t) * KC5 + i) * C_ + c] = (bf16_t)sum;
  }
}

// ---------------------------------------------------------------------------
// Residual + LayerNorm combine kernels
// ---------------------------------------------------------------------------
__device__ __forceinline__ void block_reduce2(float& s, float& ss, float* red) {
  #pragma unroll
  for (int off = 32; off > 0; off >>= 1) {
    s += __shfl_down(s, off);
    ss += __shfl_down(ss, off);
  }
  int wid = threadIdx.x >> 6;
  if ((threadIdx.x & 63) == 0) { red[wid * 2] = s; red[wid * 2 + 1] = ss; }
  __syncthreads();
  s  = red[0] + red[2] + red[4] + red[6];
  ss = red[1] + red[3] + red[5] + red[7];
}

__device__ __forceinline__ void ln_row(const float vals[3], float s, float ss,
                                       const float* __restrict__ g,
                                       const float* __restrict__ bb,
                                       float* __restrict__ orow, float* red) {
  block_reduce2(s, ss, red);
  float mean = s * (1.f / (float)C_);
  float var = ss * (1.f / (float)C_) - mean * mean;
  var = fmaxf(var, 0.f);
  float rs = rsqrtf(var + EPS_);
  #pragma unroll
  for (int ii = 0; ii < 3; ++ii) {
    int c = threadIdx.x + ii * 256;
    orow[c] = (vals[ii] - mean) * rs * g[c] + bb[c];
  }
}

__global__ __launch_bounds__(256) void combine_main(
    const float* __restrict__ yselfP, const float* __restrict__ poutn,
    const float* __restrict__ x, const float* __restrict__ g,
    const float* __restrict__ bln, int b0, float* __restrict__ dout)
{
  __shared__ float red[8];
  const int bt = blockIdx.x;
  const int bbb = bt / TM1, t = bt % TM1;
  const int b = b0 + bbb;
  const float* ys = yselfP + ((size_t)(b * TM1) + t) * C_;
  const float* pn = poutn + (((size_t)(bbb * TM1) + t) * KC5 + 0) * C_;
  const float* xr = x + ((size_t)(b * T_) + t + 1) * C_;
  float* orow = dout + ((size_t)(b * T_) + t + 1) * C_;
  float vals[3], s = 0.f, ss = 0.f;
  #pragma unroll
  for (int ii = 0; ii < 3; ++ii) {
    int c = threadIdx.x + ii * 256;
    float v = SCALE_ * pn[c] + (1.f - SCALE_) * ys[c] + xr[c];
    vals[ii] = v; s += v; ss += v * v;
  }
  ln_row(vals, s, ss, g, bln, orow, red);
}

__global__ __launch_bounds__(256) void combine_neigh(
    const float* __restrict__ poutn, const float* __restrict__ nrc,
    const float* __restrict__ g, const float* __restrict__ bln,
    int b0, float* __restrict__ dout)
{
  __shared__ float red[8];
  const int idx = blockIdx.x;
  const int i1 = idx % KN_;
  const int bt = idx / KN_;
  const int bbb = bt / TM1, t = bt % TM1;
  const int b = b0 + bbb;
  const float* pn = poutn + ((size_t)bt * KC5 + 1 + i1) * C_;
  const float* nr = nrc + ((size_t)bt * KN_ + i1) * C_;
  float* orow = dout + (((size_t)(b * TM1) + t) * KN_ + i1) * C_;
  float vals[3], s = 0.f, ss = 0.f;
  #pragma unroll
  for (int ii = 0; ii < 3; ++ii) {
    int c = threadIdx.x + ii * 256;
    float v = pn[c] + nr[c];
    vals[ii] = v; s += v; ss += v * v;
  }
  ln_row(vals, s, ss, g, bln, orow, red);
}

__global__ __launch_bounds__(256) void combine_cls(
    const float* __restrict__ yclsP, const float* __restrict__ x,
    const float* __restrict__ g, const float* __restrict__ bln,
    float* __restrict__ dout)
{
  __shared__ float red[8];
  const int b = blockIdx.x;
  const float* yc = yclsP + (size_t)b * C_;
  const float* xr = x + (size_t)(b * T_) * C_;
  float* orow = dout + (size_t)(b * T_) * C_;
  float vals[3], s = 0.f, ss = 0.f;
  #pragma unroll
  for (int ii = 0; ii < 3; ++ii) {
    int c = threadIdx.x + ii * 256;
    float v = yc[c] + xr[c];
    vals[ii] = v; s += v; ss += v * v;
  }
  ln_row(vals, s, ss, g, bln, orow, red);
}

// ---------------------------------------------------------------------------
extern "C" void kernel_launch(void* const* d_in, const int* in_sizes, int n_in,
                              void* d_out, int out_size, void* d_ws, size_t ws_size,
                              hipStream_t stream) {
  (void)in_sizes; (void)n_in; (void)out_size;
  const float* x    = (const float*)d_in[0];
  const int*   mask = (const int*)d_in[1];
  const float* nrep = (const float*)d_in[2];
  const float* Wq = (const float*)d_in[3];  const float* bq = (const float*)d_in[4];
  const float* Wk = (const float*)d_in[5];  const float* bk = (const float*)d_in[6];
  const float* Wv = (const float*)d_in[7];  const float* bv = (const float*)d_in[8];
  const float* Wp = (const float*)d_in[9];  const float* bp = (const float*)d_in[10];
  const float* Wd = (const float*)d_in[11]; const float* bd = (const float*)d_in[12];
  const float* Wu = (const float*)d_in[13]; const float* bu = (const float*)d_in[14];
  const float* lng = (const float*)d_in[15];
  const float* lnb = (const float*)d_in[16];
  float* dout = (float*)d_out;
  const size_t OUT1 = (size_t)B_ * T_ * C_;

  char* ws = (char*)d_ws;
  size_t off = 0;
  auto alloc = [&](size_t bytes) -> void* {
    void* p = ws + off; off += (bytes + 255) & ~(size_t)255; return p;
  };
  const size_t NT = (size_t)B_ * T_;
  const size_t NR = (size_t)B_ * TM1 * KN_;

  bf16_t* xbf  = (bf16_t*)alloc(NT * C_ * 2);
  bf16_t* nrbf = (bf16_t*)alloc(NR * C_ * 2);
  bf16_t* Wtq  = (bf16_t*)alloc((size_t)C_ * C_ * 2);
  bf16_t* Wtk  = (bf16_t*)alloc((size_t)C_ * C_ * 2);
  bf16_t* Wtv  = (bf16_t*)alloc((size_t)C_ * C_ * 2);
  bf16_t* Wtp  = (bf16_t*)alloc((size_t)C_ * C_ * 2);
  float* Q   = (float*)alloc(NT * C_ * 4);
  float* Km  = (float*)alloc(NT * C_ * 4);
  float* Vm  = (float*)alloc(NT * C_ * 4);
  bf16_t* Qb  = (bf16_t*)alloc(NT * C_ * 2);
  bf16_t* Kbf = (bf16_t*)alloc(NT * C_ * 2);
  bf16_t* Vtg = (bf16_t*)alloc(NT * C_ * 2);   // [b][h][d][T]
  float* t1  = (float*)alloc(NT * R_ * 4);
  float* kc  = (float*)alloc(NT * C_ * 4);
  bf16_t* ysh = (bf16_t*)alloc((size_t)B_ * TM1 * C_ * 2);
  float* ysp = (float*)alloc((size_t)B_ * TM1 * C_ * 4);
  float* ych = (float*)alloc((size_t)B_ * C_ * 4);
  float* ycp = (float*)alloc((size_t)B_ * C_ * 4);
  const size_t fixed = off;
  const size_t perb = (size_t)TM1 * KN_ * C_ * 4 * 3 + (size_t)TM1 * KN_ * R_ * 4
                    + (size_t)TM1 * KC5 * C_ * 2 + (size_t)TM1 * KC5 * C_ * 4
                    + 6 * 256;
  int nb = 1;
  for (int cand : {8, 4, 2, 1}) {
    if (fixed + perb * (size_t)cand <= ws_size) { nb = cand; break; }
  }
  float*  qn    = (float*)alloc((size_t)nb * TM1 * KN_ * C_ * 4);
  float*  vn    = (float*)alloc((size_t)nb * TM1 * KN_ * C_ * 4);
  float*  t2    = (float*)alloc((size_t)nb * TM1 * KN_ * R_ * 4);
  float*  kn    = (float*)alloc((size_t)nb * TM1 * KN_ * C_ * 4);
  bf16_t* outn  = (bf16_t*)alloc((size_t)nb * TM1 * KC5 * C_ * 2);
  float*  poutn = (float*)alloc((size_t)nb * TM1 * KC5 * C_ * 4);

  dim3 blk(256);
  auto g2 = [](int M, int N) { return dim3((N + BN - 1) / BN, (M + BM - 1) / BM); };
  auto gm = [](int M) { return dim3(C_ / 128, (M + 127) / 128); };

  // conversions
  cvt_bf16<<<1024, blk, 0, stream>>>(x, xbf, (long)(NT * C_));
  cvt_bf16<<<2048, blk, 0, stream>>>(nrep, nrbf, (long)(NR * C_));
  dim3 tg(C_ / 32, C_ / 32);
  wtrans<<<tg, blk, 0, stream>>>(Wq, Wtq);
  wtrans<<<tg, blk, 0, stream>>>(Wk, Wtk);
  wtrans<<<tg, blk, 0, stream>>>(Wv, Wtv);
  wtrans<<<tg, blk, 0, stream>>>(Wp, Wtp);

  // QKV / low-rank projections (Q/K also emit bf16; V emits transposed bf16)
  gemm_mfma<<<gm((int)NT), blk, 0, stream>>>(xbf, Wtq, bq, Q, Qb, 1, (int)NT, C_, C_);
  gemm_mfma<<<gm((int)NT), blk, 0, stream>>>(xbf, Wtk, bk, Km, Kbf, 1, (int)NT, C_, C_);
  gemm_mfma<<<gm((int)NT), blk, 0, stream>>>(xbf, Wtv, bv, Vm, Vtg, 2, (int)NT, C_, C_);
  gemm_bias<<<g2((int)NT, R_), blk, 0, stream>>>(x, Wd, bd, t1, (int)NT, C_, R_);
  gemm_bias<<<g2((int)NT, C_), blk, 0, stream>>>(t1, Wu, bu, kc, (int)NT, R_, C_);

  // MFMA flash self-attention + projection
  attn_mfma<<<dim3(8, H_, B_), blk, 0, stream>>>(Qb, Kbf, Vtg, mask, ysh);
  gemm_mfma<<<gm(B_ * TM1), blk, 0, stream>>>(ysh, Wtp, bp, ysp, nullptr, 0,
                                              B_ * TM1, C_, C_);

  // cls attention + projection + combine
  cls_attn<<<B_ * H_, 64, 0, stream>>>(Q, kc, Vm, mask, ych);
  gemm_bias<<<g2(B_, C_), blk, 0, stream>>>(ych, Wp, bp, ycp, B_, C_, C_);
  combine_cls<<<B_, blk, 0, stream>>>(ycp, x, lng, lnb, dout);

  // neighbour pipeline, chunked over b
  for (int b0 = 0; b0 < B_; b0 += nb) {
    const int Mn = nb * TM1 * KN_;
    const int Mo = nb * TM1 * KC5;
    const float*  nrc   = nrep + (size_t)b0 * TM1 * KN_ * C_;
    const bf16_t* nrcbf = nrbf + (size_t)b0 * TM1 * KN_ * C_;
    gemm_mfma<<<gm(Mn), blk, 0, stream>>>(nrcbf, Wtq, bq, qn, nullptr, 0, Mn, C_, C_);
    gemm_mfma<<<gm(Mn), blk, 0, stream>>>(nrcbf, Wtv, bv, vn, nullptr, 0, Mn, C_, C_);
    gemm_bias<<<g2(Mn, R_), blk, 0, stream>>>(nrc, Wd, bd, t2, Mn, C_, R_);
    gemm_bias<<<g2(Mn, C_), blk, 0, stream>>>(t2, Wu, bu, kn, Mn, R_, C_);
    neigh_attn<<<nb * TM1, blk, 0, stream>>>(Q, kc, Vm, qn, kn, vn, b0, outn);
    gemm_mfma<<<gm(Mo), blk, 0, stream>>>(outn, Wtp, bp, poutn, nullptr, 0, Mo, C_, C_);
    combine_main<<<nb * TM1, blk, 0, stream>>>(ysp, poutn, x, lng, lnb, b0, dout);
    combine_neigh<<<nb * TM1 * KN_, blk, 0, stream>>>(poutn, nrc, lng, lnb, b0,
                                                      dout + OUT1);
  }
}

// Round 4
// 547.571 us; speedup vs baseline: 3.4603x; 1.3742x over previous
//
#include <hip/hip_runtime.h>
#include <math.h>

#define C_    768
#define H_    12
#define D_    64
#define B_    8
#define T_    512
#define TM1   511
#define R_    8
#define KN_   4
#define KC5   5
#define SCALE_ 0.5f
#define EPS_  1e-12f
#define NEG_  -1000000000.0f
#define INV_  0.125f   /* 1/sqrt(64) */

typedef __bf16 bf16_t;
typedef __bf16 bf16x4_t __attribute__((ext_vector_type(4)));
typedef __bf16 bf16x8_t __attribute__((ext_vector_type(8)));
typedef float  f32x4_t  __attribute__((ext_vector_type(4)));
typedef const void __attribute__((address_space(1)))* gas_t;
typedef void       __attribute__((address_space(3)))* las_t;

__device__ __forceinline__ void gl_lds16(const bf16_t* g, bf16_t* l) {
  __builtin_amdgcn_global_load_lds((gas_t)g, (las_t)l, 16, 0, 0);
}

// ---------------------------------------------------------------------------
// fp32 -> bf16 flat convert (n % 4 == 0)
// ---------------------------------------------------------------------------
__global__ __launch_bounds__(256) void cvt_bf16(const float* __restrict__ in,
                                                bf16_t* __restrict__ out, long n) {
  long i = ((long)blockIdx.x * 256 + threadIdx.x) * 4;
  const long stride = (long)gridDim.x * 256 * 4;
  for (; i < n; i += stride) {
    float4 v = *(const float4*)(in + i);
    bf16x4_t o = { (bf16_t)v.x, (bf16_t)v.y, (bf16_t)v.z, (bf16_t)v.w };
    *(bf16x4_t*)(out + i) = o;
  }
}

// ---------------------------------------------------------------------------
// Weight transpose + convert: Wt[n][k] = (bf16) W[k][n], 768x768.
// ---------------------------------------------------------------------------
__global__ __launch_bounds__(256) void wtrans(const float* __restrict__ W,
                                              bf16_t* __restrict__ Wt) {
  __shared__ float tile[32][33];
  const int n0 = blockIdx.x * 32, k0 = blockIdx.y * 32;
  const int tx = threadIdx.x & 31, ty = threadIdx.x >> 5;
  #pragma unroll
  for (int r = ty; r < 32; r += 8)
    tile[r][tx] = W[(size_t)(k0 + r) * C_ + n0 + tx];
  __syncthreads();
  #pragma unroll
  for (int r = ty; r < 32; r += 8)
    Wt[(size_t)(n0 + r) * C_ + k0 + tx] = (bf16_t)tile[tx][r];
}

// ---------------------------------------------------------------------------
// Fused low-rank weight: Wt_du[n][k] = (bf16) sum_r Wd[k][r]*Wu[r][n];
// bias_du[n] = sum_r bd[r]*Wu[r][n] + bu[n].
// ---------------------------------------------------------------------------
__global__ __launch_bounds__(256) void wfuse(
    const float* __restrict__ Wd, const float* __restrict__ Wu,
    const float* __restrict__ bd, const float* __restrict__ bu,
    bf16_t* __restrict__ Wt_du, float* __restrict__ bias_du) {
  const int idx = blockIdx.x * 256 + threadIdx.x;   // over 768*768
  const int n = idx / C_, k = idx % C_;
  float s = 0.f;
  #pragma unroll
  for (int r = 0; r < R_; ++r) s += Wd[k * R_ + r] * Wu[r * C_ + n];
  Wt_du[(size_t)n * C_ + k] = (bf16_t)s;
  if (idx < C_) {
    float bs = bu[idx];
    #pragma unroll
    for (int r = 0; r < R_; ++r) bs += bd[r] * Wu[r * C_ + idx];
    bias_du[idx] = bs;
  }
}

// ---------------------------------------------------------------------------
// bf16 MFMA GEMM: mode bitmask: 1 = linear bf16 out (Cbf), 2 = transposed-V
// bf16 out [b][h][d][T] (Ctr; needs M%512==0, N==768), 4 = suppress fp32 Cmat.
// ---------------------------------------------------------------------------
__global__ __launch_bounds__(256) void gemm_mfma(
    const bf16_t* __restrict__ A, const bf16_t* __restrict__ Bt,
    const float* __restrict__ bias, float* __restrict__ Cmat,
    bf16_t* __restrict__ Cbf, bf16_t* __restrict__ Ctr, int mode,
    int M, int K, int N)
{
  __shared__ bf16_t As[128 * 32];
  __shared__ bf16_t Bs[128 * 32];
  const int tid = threadIdx.x;
  const int lane = tid & 63;
  const int wv = tid >> 6;
  const int row0 = blockIdx.y * 128;
  const int col0 = blockIdx.x * 128;
  const int wr = (wv >> 1) * 64;
  const int wc = (wv & 1) * 64;
  const int sr = tid >> 2;
  const int sk = (tid & 3) * 8;

  int ra0 = row0 + sr;       if (ra0 > M - 1) ra0 = M - 1;
  int ra1 = row0 + 64 + sr;  if (ra1 > M - 1) ra1 = M - 1;
  const bf16_t* ga0 = A + (size_t)ra0 * K + sk;
  const bf16_t* ga1 = A + (size_t)ra1 * K + sk;
  const bf16_t* gb0 = Bt + (size_t)(col0 + sr) * K + sk;
  const bf16_t* gb1 = Bt + (size_t)(col0 + 64 + sr) * K + sk;
  bf16_t* lA = As + wv * 512;
  bf16_t* lB = Bs + wv * 512;

  f32x4_t acc[4][4];
  #pragma unroll
  for (int i = 0; i < 4; ++i)
    #pragma unroll
    for (int j = 0; j < 4; ++j) acc[i][j] = (f32x4_t){0.f, 0.f, 0.f, 0.f};

  const int fm = lane & 15;
  const int kb = (lane >> 4) * 8;

  for (int k0 = 0; k0 < K; k0 += 32) {
    gl_lds16(ga0 + k0, lA);
    gl_lds16(ga1 + k0, lA + 2048);
    gl_lds16(gb0 + k0, lB);
    gl_lds16(gb1 + k0, lB + 2048);
    __syncthreads();
    bf16x8_t af[4], bfr[4];
    #pragma unroll
    for (int mi = 0; mi < 4; ++mi)
      af[mi] = *(const bf16x8_t*)(As + (wr + mi * 16 + fm) * 32 + kb);
    #pragma unroll
    for (int ni = 0; ni < 4; ++ni)
      bfr[ni] = *(const bf16x8_t*)(Bs + (wc + ni * 16 + fm) * 32 + kb);
    #pragma unroll
    for (int mi = 0; mi < 4; ++mi)
      #pragma unroll
      for (int ni = 0; ni < 4; ++ni)
        acc[mi][ni] = __builtin_amdgcn_mfma_f32_16x16x32_bf16(af[mi], bfr[ni],
                                                              acc[mi][ni], 0, 0, 0);
    __syncthreads();
  }

  const int r4 = (lane >> 4) * 4;
  #pragma unroll
  for (int ni = 0; ni < 4; ++ni) {
    const int col = col0 + wc + ni * 16 + fm;
    const float bv = bias[col];
    #pragma unroll
    for (int mi = 0; mi < 4; ++mi) {
      const int rb = row0 + wr + mi * 16 + r4;
      float v[4];
      #pragma unroll
      for (int r = 0; r < 4; ++r) v[r] = acc[mi][ni][r] + bv;
      if (!(mode & 4)) {
        #pragma unroll
        for (int r = 0; r < 4; ++r)
          if (rb + r < M) Cmat[(size_t)(rb + r) * N + col] = v[r];
      }
      if (mode & 1) {
        #pragma unroll
        for (int r = 0; r < 4; ++r)
          if (rb + r < M) Cbf[(size_t)(rb + r) * N + col] = (bf16_t)v[r];
      }
      if (mode & 2) {
        bf16x4_t o4 = {(bf16_t)v[0], (bf16_t)v[1], (bf16_t)v[2], (bf16_t)v[3]};
        size_t idx = ((size_t)(rb >> 9) * H_ + (size_t)(col >> 6)) * ((size_t)D_ * T_)
                   + (size_t)(col & 63) * T_ + (size_t)(rb & 511);
        *(bf16x4_t*)(Ctr + idx) = o4;
      }
    }
  }
}

// ---------------------------------------------------------------------------
// Generic fp32 GEMM (only the tiny M=8 cls projection now)
// ---------------------------------------------------------------------------
#define BM 64
#define BN 64
#define BK 16

__global__ __launch_bounds__(256) void gemm_bias(
    const float* __restrict__ A, const float* __restrict__ W,
    const float* __restrict__ bias, float* __restrict__ Cmat,
    int M, int K, int N)
{
  __shared__ float As[BK][BM + 4];
  __shared__ float Bs[BK][BN];
  const int tid  = threadIdx.x;
  const int row0 = blockIdx.y * BM;
  const int col0 = blockIdx.x * BN;
  const int m0 = (tid >> 4) << 2;
  const int n0 = (tid & 15) << 2;
  const int la_r = tid >> 2;
  const int la_k = (tid & 3) << 2;
  const int lb_k = tid >> 4;
  const int lb_n = (tid & 15) << 2;

  float acc[4][4] = {};

  for (int k0 = 0; k0 < K; k0 += BK) {
    float a0 = 0.f, a1 = 0.f, a2 = 0.f, a3 = 0.f;
    {
      int ar = row0 + la_r;
      int ak = k0 + la_k;
      if (ar < M) {
        const float* ap = A + (size_t)ar * K + ak;
        if (ak + 3 < K) {
          float4 t = *(const float4*)ap;
          a0 = t.x; a1 = t.y; a2 = t.z; a3 = t.w;
        } else {
          if (ak + 0 < K) a0 = ap[0];
          if (ak + 1 < K) a1 = ap[1];
          if (ak + 2 < K) a2 = ap[2];
          if (ak + 3 < K) a3 = ap[3];
        }
      }
    }
    As[la_k + 0][la_r] = a0;
    As[la_k + 1][la_r] = a1;
    As[la_k + 2][la_r] = a2;
    As[la_k + 3][la_r] = a3;
    {
      float4 bv = {0.f, 0.f, 0.f, 0.f};
      int bk = k0 + lb_k;
      int bn = col0 + lb_n;
      if (bk < K) {
        const float* bp = W + (size_t)bk * N + bn;
        if (bn + 3 < N) bv = *(const float4*)bp;
        else {
          if (bn + 0 < N) bv.x = bp[0];
          if (bn + 1 < N) bv.y = bp[1];
          if (bn + 2 < N) bv.z = bp[2];
          if (bn + 3 < N) bv.w = bp[3];
        }
      }
      *(float4*)&Bs[lb_k][lb_n] = bv;
    }
    __syncthreads();
    #pragma unroll
    for (int kk = 0; kk < BK; ++kk) {
      float4 av = *(const float4*)&As[kk][m0];
      float4 bv = *(const float4*)&Bs[kk][n0];
      float am[4] = {av.x, av.y, av.z, av.w};
      float bn4[4] = {bv.x, bv.y, bv.z, bv.w};
      #pragma unroll
      for (int i = 0; i < 4; ++i)
        #pragma unroll
        for (int j = 0; j < 4; ++j)
          acc[i][j] += am[i] * bn4[j];
    }
    __syncthreads();
  }

  if (col0 + n0 < N) {
    float4 b4 = *(const float4*)&bias[col0 + n0];
    #pragma unroll
    for (int i = 0; i < 4; ++i) {
      int r = row0 + m0 + i;
      if (r < M) {
        float4 o;
        o.x = acc[i][0] + b4.x;
        o.y = acc[i][1] + b4.y;
        o.z = acc[i][2] + b4.z;
        o.w = acc[i][3] + b4.w;
        *(float4*)&Cmat[(size_t)r * N + col0 + n0] = o;
      }
    }
  }
}

// ---------------------------------------------------------------------------
// MFMA flash self-attention (unchanged from round 3).
// ---------------------------------------------------------------------------
__global__ __launch_bounds__(256) void attn_mfma(
    const bf16_t* __restrict__ Qb, const bf16_t* __restrict__ Kb,
    const bf16_t* __restrict__ Vtg, const int* __restrict__ mask,
    bf16_t* __restrict__ yout /* (B,511,768) bf16 */)
{
  __shared__ bf16_t Ks[64 * 64];
  __shared__ bf16_t Vs[64 * 64];
  __shared__ bf16_t Pl[4][16 * 64];
  __shared__ float  fac_s[4][16];
  __shared__ float  l_s[4][16];
  __shared__ int    msk_s[64];

  const int b = blockIdx.z, h = blockIdx.y;
  const int qt0 = blockIdx.x * 64;
  const int tid = threadIdx.x;
  const int lane = tid & 63;
  const int w = tid >> 6;
  const int lq = lane & 15;
  const int g = lane >> 4;

  const int qi_frag = qt0 + w * 16 + lq;
  const int qtok = (qi_frag < TM1 ? qi_frag : TM1 - 1) + 1;
  bf16x8_t qf[2];
  {
    const bf16_t* qp = Qb + ((size_t)(b * T_) + qtok) * C_ + h * D_ + 8 * g;
    qf[0] = *(const bf16x8_t*)qp;
    qf[1] = *(const bf16x8_t*)(qp + 32);
  }

  const bf16_t* kbase = Kb + (size_t)(b * T_) * C_ + h * D_;
  const bf16_t* vbase = Vtg + ((size_t)(b * H_) + h) * ((size_t)D_ * T_);

  f32x4_t o[4];
  #pragma unroll
  for (int i = 0; i < 4; ++i) o[i] = (f32x4_t){0.f, 0.f, 0.f, 0.f};
  float m = -INFINITY, l = 0.f;

  for (int kt = 0; kt < T_; kt += 64) {
    #pragma unroll
    for (int i = 0; i < 2; ++i) {
      const int tp = tid + i * 256;
      const int kr = tp >> 3;
      const int sl = tp & 7;
      const int ss = sl ^ (kr & 7);
      gl_lds16(kbase + (size_t)(kt + kr) * C_ + 8 * ss,
               Ks + (size_t)(i * 4 + w) * 512);
      gl_lds16(vbase + (size_t)kr * T_ + kt + 8 * ss,
               Vs + (size_t)(i * 4 + w) * 512);
    }
    if (tid < 64) msk_s[tid] = mask[b * T_ + kt + tid];
    __syncthreads();

    f32x4_t st[4];
    #pragma unroll
    for (int t = 0; t < 4; ++t) {
      st[t] = (f32x4_t){0.f, 0.f, 0.f, 0.f};
      const int kk = t * 16 + lq;
      const bf16_t* krow = Ks + kk * 64;
      bf16x8_t kf0 = *(const bf16x8_t*)(krow + 8 * ((g)     ^ (kk & 7)));
      bf16x8_t kf1 = *(const bf16x8_t*)(krow + 8 * ((4 + g) ^ (kk & 7)));
      st[t] = __builtin_amdgcn_mfma_f32_16x16x32_bf16(kf0, qf[0], st[t], 0, 0, 0);
      st[t] = __builtin_amdgcn_mfma_f32_16x16x32_bf16(kf1, qf[1], st[t], 0, 0, 0);
    }

    float p[16];
    float mt = -INFINITY;
    #pragma unroll
    for (int t = 0; t < 4; ++t) {
      const int4 mk = *(const int4*)&msk_s[t * 16 + 4 * g];
      p[4*t+0] = mk.x ? st[t][0] * INV_ : NEG_;
      p[4*t+1] = mk.y ? st[t][1] * INV_ : NEG_;
      p[4*t+2] = mk.z ? st[t][2] * INV_ : NEG_;
      p[4*t+3] = mk.w ? st[t][3] * INV_ : NEG_;
      mt = fmaxf(mt, fmaxf(fmaxf(p[4*t], p[4*t+1]), fmaxf(p[4*t+2], p[4*t+3])));
    }
    mt = fmaxf(mt, __shfl_xor(mt, 16));
    mt = fmaxf(mt, __shfl_xor(mt, 32));
    const float mnew = fmaxf(m, mt);
    const float fac = __expf(m - mnew);
    float ps = 0.f;
    #pragma unroll
    for (int i = 0; i < 16; ++i) { p[i] = __expf(p[i] - mnew); ps += p[i]; }
    ps += __shfl_xor(ps, 16);
    ps += __shfl_xor(ps, 32);
    l = l * fac + ps;
    m = mnew;
    if (lane < 16) fac_s[w][lane] = fac;

    bf16_t* prow = Pl[w] + lq * 64;
    #pragma unroll
    for (int t = 0; t < 4; ++t) {
      bf16x4_t pb = {(bf16_t)p[4*t], (bf16_t)p[4*t+1],
                     (bf16_t)p[4*t+2], (bf16_t)p[4*t+3]};
      *(bf16x4_t*)(prow + 8 * ((2*t + (g >> 1)) ^ (lq & 7)) + 4 * (g & 1)) = pb;
    }
    bf16x8_t pa0 = *(const bf16x8_t*)(prow + 8 * ((g)     ^ (lq & 7)));
    bf16x8_t pa1 = *(const bf16x8_t*)(prow + 8 * ((4 + g) ^ (lq & 7)));

    const float4 fc = *(const float4*)&fac_s[w][4 * g];
    #pragma unroll
    for (int db = 0; db < 4; ++db) {
      const int dr = db * 16 + lq;
      const bf16_t* vrow = Vs + dr * 64;
      bf16x8_t vf0 = *(const bf16x8_t*)(vrow + 8 * ((g)     ^ (dr & 7)));
      bf16x8_t vf1 = *(const bf16x8_t*)(vrow + 8 * ((4 + g) ^ (dr & 7)));
      o[db][0] *= fc.x; o[db][1] *= fc.y; o[db][2] *= fc.z; o[db][3] *= fc.w;
      o[db] = __builtin_amdgcn_mfma_f32_16x16x32_bf16(pa0, vf0, o[db], 0, 0, 0);
      o[db] = __builtin_amdgcn_mfma_f32_16x16x32_bf16(pa1, vf1, o[db], 0, 0, 0);
    }
    __syncthreads();
  }

  if (lane < 16) l_s[w][lane] = l;
  const float4 lv = *(const float4*)&l_s[w][4 * g];
  const float rl0 = 1.f / lv.x, rl1 = 1.f / lv.y;
  const float rl2 = 1.f / lv.z, rl3 = 1.f / lv.w;
  const int qr0 = qt0 + w * 16 + 4 * g;
  #pragma unroll
  for (int db = 0; db < 4; ++db) {
    const int col = h * D_ + db * 16 + lq;
    bf16_t* yp = yout + ((size_t)(b * TM1) + qr0) * C_ + col;
    if (qr0 + 0 < TM1) yp[0 * (size_t)C_] = (bf16_t)(o[db][0] * rl0);
    if (qr0 + 1 < TM1) yp[1 * (size_t)C_] = (bf16_t)(o[db][1] * rl1);
    if (qr0 + 2 < TM1) yp[2 * (size_t)C_] = (bf16_t)(o[db][2] * rl2);
    if (qr0 + 3 < TM1) yp[3 * (size_t)C_] = (bf16_t)(o[db][3] * rl3);
  }
}

// ---------------------------------------------------------------------------
// cls attention (bf16 inputs, fp32 compute)
// ---------------------------------------------------------------------------
__global__ __launch_bounds__(64) void cls_attn(
    const bf16_t* __restrict__ Qb, const bf16_t* __restrict__ kcb,
    const bf16_t* __restrict__ Vb, const int* __restrict__ mask,
    float* __restrict__ yout /* (B,768) */)
{
  __shared__ float qs[64];
  __shared__ float Ks[64][65];
  __shared__ float Vs[64][65];
  __shared__ float Ps[64];

  const int b = blockIdx.x / H_, h = blockIdx.x % H_;
  const int lane = threadIdx.x;

  qs[lane] = (float)Qb[(size_t)(b * T_) * C_ + h * D_ + lane];
  __syncthreads();

  float m = -INFINITY, l = 0.f, acc = 0.f;
  for (int kt = 0; kt < T_; kt += 64) {
    for (int rr = 0; rr < 64; ++rr) {
      size_t gro = ((size_t)(b * T_) + kt + rr) * C_ + h * D_ + lane;
      Ks[rr][lane] = (float)kcb[gro];
      Vs[rr][lane] = (float)Vb[gro];
    }
    __syncthreads();
    float sc = 0.f;
    #pragma unroll
    for (int d = 0; d < 64; ++d) sc += qs[d] * Ks[lane][d];
    sc *= INV_;
    if (!mask[b * T_ + kt + lane]) sc = NEG_;
    float mt = sc;
    #pragma unroll
    for (int off = 32; off > 0; off >>= 1) mt = fmaxf(mt, __shfl_xor(mt, off));
    float mnew = fmaxf(m, mt);
    float e = __expf(sc - mnew);
    float ssum = e;
    #pragma unroll
    for (int off = 32; off > 0; off >>= 1) ssum += __shfl_xor(ssum, off);
    float fac = __expf(m - mnew);
    acc *= fac;
    l = l * fac + ssum;
    Ps[lane] = e;
    __syncthreads();
    #pragma unroll
    for (int j = 0; j < 64; ++j) acc += Ps[j] * Vs[j][lane];
    m = mnew;
    __syncthreads();
  }
  yout[(size_t)b * C_ + h * D_ + lane] = acc / l;
}

// ---------------------------------------------------------------------------
// Neighbour attention (bf16 inputs, fp32 compute, bf16 output).
// ---------------------------------------------------------------------------
__global__ __launch_bounds__(256) void neigh_attn(
    const bf16_t* __restrict__ Qb, const bf16_t* __restrict__ kcb,
    const bf16_t* __restrict__ Vb,
    const bf16_t* __restrict__ qn_r, const bf16_t* __restrict__ kn_r,
    const bf16_t* __restrict__ vn_r,
    int b0, bf16_t* __restrict__ outn /* (nb*511*5, 768) bf16 */)
{
  __shared__ float qs[KC5 * C_];
  __shared__ float ks[KC5 * C_];
  __shared__ float vs[KC5 * C_];
  __shared__ float Ps[H_ * 25];

  const int bt = blockIdx.x;
  const int bb = bt / TM1, t = bt % TM1;
  const int b = b0 + bb;
  const int tid = threadIdx.x;
  const size_t tok = (size_t)(b * T_) + t + 1;
  const size_t nrow = ((size_t)(bb * TM1) + t) * KN_;

  for (int idx = tid; idx < KC5 * C_ / 8; idx += 256) {
    int i = idx / (C_ / 8);
    int d8 = (idx % (C_ / 8)) * 8;
    const bf16_t *qp, *kp, *vp;
    if (i == 0) {
      qp = Qb + tok * C_ + d8;
      kp = kcb + tok * C_ + d8;
      vp = Vb + tok * C_ + d8;
    } else {
      size_t rr = (nrow + i - 1) * C_ + d8;
      qp = qn_r + rr; kp = kn_r + rr; vp = vn_r + rr;
    }
    bf16x8_t qv = *(const bf16x8_t*)qp;
    bf16x8_t kv = *(const bf16x8_t*)kp;
    bf16x8_t vv = *(const bf16x8_t*)vp;
    #pragma unroll
    for (int j = 0; j < 8; ++j) {
      qs[i * C_ + d8 + j] = (float)qv[j];
      ks[i * C_ + d8 + j] = (float)kv[j];
      vs[i * C_ + d8 + j] = (float)vv[j];
    }
  }
  __syncthreads();

  if (tid < H_ * KC5) {
    int h = tid / KC5, i = tid % KC5;
    float sc[KC5];
    #pragma unroll
    for (int j = 0; j < KC5; ++j) {
      float sum = 0.f;
      #pragma unroll
      for (int d = 0; d < D_; ++d)
        sum += qs[i * C_ + h * D_ + d] * ks[j * C_ + h * D_ + d];
      sc[j] = sum * INV_;
    }
    float mt = sc[0];
    #pragma unroll
    for (int j = 1; j < KC5; ++j) mt = fmaxf(mt, sc[j]);
    float e[KC5], ssum = 0.f;
    #pragma unroll
    for (int j = 0; j < KC5; ++j) { e[j] = __expf(sc[j] - mt); ssum += e[j]; }
    float rs = 1.f / ssum;
    #pragma unroll
    for (int j = 0; j < KC5; ++j) Ps[h * 25 + i * KC5 + j] = e[j] * rs;
  }
  __syncthreads();

  for (int idx = tid; idx < KC5 * C_; idx += 256) {
    int i = idx / C_, c = idx % C_;
    int h = c / D_;
    float sum = 0.f;
    #pragma unroll
    for (int j = 0; j < KC5; ++j)
      sum += Ps[h * 25 + i * KC5 + j] * vs[j * C_ + c];
    outn[(((size_t)(bb * TM1) + t) * KC5 + i) * C_ + c] = (bf16_t)sum;
  }
}

// ---------------------------------------------------------------------------
// Residual + LayerNorm combine kernels (bf16 projected inputs)
// ---------------------------------------------------------------------------
__device__ __forceinline__ void block_reduce2(float& s, float& ss, float* red) {
  #pragma unroll
  for (int off = 32; off > 0; off >>= 1) {
    s += __shfl_down(s, off);
    ss += __shfl_down(ss, off);
  }
  int wid = threadIdx.x >> 6;
  if ((threadIdx.x & 63) == 0) { red[wid * 2] = s; red[wid * 2 + 1] = ss; }
  __syncthreads();
  s  = red[0] + red[2] + red[4] + red[6];
  ss = red[1] + red[3] + red[5] + red[7];
}

__device__ __forceinline__ void ln_row(const float vals[3], float s, float ss,
                                       const float* __restrict__ g,
                                       const float* __restrict__ bb,
                                       float* __restrict__ orow, float* red) {
  block_reduce2(s, ss, red);
  float mean = s * (1.f / (float)C_);
  float var = ss * (1.f / (float)C_) - mean * mean;
  var = fmaxf(var, 0.f);
  float rs = rsqrtf(var + EPS_);
  #pragma unroll
  for (int ii = 0; ii < 3; ++ii) {
    int c = threadIdx.x + ii * 256;
    orow[c] = (vals[ii] - mean) * rs * g[c] + bb[c];
  }
}

__global__ __launch_bounds__(256) void combine_main(
    const bf16_t* __restrict__ yselfP, const bf16_t* __restrict__ poutn,
    const float* __restrict__ x, const float* __restrict__ g,
    const float* __restrict__ bln, int b0, float* __restrict__ dout)
{
  __shared__ float red[8];
  const int bt = blockIdx.x;
  const int bbb = bt / TM1, t = bt % TM1;
  const int b = b0 + bbb;
  const bf16_t* ys = yselfP + ((size_t)(b * TM1) + t) * C_;
  const bf16_t* pn = poutn + (((size_t)(bbb * TM1) + t) * KC5 + 0) * C_;
  const float* xr = x + ((size_t)(b * T_) + t + 1) * C_;
  float* orow = dout + ((size_t)(b * T_) + t + 1) * C_;
  float vals[3], s = 0.f, ss = 0.f;
  #pragma unroll
  for (int ii = 0; ii < 3; ++ii) {
    int c = threadIdx.x + ii * 256;
    float v = SCALE_ * (float)pn[c] + (1.f - SCALE_) * (float)ys[c] + xr[c];
    vals[ii] = v; s += v; ss += v * v;
  }
  ln_row(vals, s, ss, g, bln, orow, red);
}

__global__ __launch_bounds__(256) void combine_neigh(
    const bf16_t* __restrict__ poutn, const float* __restrict__ nrc,
    const float* __restrict__ g, const float* __restrict__ bln,
    int b0, float* __restrict__ dout)
{
  __shared__ float red[8];
  const int idx = blockIdx.x;
  const int i1 = idx % KN_;
  const int bt = idx / KN_;
  const int bbb = bt / TM1, t = bt % TM1;
  const int b = b0 + bbb;
  const bf16_t* pn = poutn + ((size_t)bt * KC5 + 1 + i1) * C_;
  const float* nr = nrc + ((size_t)bt * KN_ + i1) * C_;
  float* orow = dout + (((size_t)(b * TM1) + t) * KN_ + i1) * C_;
  float vals[3], s = 0.f, ss = 0.f;
  #pragma unroll
  for (int ii = 0; ii < 3; ++ii) {
    int c = threadIdx.x + ii * 256;
    float v = (float)pn[c] + nr[c];
    vals[ii] = v; s += v; ss += v * v;
  }
  ln_row(vals, s, ss, g, bln, orow, red);
}

__global__ __launch_bounds__(256) void combine_cls(
    const float* __restrict__ yclsP, const float* __restrict__ x,
    const float* __restrict__ g, const float* __restrict__ bln,
    float* __restrict__ dout)
{
  __shared__ float red[8];
  const int b = blockIdx.x;
  const float* yc = yclsP + (size_t)b * C_;
  const float* xr = x + (size_t)(b * T_) * C_;
  float* orow = dout + (size_t)(b * T_) * C_;
  float vals[3], s = 0.f, ss = 0.f;
  #pragma unroll
  for (int ii = 0; ii < 3; ++ii) {
    int c = threadIdx.x + ii * 256;
    float v = yc[c] + xr[c];
    vals[ii] = v; s += v; ss += v * v;
  }
  ln_row(vals, s, ss, g, bln, orow, red);
}

// ---------------------------------------------------------------------------
extern "C" void kernel_launch(void* const* d_in, const int* in_sizes, int n_in,
                              void* d_out, int out_size, void* d_ws, size_t ws_size,
                              hipStream_t stream) {
  (void)in_sizes; (void)n_in; (void)out_size;
  const float* x    = (const float*)d_in[0];
  const int*   mask = (const int*)d_in[1];
  const float* nrep = (const float*)d_in[2];
  const float* Wq = (const float*)d_in[3];  const float* bq = (const float*)d_in[4];
  const float* Wk = (const float*)d_in[5];  const float* bk = (const float*)d_in[6];
  const float* Wv = (const float*)d_in[7];  const float* bv = (const float*)d_in[8];
  const float* Wp = (const float*)d_in[9];  const float* bp = (const float*)d_in[10];
  const float* Wd = (const float*)d_in[11]; const float* bd = (const float*)d_in[12];
  const float* Wu = (const float*)d_in[13]; const float* bu = (const float*)d_in[14];
  const float* lng = (const float*)d_in[15];
  const float* lnb = (const float*)d_in[16];
  float* dout = (float*)d_out;
  const size_t OUT1 = (size_t)B_ * T_ * C_;

  char* ws = (char*)d_ws;
  size_t off = 0;
  auto alloc = [&](size_t bytes) -> void* {
    void* p = ws + off; off += (bytes + 255) & ~(size_t)255; return p;
  };
  const size_t NT = (size_t)B_ * T_;
  const size_t NR = (size_t)B_ * TM1 * KN_;

  bf16_t* xbf  = (bf16_t*)alloc(NT * C_ * 2);
  bf16_t* nrbf = (bf16_t*)alloc(NR * C_ * 2);
  bf16_t* Wtq  = (bf16_t*)alloc((size_t)C_ * C_ * 2);
  bf16_t* Wtk  = (bf16_t*)alloc((size_t)C_ * C_ * 2);
  bf16_t* Wtv  = (bf16_t*)alloc((size_t)C_ * C_ * 2);
  bf16_t* Wtp  = (bf16_t*)alloc((size_t)C_ * C_ * 2);
  bf16_t* Wtdu = (bf16_t*)alloc((size_t)C_ * C_ * 2);
  float*  bdu  = (float*)alloc((size_t)C_ * 4);
  bf16_t* Qb  = (bf16_t*)alloc(NT * C_ * 2);
  bf16_t* Kbf = (bf16_t*)alloc(NT * C_ * 2);
  bf16_t* Vb  = (bf16_t*)alloc(NT * C_ * 2);
  bf16_t* Vtg = (bf16_t*)alloc(NT * C_ * 2);   // [b][h][d][T]
  bf16_t* kcb = (bf16_t*)alloc(NT * C_ * 2);
  bf16_t* ysh = (bf16_t*)alloc((size_t)B_ * TM1 * C_ * 2);
  bf16_t* yspb = (bf16_t*)alloc((size_t)B_ * TM1 * C_ * 2);
  float* ych = (float*)alloc((size_t)B_ * C_ * 4);
  float* ycp = (float*)alloc((size_t)B_ * C_ * 4);
  const size_t fixed = off;
  // per-batch chunk bytes: qnb,vnb,knb + outn + poutnb (all bf16)
  const size_t perb = (size_t)TM1 * KN_ * C_ * 2 * 3
                    + (size_t)TM1 * KC5 * C_ * 2 * 2 + 5 * 256;
  int nb = 1;
  for (int cand : {8, 4, 2, 1}) {
    if (fixed + perb * (size_t)cand <= ws_size) { nb = cand; break; }
  }
  bf16_t* qnb    = (bf16_t*)alloc((size_t)nb * TM1 * KN_ * C_ * 2);
  bf16_t* vnb    = (bf16_t*)alloc((size_t)nb * TM1 * KN_ * C_ * 2);
  bf16_t* knb    = (bf16_t*)alloc((size_t)nb * TM1 * KN_ * C_ * 2);
  bf16_t* outn   = (bf16_t*)alloc((size_t)nb * TM1 * KC5 * C_ * 2);
  bf16_t* poutnb = (bf16_t*)alloc((size_t)nb * TM1 * KC5 * C_ * 2);

  dim3 blk(256);
  auto g2 = [](int M, int N) { return dim3((N + BN - 1) / BN, (M + BM - 1) / BM); };
  auto gm = [](int M) { return dim3(C_ / 128, (M + 127) / 128); };

  // conversions + weight prep
  cvt_bf16<<<1024, blk, 0, stream>>>(x, xbf, (long)(NT * C_));
  cvt_bf16<<<2048, blk, 0, stream>>>(nrep, nrbf, (long)(NR * C_));
  dim3 tg(C_ / 32, C_ / 32);
  wtrans<<<tg, blk, 0, stream>>>(Wq, Wtq);
  wtrans<<<tg, blk, 0, stream>>>(Wk, Wtk);
  wtrans<<<tg, blk, 0, stream>>>(Wv, Wtv);
  wtrans<<<tg, blk, 0, stream>>>(Wp, Wtp);
  wfuse<<<(C_ * C_) / 256, blk, 0, stream>>>(Wd, Wu, bd, bu, Wtdu, bdu);

  // projections: Q,K (bf16), V (bf16 linear + transposed), kc (fused low-rank)
  gemm_mfma<<<gm((int)NT), blk, 0, stream>>>(xbf, Wtq, bq, nullptr, Qb, nullptr, 5,
                                             (int)NT, C_, C_);
  gemm_mfma<<<gm((int)NT), blk, 0, stream>>>(xbf, Wtk, bk, nullptr, Kbf, nullptr, 5,
                                             (int)NT, C_, C_);
  gemm_mfma<<<gm((int)NT), blk, 0, stream>>>(xbf, Wtv, bv, nullptr, Vb, Vtg, 7,
                                             (int)NT, C_, C_);
  gemm_mfma<<<gm((int)NT), blk, 0, stream>>>(xbf, Wtdu, bdu, nullptr, kcb, nullptr, 5,
                                             (int)NT, C_, C_);

  // MFMA flash self-attention + projection (bf16 out)
  attn_mfma<<<dim3(8, H_, B_), blk, 0, stream>>>(Qb, Kbf, Vtg, mask, ysh);
  gemm_mfma<<<gm(B_ * TM1), blk, 0, stream>>>(ysh, Wtp, bp, nullptr, yspb, nullptr, 5,
                                              B_ * TM1, C_, C_);

  // cls attention + projection + combine
  cls_attn<<<B_ * H_, 64, 0, stream>>>(Qb, kcb, Vb, mask, ych);
  gemm_bias<<<g2(B_, C_), blk, 0, stream>>>(ych, Wp, bp, ycp, B_, C_, C_);
  combine_cls<<<B_, blk, 0, stream>>>(ycp, x, lng, lnb, dout);

  // neighbour pipeline, chunked over b
  for (int b0 = 0; b0 < B_; b0 += nb) {
    const int Mn = nb * TM1 * KN_;
    const int Mo = nb * TM1 * KC5;
    const float*  nrc   = nrep + (size_t)b0 * TM1 * KN_ * C_;
    const bf16_t* nrcbf = nrbf + (size_t)b0 * TM1 * KN_ * C_;
    gemm_mfma<<<gm(Mn), blk, 0, stream>>>(nrcbf, Wtq, bq, nullptr, qnb, nullptr, 5,
                                          Mn, C_, C_);
    gemm_mfma<<<gm(Mn), blk, 0, stream>>>(nrcbf, Wtv, bv, nullptr, vnb, nullptr, 5,
                                          Mn, C_, C_);
    gemm_mfma<<<gm(Mn), blk, 0, stream>>>(nrcbf, Wtdu, bdu, nullptr, knb, nullptr, 5,
                                          Mn, C_, C_);
    neigh_attn<<<nb * TM1, blk, 0, stream>>>(Qb, kcb, Vb, qnb, knb, vnb, b0, outn);
    gemm_mfma<<<gm(Mo), blk, 0, stream>>>(outn, Wtp, bp, nullptr, poutnb, nullptr, 5,
                                          Mo, C_, C_);
    combine_main<<<nb * TM1, blk, 0, stream>>>(yspb, poutnb, x, lng, lnb, b0, dout);
    combine_neigh<<<nb * TM1 * KN_, blk, 0, stream>>>(poutnb, nrc, lng, lnb, b0,
                                                      dout + OUT1);
  }
}

// Round 5
// 489.284 us; speedup vs baseline: 3.8725x; 1.1191x over previous
//
#include <hip/hip_runtime.h>
#include <math.h>

#define C_    768
#define H_    12
#define D_    64
#define B_    8
#define T_    512
#define TM1   511
#define R_    8
#define KN_   4
#define KC5   5
#define SCALE_ 0.5f
#define EPS_  1e-12f
#define NEG_  -1000000000.0f
#define INV_  0.125f   /* 1/sqrt(64) */
#define LDQ   2304     /* row stride of fused QKV output */

typedef __bf16 bf16_t;
typedef __bf16 bf16x4_t __attribute__((ext_vector_type(4)));
typedef __bf16 bf16x8_t __attribute__((ext_vector_type(8)));
typedef float  f32x4_t  __attribute__((ext_vector_type(4)));
typedef const void __attribute__((address_space(1)))* gas_t;
typedef void       __attribute__((address_space(3)))* las_t;

__device__ __forceinline__ void gl_lds16(const bf16_t* g, bf16_t* l) {
  __builtin_amdgcn_global_load_lds((gas_t)g, (las_t)l, 16, 0, 0);
}

// ---------------------------------------------------------------------------
// fp32 -> bf16 flat convert (n % 4 == 0)
// ---------------------------------------------------------------------------
__global__ __launch_bounds__(256) void cvt_bf16(const float* __restrict__ in,
                                                bf16_t* __restrict__ out, long n) {
  long i = ((long)blockIdx.x * 256 + threadIdx.x) * 4;
  const long stride = (long)gridDim.x * 256 * 4;
  for (; i < n; i += stride) {
    float4 v = *(const float4*)(in + i);
    bf16x4_t o = { (bf16_t)v.x, (bf16_t)v.y, (bf16_t)v.z, (bf16_t)v.w };
    *(bf16x4_t*)(out + i) = o;
  }
}

// ---------------------------------------------------------------------------
// Weight transpose + convert: Wt[n][k] = (bf16) W[k][n], 768x768.
// ---------------------------------------------------------------------------
__global__ __launch_bounds__(256) void wtrans(const float* __restrict__ W,
                                              bf16_t* __restrict__ Wt) {
  __shared__ float tile[32][33];
  const int n0 = blockIdx.x * 32, k0 = blockIdx.y * 32;
  const int tx = threadIdx.x & 31, ty = threadIdx.x >> 5;
  #pragma unroll
  for (int r = ty; r < 32; r += 8)
    tile[r][tx] = W[(size_t)(k0 + r) * C_ + n0 + tx];
  __syncthreads();
  #pragma unroll
  for (int r = ty; r < 32; r += 8)
    Wt[(size_t)(n0 + r) * C_ + k0 + tx] = (bf16_t)tile[tx][r];
}

// ---------------------------------------------------------------------------
// Wqp[n=256][k=768]: per-head low-rank projection weight.
// n = h*16+r : r<8 -> Wu[r][k] (k in head h), r==8 -> bu[k], else 0.
// ---------------------------------------------------------------------------
__global__ __launch_bounds__(256) void build_wqp(
    const float* __restrict__ Wu, const float* __restrict__ bu,
    bf16_t* __restrict__ Wqp) {
  int idx = blockIdx.x * 256 + threadIdx.x;   // 256*768
  int n = idx / C_, k = idx % C_;
  int h = n >> 4, r = n & 15;
  float v = 0.f;
  if (h < H_ && (k >> 6) == h) {
    if (r < 8) v = Wu[r * C_ + k];
    else if (r == 8) v = bu[k];
  }
  Wqp[idx] = (bf16_t)v;
}

// WdT[r][k] = Wd[k][r]
__global__ __launch_bounds__(256) void build_wdt(const float* __restrict__ Wd,
                                                 float* __restrict__ WdT) {
  int idx = blockIdx.x * 256 + threadIdx.x;   // 8*768
  if (idx < R_ * C_) {
    int r = idx / C_, k = idx % C_;
    WdT[idx] = Wd[k * R_ + r];
  }
}

// bias concat (3 x 768)
__global__ __launch_bounds__(256) void cat3(const float* __restrict__ a,
                                            const float* __restrict__ b,
                                            const float* __restrict__ c,
                                            float* __restrict__ o) {
  int i = blockIdx.x * 256 + threadIdx.x;   // < 2304
  const float* s = (i < 768) ? a : (i < 1536 ? b : c);
  o[i] = s[i % 768];
}

// ---------------------------------------------------------------------------
// bf16 MFMA GEMM with lda/ldc strides and bijective XCD swizzle.
// mode bit0: write bf16 Cbf; bit1: also write transposed copy of cols
// [trcol0, trcol0+768) into Ctr laid out [b][h][d=64][T=512] (needs M%512==0).
// ---------------------------------------------------------------------------
__global__ __launch_bounds__(256) void gemm_mfma(
    const bf16_t* __restrict__ A, int lda,
    const bf16_t* __restrict__ Bt,
    const float* __restrict__ bias,
    bf16_t* __restrict__ Cbf, int ldc,
    bf16_t* __restrict__ Ctr, int trcol0, int mode,
    int M, int K, int N)
{
  __shared__ bf16_t As[128 * 32];
  __shared__ bf16_t Bs[128 * 32];
  const int gx = gridDim.x;
  int lid = blockIdx.y * gx + blockIdx.x;
  {
    const int nwg = gx * gridDim.y;
    const int q0 = nwg >> 3, r0 = nwg & 7;
    const int xcd = lid & 7, idx = lid >> 3;
    lid = (xcd < r0 ? xcd * (q0 + 1) : r0 * (q0 + 1) + (xcd - r0) * q0) + idx;
  }
  const int row0 = (lid / gx) * 128;
  const int col0 = (lid % gx) * 128;

  const int tid = threadIdx.x;
  const int lane = tid & 63;
  const int wv = tid >> 6;
  const int wr = (wv >> 1) * 64;
  const int wc = (wv & 1) * 64;
  const int sr = tid >> 2;
  const int sk = (tid & 3) * 8;

  int ra0 = row0 + sr;       if (ra0 > M - 1) ra0 = M - 1;
  int ra1 = row0 + 64 + sr;  if (ra1 > M - 1) ra1 = M - 1;
  const bf16_t* ga0 = A + (size_t)ra0 * lda + sk;
  const bf16_t* ga1 = A + (size_t)ra1 * lda + sk;
  const bf16_t* gb0 = Bt + (size_t)(col0 + sr) * K + sk;
  const bf16_t* gb1 = Bt + (size_t)(col0 + 64 + sr) * K + sk;
  bf16_t* lA = As + wv * 512;
  bf16_t* lB = Bs + wv * 512;

  f32x4_t acc[4][4];
  #pragma unroll
  for (int i = 0; i < 4; ++i)
    #pragma unroll
    for (int j = 0; j < 4; ++j) acc[i][j] = (f32x4_t){0.f, 0.f, 0.f, 0.f};

  const int fm = lane & 15;
  const int kb = (lane >> 4) * 8;

  for (int k0 = 0; k0 < K; k0 += 32) {
    gl_lds16(ga0 + k0, lA);
    gl_lds16(ga1 + k0, lA + 2048);
    gl_lds16(gb0 + k0, lB);
    gl_lds16(gb1 + k0, lB + 2048);
    __syncthreads();
    bf16x8_t af[4], bfr[4];
    #pragma unroll
    for (int mi = 0; mi < 4; ++mi)
      af[mi] = *(const bf16x8_t*)(As + (wr + mi * 16 + fm) * 32 + kb);
    #pragma unroll
    for (int ni = 0; ni < 4; ++ni)
      bfr[ni] = *(const bf16x8_t*)(Bs + (wc + ni * 16 + fm) * 32 + kb);
    #pragma unroll
    for (int mi = 0; mi < 4; ++mi)
      #pragma unroll
      for (int ni = 0; ni < 4; ++ni)
        acc[mi][ni] = __builtin_amdgcn_mfma_f32_16x16x32_bf16(af[mi], bfr[ni],
                                                              acc[mi][ni], 0, 0, 0);
    __syncthreads();
  }

  const int r4 = (lane >> 4) * 4;
  #pragma unroll
  for (int ni = 0; ni < 4; ++ni) {
    const int col = col0 + wc + ni * 16 + fm;
    const float bv = bias[col];
    #pragma unroll
    for (int mi = 0; mi < 4; ++mi) {
      const int rb = row0 + wr + mi * 16 + r4;
      float v[4];
      #pragma unroll
      for (int r = 0; r < 4; ++r) v[r] = acc[mi][ni][r] + bv;
      if (mode & 1) {
        #pragma unroll
        for (int r = 0; r < 4; ++r)
          if (rb + r < M) Cbf[(size_t)(rb + r) * ldc + col] = (bf16_t)v[r];
      }
      if ((mode & 2) && (unsigned)(col - trcol0) < 768u) {
        const int vcol = col - trcol0;
        bf16x4_t o4 = {(bf16_t)v[0], (bf16_t)v[1], (bf16_t)v[2], (bf16_t)v[3]};
        size_t idx = ((size_t)(rb >> 9) * H_ + (size_t)(vcol >> 6)) * ((size_t)D_ * T_)
                   + (size_t)(vcol & 63) * T_ + (size_t)(rb & 511);
        *(bf16x4_t*)(Ctr + idx) = o4;
      }
    }
  }
}

// ---------------------------------------------------------------------------
// Narrow GEMV: out[M][8] = A(bf16,[M][768]) @ WdT^T + bd.  thread = (row, r).
// ---------------------------------------------------------------------------
__global__ __launch_bounds__(256) void gemv8(
    const bf16_t* __restrict__ A, const float* __restrict__ WdT,
    const float* __restrict__ bd, float* __restrict__ out, int M)
{
  int row = blockIdx.x * 32 + (threadIdx.x >> 3);
  int r = threadIdx.x & 7;
  if (row >= M) return;
  const bf16_t* ar = A + (size_t)row * C_;
  const float* wr = WdT + r * C_;
  float acc = 0.f;
  for (int k = 0; k < C_; k += 8) {
    bf16x8_t av = *(const bf16x8_t*)(ar + k);
    float4 w0 = *(const float4*)(wr + k);
    float4 w1 = *(const float4*)(wr + k + 4);
    acc += (float)av[0]*w0.x + (float)av[1]*w0.y + (float)av[2]*w0.z + (float)av[3]*w0.w
         + (float)av[4]*w1.x + (float)av[5]*w1.y + (float)av[6]*w1.z + (float)av[7]*w1.w;
  }
  out[(size_t)row * R_ + r] = acc + bd[r];
}

// ---------------------------------------------------------------------------
// Small dense projection for the 8 cls rows: out[8][768] = A @ W + bias.
// grid = 8 rows * 3 col-chunks.
// ---------------------------------------------------------------------------
__global__ __launch_bounds__(256) void gemv_cls(
    const float* __restrict__ A, const float* __restrict__ W,
    const float* __restrict__ bias, float* __restrict__ out)
{
  __shared__ float as[C_];
  const int row = blockIdx.x / 3;
  const int c = (blockIdx.x % 3) * 256 + threadIdx.x;
  for (int i = threadIdx.x; i < C_; i += 256) as[i] = A[(size_t)row * C_ + i];
  __syncthreads();
  float acc = bias[c];
  for (int k = 0; k < C_; ++k) acc += as[k] * W[(size_t)k * C_ + c];
  out[(size_t)row * C_ + c] = acc;
}

// ---------------------------------------------------------------------------
// MFMA flash self-attention; Q/K read from fused QKVc (stride LDQ).
// ---------------------------------------------------------------------------
__global__ __launch_bounds__(256) void attn_mfma(
    const bf16_t* __restrict__ QKVc, const bf16_t* __restrict__ Vtg,
    const int* __restrict__ mask, bf16_t* __restrict__ yout)
{
  __shared__ bf16_t Ks[64 * 64];
  __shared__ bf16_t Vs[64 * 64];
  __shared__ bf16_t Pl[4][16 * 64];
  __shared__ float  fac_s[4][16];
  __shared__ float  l_s[4][16];
  __shared__ int    msk_s[64];

  const int b = blockIdx.z, h = blockIdx.y;
  const int qt0 = blockIdx.x * 64;
  const int tid = threadIdx.x;
  const int lane = tid & 63;
  const int w = tid >> 6;
  const int lq = lane & 15;
  const int g = lane >> 4;

  const int qi_frag = qt0 + w * 16 + lq;
  const int qtok = (qi_frag < TM1 ? qi_frag : TM1 - 1) + 1;
  bf16x8_t qf[2];
  {
    const bf16_t* qp = QKVc + ((size_t)(b * T_) + qtok) * LDQ + h * D_ + 8 * g;
    qf[0] = *(const bf16x8_t*)qp;
    qf[1] = *(const bf16x8_t*)(qp + 32);
  }

  const bf16_t* kbase = QKVc + (size_t)(b * T_) * LDQ + 768 + h * D_;
  const bf16_t* vbase = Vtg + ((size_t)(b * H_) + h) * ((size_t)D_ * T_);

  f32x4_t o[4];
  #pragma unroll
  for (int i = 0; i < 4; ++i) o[i] = (f32x4_t){0.f, 0.f, 0.f, 0.f};
  float m = -INFINITY, l = 0.f;

  for (int kt = 0; kt < T_; kt += 64) {
    #pragma unroll
    for (int i = 0; i < 2; ++i) {
      const int tp = tid + i * 256;
      const int kr = tp >> 3;
      const int sl = tp & 7;
      const int ss = sl ^ (kr & 7);
      gl_lds16(kbase + (size_t)(kt + kr) * LDQ + 8 * ss,
               Ks + (size_t)(i * 4 + w) * 512);
      gl_lds16(vbase + (size_t)kr * T_ + kt + 8 * ss,
               Vs + (size_t)(i * 4 + w) * 512);
    }
    if (tid < 64) msk_s[tid] = mask[b * T_ + kt + tid];
    __syncthreads();

    f32x4_t st[4];
    #pragma unroll
    for (int t = 0; t < 4; ++t) {
      st[t] = (f32x4_t){0.f, 0.f, 0.f, 0.f};
      const int kk = t * 16 + lq;
      const bf16_t* krow = Ks + kk * 64;
      bf16x8_t kf0 = *(const bf16x8_t*)(krow + 8 * ((g)     ^ (kk & 7)));
      bf16x8_t kf1 = *(const bf16x8_t*)(krow + 8 * ((4 + g) ^ (kk & 7)));
      st[t] = __builtin_amdgcn_mfma_f32_16x16x32_bf16(kf0, qf[0], st[t], 0, 0, 0);
      st[t] = __builtin_amdgcn_mfma_f32_16x16x32_bf16(kf1, qf[1], st[t], 0, 0, 0);
    }

    float p[16];
    float mt = -INFINITY;
    #pragma unroll
    for (int t = 0; t < 4; ++t) {
      const int4 mk = *(const int4*)&msk_s[t * 16 + 4 * g];
      p[4*t+0] = mk.x ? st[t][0] * INV_ : NEG_;
      p[4*t+1] = mk.y ? st[t][1] * INV_ : NEG_;
      p[4*t+2] = mk.z ? st[t][2] * INV_ : NEG_;
      p[4*t+3] = mk.w ? st[t][3] * INV_ : NEG_;
      mt = fmaxf(mt, fmaxf(fmaxf(p[4*t], p[4*t+1]), fmaxf(p[4*t+2], p[4*t+3])));
    }
    mt = fmaxf(mt, __shfl_xor(mt, 16));
    mt = fmaxf(mt, __shfl_xor(mt, 32));
    const float mnew = fmaxf(m, mt);
    const float fac = __expf(m - mnew);
    float ps = 0.f;
    #pragma unroll
    for (int i = 0; i < 16; ++i) { p[i] = __expf(p[i] - mnew); ps += p[i]; }
    ps += __shfl_xor(ps, 16);
    ps += __shfl_xor(ps, 32);
    l = l * fac + ps;
    m = mnew;
    if (lane < 16) fac_s[w][lane] = fac;

    bf16_t* prow = Pl[w] + lq * 64;
    #pragma unroll
    for (int t = 0; t < 4; ++t) {
      bf16x4_t pb = {(bf16_t)p[4*t], (bf16_t)p[4*t+1],
                     (bf16_t)p[4*t+2], (bf16_t)p[4*t+3]};
      *(bf16x4_t*)(prow + 8 * ((2*t + (g >> 1)) ^ (lq & 7)) + 4 * (g & 1)) = pb;
    }
    bf16x8_t pa0 = *(const bf16x8_t*)(prow + 8 * ((g)     ^ (lq & 7)));
    bf16x8_t pa1 = *(const bf16x8_t*)(prow + 8 * ((4 + g) ^ (lq & 7)));

    const float4 fc = *(const float4*)&fac_s[w][4 * g];
    #pragma unroll
    for (int db = 0; db < 4; ++db) {
      const int dr = db * 16 + lq;
      const bf16_t* vrow = Vs + dr * 64;
      bf16x8_t vf0 = *(const bf16x8_t*)(vrow + 8 * ((g)     ^ (dr & 7)));
      bf16x8_t vf1 = *(const bf16x8_t*)(vrow + 8 * ((4 + g) ^ (dr & 7)));
      o[db][0] *= fc.x; o[db][1] *= fc.y; o[db][2] *= fc.z; o[db][3] *= fc.w;
      o[db] = __builtin_amdgcn_mfma_f32_16x16x32_bf16(pa0, vf0, o[db], 0, 0, 0);
      o[db] = __builtin_amdgcn_mfma_f32_16x16x32_bf16(pa1, vf1, o[db], 0, 0, 0);
    }
    __syncthreads();
  }

  if (lane < 16) l_s[w][lane] = l;
  const float4 lv = *(const float4*)&l_s[w][4 * g];
  const float rl0 = 1.f / lv.x, rl1 = 1.f / lv.y;
  const float rl2 = 1.f / lv.z, rl3 = 1.f / lv.w;
  const int qr0 = qt0 + w * 16 + 4 * g;
  #pragma unroll
  for (int db = 0; db < 4; ++db) {
    const int col = h * D_ + db * 16 + lq;
    bf16_t* yp = yout + ((size_t)(b * TM1) + qr0) * C_ + col;
    if (qr0 + 0 < TM1) yp[0 * (size_t)C_] = (bf16_t)(o[db][0] * rl0);
    if (qr0 + 1 < TM1) yp[1 * (size_t)C_] = (bf16_t)(o[db][1] * rl1);
    if (qr0 + 2 < TM1) yp[2 * (size_t)C_] = (bf16_t)(o[db][2] * rl2);
    if (qr0 + 3 < TM1) yp[3 * (size_t)C_] = (bf16_t)(o[db][3] * rl3);
  }
}

// ---------------------------------------------------------------------------
// cls attention via low-rank keys: score = dot8(qp, t1[key]) + qp[8].
// ---------------------------------------------------------------------------
__global__ __launch_bounds__(64) void cls_attn(
    const bf16_t* __restrict__ QKVc, const bf16_t* __restrict__ qpx,
    const float* __restrict__ t1, const int* __restrict__ mask,
    float* __restrict__ yout /* (B,768) */)
{
  __shared__ float qp_s[16];
  __shared__ float Vs[64][65];
  __shared__ float Ps[64];

  const int b = blockIdx.x / H_, h = blockIdx.x % H_;
  const int lane = threadIdx.x;

  if (lane < 16) qp_s[lane] = (float)qpx[(size_t)(b * T_) * 256 + h * 16 + lane];
  __syncthreads();

  float m = -INFINITY, l = 0.f, acc = 0.f;
  for (int kt = 0; kt < T_; kt += 64) {
    for (int rr = 0; rr < 64; ++rr)
      Vs[rr][lane] = (float)QKVc[((size_t)(b * T_) + kt + rr) * LDQ + 1536 + h * D_ + lane];
    __syncthreads();
    const float* t1r = t1 + ((size_t)(b * T_) + kt + lane) * R_;
    float sc = qp_s[8];
    #pragma unroll
    for (int r = 0; r < 8; ++r) sc += qp_s[r] * t1r[r];
    sc *= INV_;
    if (!mask[b * T_ + kt + lane]) sc = NEG_;
    float mt = sc;
    #pragma unroll
    for (int off = 32; off > 0; off >>= 1) mt = fmaxf(mt, __shfl_xor(mt, off));
    float mnew = fmaxf(m, mt);
    float e = __expf(sc - mnew);
    float ssum = e;
    #pragma unroll
    for (int off = 32; off > 0; off >>= 1) ssum += __shfl_xor(ssum, off);
    float fac = __expf(m - mnew);
    acc *= fac;
    l = l * fac + ssum;
    Ps[lane] = e;
    __syncthreads();
    #pragma unroll
    for (int j = 0; j < 64; ++j) acc += Ps[j] * Vs[j][lane];
    m = mnew;
    __syncthreads();
  }
  yout[(size_t)b * C_ + h * D_ + lane] = acc / l;
}

// ---------------------------------------------------------------------------
// Neighbour attention via low-rank keys.  Per token: qp (5x192), t2 (5x8),
// V (5x768).  i=0 comes from QKVc/qpx/t1 at the token row.
// ---------------------------------------------------------------------------
__global__ __launch_bounds__(256) void neigh_attn(
    const bf16_t* __restrict__ QKVc, const float* __restrict__ t1,
    const bf16_t* __restrict__ qpx,
    const bf16_t* __restrict__ qvn,  /* [rows][1536] q|v */
    const float* __restrict__ t2,    /* [rows][8] */
    const bf16_t* __restrict__ qpn,  /* [rows][256] */
    int b0, bf16_t* __restrict__ outn)
{
  __shared__ float vs[KC5 * C_];
  __shared__ float qp_s[KC5][200];
  __shared__ float t2_s[KC5][8];
  __shared__ float Ps[H_ * 25];

  const int bt = blockIdx.x;
  const int bb = bt / TM1, t = bt % TM1;
  const int b = b0 + bb;
  const int tid = threadIdx.x;
  const size_t tok = (size_t)(b * T_) + t + 1;
  const size_t nrow = ((size_t)(bb * TM1) + t) * KN_;

  for (int idx = tid; idx < KC5 * 96; idx += 256) {
    int i = idx / 96, d8 = (idx % 96) * 8;
    const bf16_t* vp = (i == 0) ? QKVc + tok * LDQ + 1536 + d8
                                : qvn + (nrow + i - 1) * 1536 + 768 + d8;
    bf16x8_t vv = *(const bf16x8_t*)vp;
    #pragma unroll
    for (int j = 0; j < 8; ++j) vs[i * C_ + d8 + j] = (float)vv[j];
  }
  for (int idx = tid; idx < KC5 * 24; idx += 256) {
    int i = idx / 24, c8 = (idx % 24) * 8;
    const bf16_t* qpp = (i == 0) ? qpx + tok * 256 + c8
                                 : qpn + (nrow + i - 1) * 256 + c8;
    bf16x8_t qv = *(const bf16x8_t*)qpp;
    #pragma unroll
    for (int j = 0; j < 8; ++j) qp_s[i][c8 + j] = (float)qv[j];
  }
  if (tid < KC5 * 8) {
    int i = tid / 8, r = tid & 7;
    t2_s[i][r] = (i == 0) ? t1[tok * R_ + r] : t2[(nrow + i - 1) * R_ + r];
  }
  __syncthreads();

  if (tid < H_ * KC5) {
    int h = tid / KC5, i = tid % KC5;
    float sc[KC5];
    #pragma unroll
    for (int j = 0; j < KC5; ++j) {
      float s = qp_s[i][h * 16 + 8];
      #pragma unroll
      for (int r = 0; r < 8; ++r) s += qp_s[i][h * 16 + r] * t2_s[j][r];
      sc[j] = s * INV_;
    }
    float mt = sc[0];
    #pragma unroll
    for (int j = 1; j < KC5; ++j) mt = fmaxf(mt, sc[j]);
    float e[KC5], ssum = 0.f;
    #pragma unroll
    for (int j = 0; j < KC5; ++j) { e[j] = __expf(sc[j] - mt); ssum += e[j]; }
    float rs = 1.f / ssum;
    #pragma unroll
    for (int j = 0; j < KC5; ++j) Ps[h * 25 + i * KC5 + j] = e[j] * rs;
  }
  __syncthreads();

  for (int idx = tid; idx < KC5 * C_; idx += 256) {
    int i = idx / C_, c = idx % C_;
    int h = c / D_;
    float sum = 0.f;
    #pragma unroll
    for (int j = 0; j < KC5; ++j)
      sum += Ps[h * 25 + i * KC5 + j] * vs[j * C_ + c];
    outn[(((size_t)(bb * TM1) + t) * KC5 + i) * C_ + c] = (bf16_t)sum;
  }
}

// ---------------------------------------------------------------------------
// Residual + LayerNorm combine kernels
// ---------------------------------------------------------------------------
__device__ __forceinline__ void block_reduce2(float& s, float& ss, float* red) {
  #pragma unroll
  for (int off = 32; off > 0; off >>= 1) {
    s += __shfl_down(s, off);
    ss += __shfl_down(ss, off);
  }
  int wid = threadIdx.x >> 6;
  if ((threadIdx.x & 63) == 0) { red[wid * 2] = s; red[wid * 2 + 1] = ss; }
  __syncthreads();
  s  = red[0] + red[2] + red[4] + red[6];
  ss = red[1] + red[3] + red[5] + red[7];
}

__device__ __forceinline__ void ln_row(const float vals[3], float s, float ss,
                                       const float* __restrict__ g,
                                       const float* __restrict__ bb,
                                       float* __restrict__ orow, float* red) {
  block_reduce2(s, ss, red);
  float mean = s * (1.f / (float)C_);
  float var = ss * (1.f / (float)C_) - mean * mean;
  var = fmaxf(var, 0.f);
  float rs = rsqrtf(var + EPS_);
  #pragma unroll
  for (int ii = 0; ii < 3; ++ii) {
    int c = threadIdx.x + ii * 256;
    orow[c] = (vals[ii] - mean) * rs * g[c] + bb[c];
  }
}

__global__ __launch_bounds__(256) void combine_main(
    const bf16_t* __restrict__ yselfP, const bf16_t* __restrict__ poutn,
    const float* __restrict__ x, const float* __restrict__ g,
    const float* __restrict__ bln, int b0, float* __restrict__ dout)
{
  __shared__ float red[8];
  const int bt = blockIdx.x;
  const int bbb = bt / TM1, t = bt % TM1;
  const int b = b0 + bbb;
  const bf16_t* ys = yselfP + ((size_t)(b * TM1) + t) * C_;
  const bf16_t* pn = poutn + (((size_t)(bbb * TM1) + t) * KC5 + 0) * C_;
  const float* xr = x + ((size_t)(b * T_) + t + 1) * C_;
  float* orow = dout + ((size_t)(b * T_) + t + 1) * C_;
  float vals[3], s = 0.f, ss = 0.f;
  #pragma unroll
  for (int ii = 0; ii < 3; ++ii) {
    int c = threadIdx.x + ii * 256;
    float v = SCALE_ * (float)pn[c] + (1.f - SCALE_) * (float)ys[c] + xr[c];
    vals[ii] = v; s += v; ss += v * v;
  }
  ln_row(vals, s, ss, g, bln, orow, red);
}

__global__ __launch_bounds__(256) void combine_neigh(
    const bf16_t* __restrict__ poutn, const float* __restrict__ nrc,
    const float* __restrict__ g, const float* __restrict__ bln,
    int b0, float* __restrict__ dout)
{
  __shared__ float red[8];
  const int idx = blockIdx.x;
  const int i1 = idx % KN_;
  const int bt = idx / KN_;
  const int bbb = bt / TM1, t = bt % TM1;
  const int b = b0 + bbb;
  const bf16_t* pn = poutn + ((size_t)bt * KC5 + 1 + i1) * C_;
  const float* nr = nrc + ((size_t)bt * KN_ + i1) * C_;
  float* orow = dout + (((size_t)(b * TM1) + t) * KN_ + i1) * C_;
  float vals[3], s = 0.f, ss = 0.f;
  #pragma unroll
  for (int ii = 0; ii < 3; ++ii) {
    int c = threadIdx.x + ii * 256;
    float v = (float)pn[c] + nr[c];
    vals[ii] = v; s += v; ss += v * v;
  }
  ln_row(vals, s, ss, g, bln, orow, red);
}

__global__ __launch_bounds__(256) void combine_cls(
    const float* __restrict__ yclsP, const float* __restrict__ x,
    const float* __restrict__ g, const float* __restrict__ bln,
    float* __restrict__ dout)
{
  __shared__ float red[8];
  const int b = blockIdx.x;
  const float* yc = yclsP + (size_t)b * C_;
  const float* xr = x + (size_t)(b * T_) * C_;
  float* orow = dout + (size_t)(b * T_) * C_;
  float vals[3], s = 0.f, ss = 0.f;
  #pragma unroll
  for (int ii = 0; ii < 3; ++ii) {
    int c = threadIdx.x + ii * 256;
    float v = yc[c] + xr[c];
    vals[ii] = v; s += v; ss += v * v;
  }
  ln_row(vals, s, ss, g, bln, orow, red);
}

// ---------------------------------------------------------------------------
extern "C" void kernel_launch(void* const* d_in, const int* in_sizes, int n_in,
                              void* d_out, int out_size, void* d_ws, size_t ws_size,
                              hipStream_t stream) {
  (void)in_sizes; (void)n_in; (void)out_size;
  const float* x    = (const float*)d_in[0];
  const int*   mask = (const int*)d_in[1];
  const float* nrep = (const float*)d_in[2];
  const float* Wq = (const float*)d_in[3];  const float* bq = (const float*)d_in[4];
  const float* Wk = (const float*)d_in[5];  const float* bk = (const float*)d_in[6];
  const float* Wv = (const float*)d_in[7];  const float* bv = (const float*)d_in[8];
  const float* Wp = (const float*)d_in[9];  const float* bp = (const float*)d_in[10];
  const float* Wd = (const float*)d_in[11]; const float* bd = (const float*)d_in[12];
  const float* Wu = (const float*)d_in[13]; const float* bu = (const float*)d_in[14];
  const float* lng = (const float*)d_in[15];
  const float* lnb = (const float*)d_in[16];
  float* dout = (float*)d_out;
  const size_t OUT1 = (size_t)B_ * T_ * C_;

  char* ws = (char*)d_ws;
  size_t off = 0;
  auto alloc = [&](size_t bytes) -> void* {
    void* p = ws + off; off += (bytes + 255) & ~(size_t)255; return p;
  };
  const size_t NT = (size_t)B_ * T_;
  const size_t NR = (size_t)B_ * TM1 * KN_;

  bf16_t* xbf   = (bf16_t*)alloc(NT * C_ * 2);
  bf16_t* nrbf  = (bf16_t*)alloc(NR * C_ * 2);
  bf16_t* Wcat  = (bf16_t*)alloc((size_t)3 * C_ * C_ * 2);   // Q|K|V, [2304][768]
  bf16_t* Wcat2 = (bf16_t*)alloc((size_t)2 * C_ * C_ * 2);   // Q|V, [1536][768]
  bf16_t* Wtp   = (bf16_t*)alloc((size_t)C_ * C_ * 2);
  bf16_t* Wqp   = (bf16_t*)alloc((size_t)256 * C_ * 2);
  float*  WdT   = (float*)alloc((size_t)R_ * C_ * 4);
  float*  bcat  = (float*)alloc(2304 * 4);
  float*  bcat2 = (float*)alloc(2304 * 4);
  float*  zbias = (float*)alloc(256 * 4);
  bf16_t* QKVc  = (bf16_t*)alloc(NT * LDQ * 2);
  bf16_t* Vtg   = (bf16_t*)alloc(NT * C_ * 2);   // [b][h][d][T]
  bf16_t* qpx   = (bf16_t*)alloc(NT * 256 * 2);
  float*  t1    = (float*)alloc(NT * R_ * 4);
  bf16_t* ysh   = (bf16_t*)alloc((size_t)B_ * TM1 * C_ * 2);
  bf16_t* yspb  = (bf16_t*)alloc((size_t)B_ * TM1 * C_ * 2);
  float*  ych   = (float*)alloc((size_t)B_ * C_ * 4);
  float*  ycp   = (float*)alloc((size_t)B_ * C_ * 4);
  const size_t fixed = off;
  // per-b: qvn [2044][1536]b + qpn [2044][256]b + t2 [2044][8]f + outn/poutn
  const size_t perb = (size_t)TM1 * KN_ * 1536 * 2 + (size_t)TM1 * KN_ * 256 * 2
                    + (size_t)TM1 * KN_ * R_ * 4
                    + (size_t)TM1 * KC5 * C_ * 2 * 2 + 6 * 256;
  int nb = 1;
  for (int cand : {8, 4, 2, 1}) {
    if (fixed + perb * (size_t)cand <= ws_size) { nb = cand; break; }
  }
  bf16_t* qvn    = (bf16_t*)alloc((size_t)nb * TM1 * KN_ * 1536 * 2);
  bf16_t* qpn    = (bf16_t*)alloc((size_t)nb * TM1 * KN_ * 256 * 2);
  float*  t2     = (float*)alloc((size_t)nb * TM1 * KN_ * R_ * 4);
  bf16_t* outn   = (bf16_t*)alloc((size_t)nb * TM1 * KC5 * C_ * 2);
  bf16_t* poutnb = (bf16_t*)alloc((size_t)nb * TM1 * KC5 * C_ * 2);

  dim3 blk(256);
  dim3 tg(C_ / 32, C_ / 32);

  // ---- prep ----
  cvt_bf16<<<1024, blk, 0, stream>>>(x, xbf, (long)(NT * C_));
  cvt_bf16<<<2048, blk, 0, stream>>>(nrep, nrbf, (long)(NR * C_));
  wtrans<<<tg, blk, 0, stream>>>(Wq, Wcat);
  wtrans<<<tg, blk, 0, stream>>>(Wk, Wcat + (size_t)C_ * C_);
  wtrans<<<tg, blk, 0, stream>>>(Wv, Wcat + (size_t)2 * C_ * C_);
  wtrans<<<tg, blk, 0, stream>>>(Wq, Wcat2);
  wtrans<<<tg, blk, 0, stream>>>(Wv, Wcat2 + (size_t)C_ * C_);
  wtrans<<<tg, blk, 0, stream>>>(Wp, Wtp);
  build_wqp<<<(256 * C_) / 256, blk, 0, stream>>>(Wu, bu, Wqp);
  build_wdt<<<24, blk, 0, stream>>>(Wd, WdT);
  cat3<<<9, blk, 0, stream>>>(bq, bk, bv, bcat);
  cat3<<<9, blk, 0, stream>>>(bq, bv, bq, bcat2);
  hipMemsetAsync(zbias, 0, 256 * 4, stream);

  // ---- self path ----
  gemm_mfma<<<dim3(18, 32), blk, 0, stream>>>(xbf, C_, Wcat, bcat,
                                              QKVc, LDQ, Vtg, 1536, 3,
                                              (int)NT, C_, 2304);
  gemm_mfma<<<dim3(2, 32), blk, 0, stream>>>(QKVc, LDQ, Wqp, zbias,
                                             qpx, 256, nullptr, 0, 1,
                                             (int)NT, C_, 256);
  gemv8<<<(int)(NT / 32), blk, 0, stream>>>(xbf, WdT, bd, t1, (int)NT);

  attn_mfma<<<dim3(8, H_, B_), blk, 0, stream>>>(QKVc, Vtg, mask, ysh);
  gemm_mfma<<<dim3(6, 32), blk, 0, stream>>>(ysh, C_, Wtp, bp,
                                             yspb, C_, nullptr, 0, 1,
                                             B_ * TM1, C_, C_);

  cls_attn<<<B_ * H_, 64, 0, stream>>>(QKVc, qpx, t1, mask, ych);
  gemv_cls<<<B_ * 3, blk, 0, stream>>>(ych, Wp, bp, ycp);
  combine_cls<<<B_, blk, 0, stream>>>(ycp, x, lng, lnb, dout);

  // ---- neighbour pipeline, chunked over b ----
  for (int b0 = 0; b0 < B_; b0 += nb) {
    const int Mn = nb * TM1 * KN_;
    const int Mo = nb * TM1 * KC5;
    const float*  nrc   = nrep + (size_t)b0 * TM1 * KN_ * C_;
    const bf16_t* nrcbf = nrbf + (size_t)b0 * TM1 * KN_ * C_;
    gemm_mfma<<<dim3(12, (Mn + 127) / 128), blk, 0, stream>>>(
        nrcbf, C_, Wcat2, bcat2, qvn, 1536, nullptr, 0, 1, Mn, C_, 1536);
    gemv8<<<(Mn + 31) / 32, blk, 0, stream>>>(nrcbf, WdT, bd, t2, Mn);
    gemm_mfma<<<dim3(2, (Mn + 127) / 128), blk, 0, stream>>>(
        qvn, 1536, Wqp, zbias, qpn, 256, nullptr, 0, 1, Mn, C_, 256);
    neigh_attn<<<nb * TM1, blk, 0, stream>>>(QKVc, t1, qpx, qvn, t2, qpn, b0, outn);
    gemm_mfma<<<dim3(6, (Mo + 127) / 128), blk, 0, stream>>>(
        outn, C_, Wtp, bp, poutnb, C_, nullptr, 0, 1, Mo, C_, C_);
    combine_main<<<nb * TM1, blk, 0, stream>>>(yspb, poutnb, x, lng, lnb, b0, dout);
    combine_neigh<<<nb * TM1 * KN_, blk, 0, stream>>>(poutnb, nrc, lng, lnb, b0,
                                                      dout + OUT1);
  }
}

// Round 6
// 458.526 us; speedup vs baseline: 4.1323x; 1.0671x over previous
//
#include <hip/hip_runtime.h>
#include <math.h>

#define C_    768
#define H_    12
#define D_    64
#define B_    8
#define T_    512
#define TM1   511
#define R_    8
#define KN_   4
#define KC5   5
#define SCALE_ 0.5f
#define EPS_  1e-12f
#define NEG_  -1000000000.0f
#define INV_  0.125f   /* 1/sqrt(64) */
#define LDQ   2304     /* row stride of fused QKV output */

typedef __bf16 bf16_t;
typedef __bf16 bf16x4_t __attribute__((ext_vector_type(4)));
typedef __bf16 bf16x8_t __attribute__((ext_vector_type(8)));
typedef float  f32x4_t  __attribute__((ext_vector_type(4)));
typedef const void __attribute__((address_space(1)))* gas_t;
typedef void       __attribute__((address_space(3)))* las_t;

__device__ __forceinline__ void gl_lds16(const bf16_t* g, bf16_t* l) {
  __builtin_amdgcn_global_load_lds((gas_t)g, (las_t)l, 16, 0, 0);
}

// ---------------------------------------------------------------------------
// fp32 -> bf16 flat convert (n % 4 == 0)
// ---------------------------------------------------------------------------
__global__ __launch_bounds__(256) void cvt_bf16(const float* __restrict__ in,
                                                bf16_t* __restrict__ out, long n) {
  long i = ((long)blockIdx.x * 256 + threadIdx.x) * 4;
  const long stride = (long)gridDim.x * 256 * 4;
  for (; i < n; i += stride) {
    float4 v = *(const float4*)(in + i);
    bf16x4_t o = { (bf16_t)v.x, (bf16_t)v.y, (bf16_t)v.z, (bf16_t)v.w };
    *(bf16x4_t*)(out + i) = o;
  }
}

// ---------------------------------------------------------------------------
// Weight transpose + convert: Wt[n][k] = (bf16) W[k][n], 768x768.
// ---------------------------------------------------------------------------
__global__ __launch_bounds__(256) void wtrans(const float* __restrict__ W,
                                              bf16_t* __restrict__ Wt) {
  __shared__ float tile[32][33];
  const int n0 = blockIdx.x * 32, k0 = blockIdx.y * 32;
  const int tx = threadIdx.x & 31, ty = threadIdx.x >> 5;
  #pragma unroll
  for (int r = ty; r < 32; r += 8)
    tile[r][tx] = W[(size_t)(k0 + r) * C_ + n0 + tx];
  __syncthreads();
  #pragma unroll
  for (int r = ty; r < 32; r += 8)
    Wt[(size_t)(n0 + r) * C_ + k0 + tx] = (bf16_t)tile[tx][r];
}

// ---------------------------------------------------------------------------
// Wqp[n=256][k=768]: per-head low-rank projection weight.
// n = h*16+r : r<8 -> Wu[r][k] (k in head h), r==8 -> bu[k], else 0.
// ---------------------------------------------------------------------------
__global__ __launch_bounds__(256) void build_wqp(
    const float* __restrict__ Wu, const float* __restrict__ bu,
    bf16_t* __restrict__ Wqp) {
  int idx = blockIdx.x * 256 + threadIdx.x;   // 256*768
  int n = idx / C_, k = idx % C_;
  int h = n >> 4, r = n & 15;
  float v = 0.f;
  if (h < H_ && (k >> 6) == h) {
    if (r < 8) v = Wu[r * C_ + k];
    else if (r == 8) v = bu[k];
  }
  Wqp[idx] = (bf16_t)v;
}

// bfq[n=h*16+r]: r<8 -> sum_{k in h} bq[k]*Wu[r][k]; r==8 -> sum bq[k]*bu[k].
__global__ __launch_bounds__(256) void build_bfq(
    const float* __restrict__ Wu, const float* __restrict__ bu,
    const float* __restrict__ bq, float* __restrict__ bfq) {
  int n = threadIdx.x;
  int h = n >> 4, r = n & 15;
  float s = 0.f;
  if (h < H_) {
    if (r < 8) {
      for (int k = 0; k < 64; ++k) s += bq[h * 64 + k] * Wu[r * C_ + h * 64 + k];
    } else if (r == 8) {
      for (int k = 0; k < 64; ++k) s += bq[h * 64 + k] * bu[h * 64 + k];
    }
  }
  bfq[n] = s;
}

// WdT[r][k] = Wd[k][r]
__global__ __launch_bounds__(256) void build_wdt(const float* __restrict__ Wd,
                                                 float* __restrict__ WdT) {
  int idx = blockIdx.x * 256 + threadIdx.x;   // 8*768
  if (idx < R_ * C_) {
    int r = idx / C_, k = idx % C_;
    WdT[idx] = Wd[k * R_ + r];
  }
}

// bias concat (3 x 768)
__global__ __launch_bounds__(256) void cat3(const float* __restrict__ a,
                                            const float* __restrict__ b,
                                            const float* __restrict__ c,
                                            float* __restrict__ o) {
  int i = blockIdx.x * 256 + threadIdx.x;   // < 2304
  const float* s = (i < 768) ? a : (i < 1536 ? b : c);
  o[i] = s[i % 768];
}

// ---------------------------------------------------------------------------
// bf16 MFMA GEMM with lda/ldc strides and bijective XCD swizzle.
// mode bit0: write bf16 Cbf; bit1: also write transposed copy of cols
// [trcol0, trcol0+768) into Ctr laid out [b][h][d=64][T=512] (needs M%512==0).
// ---------------------------------------------------------------------------
__global__ __launch_bounds__(256) void gemm_mfma(
    const bf16_t* __restrict__ A, int lda,
    const bf16_t* __restrict__ Bt,
    const float* __restrict__ bias,
    bf16_t* __restrict__ Cbf, int ldc,
    bf16_t* __restrict__ Ctr, int trcol0, int mode,
    int M, int K, int N)
{
  __shared__ bf16_t As[128 * 32];
  __shared__ bf16_t Bs[128 * 32];
  const int gx = gridDim.x;
  int lid = blockIdx.y * gx + blockIdx.x;
  {
    const int nwg = gx * gridDim.y;
    const int q0 = nwg >> 3, r0 = nwg & 7;
    const int xcd = lid & 7, idx = lid >> 3;
    lid = (xcd < r0 ? xcd * (q0 + 1) : r0 * (q0 + 1) + (xcd - r0) * q0) + idx;
  }
  const int row0 = (lid / gx) * 128;
  const int col0 = (lid % gx) * 128;

  const int tid = threadIdx.x;
  const int lane = tid & 63;
  const int wv = tid >> 6;
  const int wr = (wv >> 1) * 64;
  const int wc = (wv & 1) * 64;
  const int sr = tid >> 2;
  const int sk = (tid & 3) * 8;

  int ra0 = row0 + sr;       if (ra0 > M - 1) ra0 = M - 1;
  int ra1 = row0 + 64 + sr;  if (ra1 > M - 1) ra1 = M - 1;
  const bf16_t* ga0 = A + (size_t)ra0 * lda + sk;
  const bf16_t* ga1 = A + (size_t)ra1 * lda + sk;
  const bf16_t* gb0 = Bt + (size_t)(col0 + sr) * K + sk;
  const bf16_t* gb1 = Bt + (size_t)(col0 + 64 + sr) * K + sk;
  bf16_t* lA = As + wv * 512;
  bf16_t* lB = Bs + wv * 512;

  f32x4_t acc[4][4];
  #pragma unroll
  for (int i = 0; i < 4; ++i)
    #pragma unroll
    for (int j = 0; j < 4; ++j) acc[i][j] = (f32x4_t){0.f, 0.f, 0.f, 0.f};

  const int fm = lane & 15;
  const int kb = (lane >> 4) * 8;

  for (int k0 = 0; k0 < K; k0 += 32) {
    gl_lds16(ga0 + k0, lA);
    gl_lds16(ga1 + k0, lA + 2048);
    gl_lds16(gb0 + k0, lB);
    gl_lds16(gb1 + k0, lB + 2048);
    __syncthreads();
    bf16x8_t af[4], bfr[4];
    #pragma unroll
    for (int mi = 0; mi < 4; ++mi)
      af[mi] = *(const bf16x8_t*)(As + (wr + mi * 16 + fm) * 32 + kb);
    #pragma unroll
    for (int ni = 0; ni < 4; ++ni)
      bfr[ni] = *(const bf16x8_t*)(Bs + (wc + ni * 16 + fm) * 32 + kb);
    #pragma unroll
    for (int mi = 0; mi < 4; ++mi)
      #pragma unroll
      for (int ni = 0; ni < 4; ++ni)
        acc[mi][ni] = __builtin_amdgcn_mfma_f32_16x16x32_bf16(af[mi], bfr[ni],
                                                              acc[mi][ni], 0, 0, 0);
    __syncthreads();
  }

  const int r4 = (lane >> 4) * 4;
  #pragma unroll
  for (int ni = 0; ni < 4; ++ni) {
    const int col = col0 + wc + ni * 16 + fm;
    const float bv = bias[col];
    #pragma unroll
    for (int mi = 0; mi < 4; ++mi) {
      const int rb = row0 + wr + mi * 16 + r4;
      float v[4];
      #pragma unroll
      for (int r = 0; r < 4; ++r) v[r] = acc[mi][ni][r] + bv;
      if (mode & 1) {
        #pragma unroll
        for (int r = 0; r < 4; ++r)
          if (rb + r < M) Cbf[(size_t)(rb + r) * ldc + col] = (bf16_t)v[r];
      }
      if ((mode & 2) && (unsigned)(col - trcol0) < 768u) {
        const int vcol = col - trcol0;
        bf16x4_t o4 = {(bf16_t)v[0], (bf16_t)v[1], (bf16_t)v[2], (bf16_t)v[3]};
        size_t idx = ((size_t)(rb >> 9) * H_ + (size_t)(vcol >> 6)) * ((size_t)D_ * T_)
                   + (size_t)(vcol & 63) * T_ + (size_t)(rb & 511);
        *(bf16x4_t*)(Ctr + idx) = o4;
      }
    }
  }
}

// ---------------------------------------------------------------------------
// Narrow GEMV: out[M][8] = A(bf16,[M][768]) @ WdT^T + bd.  thread = (row, r).
// ---------------------------------------------------------------------------
__global__ __launch_bounds__(256) void gemv8(
    const bf16_t* __restrict__ A, const float* __restrict__ WdT,
    const float* __restrict__ bd, float* __restrict__ out, int M)
{
  int row = blockIdx.x * 32 + (threadIdx.x >> 3);
  int r = threadIdx.x & 7;
  if (row >= M) return;
  const bf16_t* ar = A + (size_t)row * C_;
  const float* wr = WdT + r * C_;
  float acc = 0.f;
  for (int k = 0; k < C_; k += 8) {
    bf16x8_t av = *(const bf16x8_t*)(ar + k);
    float4 w0 = *(const float4*)(wr + k);
    float4 w1 = *(const float4*)(wr + k + 4);
    acc += (float)av[0]*w0.x + (float)av[1]*w0.y + (float)av[2]*w0.z + (float)av[3]*w0.w
         + (float)av[4]*w1.x + (float)av[5]*w1.y + (float)av[6]*w1.z + (float)av[7]*w1.w;
  }
  out[(size_t)row * R_ + r] = acc + bd[r];
}

// ---------------------------------------------------------------------------
// Small dense projection for the 8 cls rows: out[8][768] = A @ W + bias.
// ---------------------------------------------------------------------------
__global__ __launch_bounds__(256) void gemv_cls(
    const float* __restrict__ A, const float* __restrict__ W,
    const float* __restrict__ bias, float* __restrict__ out)
{
  __shared__ float as[C_];
  const int row = blockIdx.x / 3;
  const int c = (blockIdx.x % 3) * 256 + threadIdx.x;
  for (int i = threadIdx.x; i < C_; i += 256) as[i] = A[(size_t)row * C_ + i];
  __syncthreads();
  float acc = bias[c];
  for (int k = 0; k < C_; ++k) acc += as[k] * W[(size_t)k * C_ + c];
  out[(size_t)row * C_ + c] = acc;
}

// ---------------------------------------------------------------------------
// MFMA flash self-attention; Q/K read from fused QKVc (stride LDQ).
// ---------------------------------------------------------------------------
__global__ __launch_bounds__(256) void attn_mfma(
    const bf16_t* __restrict__ QKVc, const bf16_t* __restrict__ Vtg,
    const int* __restrict__ mask, bf16_t* __restrict__ yout)
{
  __shared__ bf16_t Ks[64 * 64];
  __shared__ bf16_t Vs[64 * 64];
  __shared__ bf16_t Pl[4][16 * 64];
  __shared__ float  fac_s[4][16];
  __shared__ float  l_s[4][16];
  __shared__ int    msk_s[64];

  const int b = blockIdx.z, h = blockIdx.y;
  const int qt0 = blockIdx.x * 64;
  const int tid = threadIdx.x;
  const int lane = tid & 63;
  const int w = tid >> 6;
  const int lq = lane & 15;
  const int g = lane >> 4;

  const int qi_frag = qt0 + w * 16 + lq;
  const int qtok = (qi_frag < TM1 ? qi_frag : TM1 - 1) + 1;
  bf16x8_t qf[2];
  {
    const bf16_t* qp = QKVc + ((size_t)(b * T_) + qtok) * LDQ + h * D_ + 8 * g;
    qf[0] = *(const bf16x8_t*)qp;
    qf[1] = *(const bf16x8_t*)(qp + 32);
  }

  const bf16_t* kbase = QKVc + (size_t)(b * T_) * LDQ + 768 + h * D_;
  const bf16_t* vbase = Vtg + ((size_t)(b * H_) + h) * ((size_t)D_ * T_);

  f32x4_t o[4];
  #pragma unroll
  for (int i = 0; i < 4; ++i) o[i] = (f32x4_t){0.f, 0.f, 0.f, 0.f};
  float m = -INFINITY, l = 0.f;

  for (int kt = 0; kt < T_; kt += 64) {
    #pragma unroll
    for (int i = 0; i < 2; ++i) {
      const int tp = tid + i * 256;
      const int kr = tp >> 3;
      const int sl = tp & 7;
      const int ss = sl ^ (kr & 7);
      gl_lds16(kbase + (size_t)(kt + kr) * LDQ + 8 * ss,
               Ks + (size_t)(i * 4 + w) * 512);
      gl_lds16(vbase + (size_t)kr * T_ + kt + 8 * ss,
               Vs + (size_t)(i * 4 + w) * 512);
    }
    if (tid < 64) msk_s[tid] = mask[b * T_ + kt + tid];
    __syncthreads();

    f32x4_t st[4];
    #pragma unroll
    for (int t = 0; t < 4; ++t) {
      st[t] = (f32x4_t){0.f, 0.f, 0.f, 0.f};
      const int kk = t * 16 + lq;
      const bf16_t* krow = Ks + kk * 64;
      bf16x8_t kf0 = *(const bf16x8_t*)(krow + 8 * ((g)     ^ (kk & 7)));
      bf16x8_t kf1 = *(const bf16x8_t*)(krow + 8 * ((4 + g) ^ (kk & 7)));
      st[t] = __builtin_amdgcn_mfma_f32_16x16x32_bf16(kf0, qf[0], st[t], 0, 0, 0);
      st[t] = __builtin_amdgcn_mfma_f32_16x16x32_bf16(kf1, qf[1], st[t], 0, 0, 0);
    }

    float p[16];
    float mt = -INFINITY;
    #pragma unroll
    for (int t = 0; t < 4; ++t) {
      const int4 mk = *(const int4*)&msk_s[t * 16 + 4 * g];
      p[4*t+0] = mk.x ? st[t][0] * INV_ : NEG_;
      p[4*t+1] = mk.y ? st[t][1] * INV_ : NEG_;
      p[4*t+2] = mk.z ? st[t][2] * INV_ : NEG_;
      p[4*t+3] = mk.w ? st[t][3] * INV_ : NEG_;
      mt = fmaxf(mt, fmaxf(fmaxf(p[4*t], p[4*t+1]), fmaxf(p[4*t+2], p[4*t+3])));
    }
    mt = fmaxf(mt, __shfl_xor(mt, 16));
    mt = fmaxf(mt, __shfl_xor(mt, 32));
    const float mnew = fmaxf(m, mt);
    const float fac = __expf(m - mnew);
    float ps = 0.f;
    #pragma unroll
    for (int i = 0; i < 16; ++i) { p[i] = __expf(p[i] - mnew); ps += p[i]; }
    ps += __shfl_xor(ps, 16);
    ps += __shfl_xor(ps, 32);
    l = l * fac + ps;
    m = mnew;
    if (lane < 16) fac_s[w][lane] = fac;

    bf16_t* prow = Pl[w] + lq * 64;
    #pragma unroll
    for (int t = 0; t < 4; ++t) {
      bf16x4_t pb = {(bf16_t)p[4*t], (bf16_t)p[4*t+1],
                     (bf16_t)p[4*t+2], (bf16_t)p[4*t+3]};
      *(bf16x4_t*)(prow + 8 * ((2*t + (g >> 1)) ^ (lq & 7)) + 4 * (g & 1)) = pb;
    }
    bf16x8_t pa0 = *(const bf16x8_t*)(prow + 8 * ((g)     ^ (lq & 7)));
    bf16x8_t pa1 = *(const bf16x8_t*)(prow + 8 * ((4 + g) ^ (lq & 7)));

    const float4 fc = *(const float4*)&fac_s[w][4 * g];
    #pragma unroll
    for (int db = 0; db < 4; ++db) {
      const int dr = db * 16 + lq;
      const bf16_t* vrow = Vs + dr * 64;
      bf16x8_t vf0 = *(const bf16x8_t*)(vrow + 8 * ((g)     ^ (dr & 7)));
      bf16x8_t vf1 = *(const bf16x8_t*)(vrow + 8 * ((4 + g) ^ (dr & 7)));
      o[db][0] *= fc.x; o[db][1] *= fc.y; o[db][2] *= fc.z; o[db][3] *= fc.w;
      o[db] = __builtin_amdgcn_mfma_f32_16x16x32_bf16(pa0, vf0, o[db], 0, 0, 0);
      o[db] = __builtin_amdgcn_mfma_f32_16x16x32_bf16(pa1, vf1, o[db], 0, 0, 0);
    }
    __syncthreads();
  }

  if (lane < 16) l_s[w][lane] = l;
  const float4 lv = *(const float4*)&l_s[w][4 * g];
  const float rl0 = 1.f / lv.x, rl1 = 1.f / lv.y;
  const float rl2 = 1.f / lv.z, rl3 = 1.f / lv.w;
  const int qr0 = qt0 + w * 16 + 4 * g;
  #pragma unroll
  for (int db = 0; db < 4; ++db) {
    const int col = h * D_ + db * 16 + lq;
    bf16_t* yp = yout + ((size_t)(b * TM1) + qr0) * C_ + col;
    if (qr0 + 0 < TM1) yp[0 * (size_t)C_] = (bf16_t)(o[db][0] * rl0);
    if (qr0 + 1 < TM1) yp[1 * (size_t)C_] = (bf16_t)(o[db][1] * rl1);
    if (qr0 + 2 < TM1) yp[2 * (size_t)C_] = (bf16_t)(o[db][2] * rl2);
    if (qr0 + 3 < TM1) yp[3 * (size_t)C_] = (bf16_t)(o[db][3] * rl3);
  }
}

// ---------------------------------------------------------------------------
// cls attention via low-rank keys: score = dot8(qp, t1[key]) + qp[8].
// ---------------------------------------------------------------------------
__global__ __launch_bounds__(64) void cls_attn(
    const bf16_t* __restrict__ QKVc, const bf16_t* __restrict__ qpx,
    const float* __restrict__ t1, const int* __restrict__ mask,
    float* __restrict__ yout /* (B,768) */)
{
  __shared__ float qp_s[16];
  __shared__ float Vs[64][65];
  __shared__ float Ps[64];

  const int b = blockIdx.x / H_, h = blockIdx.x % H_;
  const int lane = threadIdx.x;

  if (lane < 16) qp_s[lane] = (float)qpx[(size_t)(b * T_) * 256 + h * 16 + lane];
  __syncthreads();

  float m = -INFINITY, l = 0.f, acc = 0.f;
  for (int kt = 0; kt < T_; kt += 64) {
    for (int rr = 0; rr < 64; ++rr)
      Vs[rr][lane] = (float)QKVc[((size_t)(b * T_) + kt + rr) * LDQ + 1536 + h * D_ + lane];
    __syncthreads();
    const float* t1r = t1 + ((size_t)(b * T_) + kt + lane) * R_;
    float sc = qp_s[8];
    #pragma unroll
    for (int r = 0; r < 8; ++r) sc += qp_s[r] * t1r[r];
    sc *= INV_;
    if (!mask[b * T_ + kt + lane]) sc = NEG_;
    float mt = sc;
    #pragma unroll
    for (int off = 32; off > 0; off >>= 1) mt = fmaxf(mt, __shfl_xor(mt, off));
    float mnew = fmaxf(m, mt);
    float e = __expf(sc - mnew);
    float ssum = e;
    #pragma unroll
    for (int off = 32; off > 0; off >>= 1) ssum += __shfl_xor(ssum, off);
    float fac = __expf(m - mnew);
    acc *= fac;
    l = l * fac + ssum;
    Ps[lane] = e;
    __syncthreads();
    #pragma unroll
    for (int j = 0; j < 64; ++j) acc += Ps[j] * Vs[j][lane];
    m = mnew;
    __syncthreads();
  }
  yout[(size_t)b * C_ + h * D_ + lane] = acc / l;
}

// ---------------------------------------------------------------------------
// Neighbour attention via low-rank keys.  Per token: qp (5x~200), t2 (5x8),
// V (5x768).  i=0 comes from QKVc/qpx/t1 at the token row.
// ---------------------------------------------------------------------------
__global__ __launch_bounds__(256) void neigh_attn(
    const bf16_t* __restrict__ QKVc, const float* __restrict__ t1,
    const bf16_t* __restrict__ qpx,
    const bf16_t* __restrict__ vn,   /* [rows][768] */
    const float* __restrict__ t2,    /* [rows][8] */
    const bf16_t* __restrict__ qpn,  /* [rows][256] */
    int b0, bf16_t* __restrict__ outn)
{
  __shared__ float vs[KC5 * C_];
  __shared__ float qp_s[KC5][200];
  __shared__ float t2_s[KC5][8];
  __shared__ float Ps[H_ * 25];

  const int bt = blockIdx.x;
  const int bb = bt / TM1, t = bt % TM1;
  const int b = b0 + bb;
  const int tid = threadIdx.x;
  const size_t tok = (size_t)(b * T_) + t + 1;
  const size_t nrow = ((size_t)(bb * TM1) + t) * KN_;

  for (int idx = tid; idx < KC5 * 96; idx += 256) {
    int i = idx / 96, d8 = (idx % 96) * 8;
    const bf16_t* vp = (i == 0) ? QKVc + tok * LDQ + 1536 + d8
                                : vn + (nrow + i - 1) * C_ + d8;
    bf16x8_t vv = *(const bf16x8_t*)vp;
    #pragma unroll
    for (int j = 0; j < 8; ++j) vs[i * C_ + d8 + j] = (float)vv[j];
  }
  for (int idx = tid; idx < KC5 * 24; idx += 256) {
    int i = idx / 24, c8 = (idx % 24) * 8;
    const bf16_t* qpp = (i == 0) ? qpx + tok * 256 + c8
                                 : qpn + (nrow + i - 1) * 256 + c8;
    bf16x8_t qv = *(const bf16x8_t*)qpp;
    #pragma unroll
    for (int j = 0; j < 8; ++j) qp_s[i][c8 + j] = (float)qv[j];
  }
  if (tid < KC5 * 8) {
    int i = tid / 8, r = tid & 7;
    t2_s[i][r] = (i == 0) ? t1[tok * R_ + r] : t2[(nrow + i - 1) * R_ + r];
  }
  __syncthreads();

  if (tid < H_ * KC5) {
    int h = tid / KC5, i = tid % KC5;
    float sc[KC5];
    #pragma unroll
    for (int j = 0; j < KC5; ++j) {
      float s = qp_s[i][h * 16 + 8];
      #pragma unroll
      for (int r = 0; r < 8; ++r) s += qp_s[i][h * 16 + r] * t2_s[j][r];
      sc[j] = s * INV_;
    }
    float mt = sc[0];
    #pragma unroll
    for (int j = 1; j < KC5; ++j) mt = fmaxf(mt, sc[j]);
    float e[KC5], ssum = 0.f;
    #pragma unroll
    for (int j = 0; j < KC5; ++j) { e[j] = __expf(sc[j] - mt); ssum += e[j]; }
    float rs = 1.f / ssum;
    #pragma unroll
    for (int j = 0; j < KC5; ++j) Ps[h * 25 + i * KC5 + j] = e[j] * rs;
  }
  __syncthreads();

  for (int idx = tid; idx < KC5 * C_; idx += 256) {
    int i = idx / C_, c = idx % C_;
    int h = c / D_;
    float sum = 0.f;
    #pragma unroll
    for (int j = 0; j < KC5; ++j)
      sum += Ps[h * 25 + i * KC5 + j] * vs[j * C_ + c];
    outn[(((size_t)(bb * TM1) + t) * KC5 + i) * C_ + c] = (bf16_t)sum;
  }
}

// ---------------------------------------------------------------------------
// Residual + LayerNorm combine kernels
// ---------------------------------------------------------------------------
__device__ __forceinline__ void block_reduce2(float& s, float& ss, float* red) {
  #pragma unroll
  for (int off = 32; off > 0; off >>= 1) {
    s += __shfl_down(s, off);
    ss += __shfl_down(ss, off);
  }
  int wid = threadIdx.x >> 6;
  if ((threadIdx.x & 63) == 0) { red[wid * 2] = s; red[wid * 2 + 1] = ss; }
  __syncthreads();
  s  = red[0] + red[2] + red[4] + red[6];
  ss = red[1] + red[3] + red[5] + red[7];
}

__device__ __forceinline__ void ln_row(const float vals[3], float s, float ss,
                                       const float* __restrict__ g,
                                       const float* __restrict__ bb,
                                       float* __restrict__ orow, float* red) {
  block_reduce2(s, ss, red);
  float mean = s * (1.f / (float)C_);
  float var = ss * (1.f / (float)C_) - mean * mean;
  var = fmaxf(var, 0.f);
  float rs = rsqrtf(var + EPS_);
  #pragma unroll
  for (int ii = 0; ii < 3; ++ii) {
    int c = threadIdx.x + ii * 256;
    orow[c] = (vals[ii] - mean) * rs * g[c] + bb[c];
  }
}

__global__ __launch_bounds__(256) void combine_main(
    const bf16_t* __restrict__ yselfP, const bf16_t* __restrict__ poutn,
    const float* __restrict__ x, const float* __restrict__ g,
    const float* __restrict__ bln, int b0, float* __restrict__ dout)
{
  __shared__ float red[8];
  const int bt = blockIdx.x;
  const int bbb = bt / TM1, t = bt % TM1;
  const int b = b0 + bbb;
  const bf16_t* ys = yselfP + ((size_t)(b * TM1) + t) * C_;
  const bf16_t* pn = poutn + (((size_t)(bbb * TM1) + t) * KC5 + 0) * C_;
  const float* xr = x + ((size_t)(b * T_) + t + 1) * C_;
  float* orow = dout + ((size_t)(b * T_) + t + 1) * C_;
  float vals[3], s = 0.f, ss = 0.f;
  #pragma unroll
  for (int ii = 0; ii < 3; ++ii) {
    int c = threadIdx.x + ii * 256;
    float v = SCALE_ * (float)pn[c] + (1.f - SCALE_) * (float)ys[c] + xr[c];
    vals[ii] = v; s += v; ss += v * v;
  }
  ln_row(vals, s, ss, g, bln, orow, red);
}

__global__ __launch_bounds__(256) void combine_neigh(
    const bf16_t* __restrict__ poutn, const float* __restrict__ nrc,
    const float* __restrict__ g, const float* __restrict__ bln,
    int b0, float* __restrict__ dout)
{
  __shared__ float red[8];
  const int idx = blockIdx.x;
  const int i1 = idx % KN_;
  const int bt = idx / KN_;
  const int bbb = bt / TM1, t = bt % TM1;
  const int b = b0 + bbb;
  const bf16_t* pn = poutn + ((size_t)bt * KC5 + 1 + i1) * C_;
  const float* nr = nrc + ((size_t)bt * KN_ + i1) * C_;
  float* orow = dout + (((size_t)(b * TM1) + t) * KN_ + i1) * C_;
  float vals[3], s = 0.f, ss = 0.f;
  #pragma unroll
  for (int ii = 0; ii < 3; ++ii) {
    int c = threadIdx.x + ii * 256;
    float v = (float)pn[c] + nr[c];
    vals[ii] = v; s += v; ss += v * v;
  }
  ln_row(vals, s, ss, g, bln, orow, red);
}

__global__ __launch_bounds__(256) void combine_cls(
    const float* __restrict__ yclsP, const float* __restrict__ x,
    const float* __restrict__ g, const float* __restrict__ bln,
    float* __restrict__ dout)
{
  __shared__ float red[8];
  const int b = blockIdx.x;
  const float* yc = yclsP + (size_t)b * C_;
  const float* xr = x + (size_t)(b * T_) * C_;
  float* orow = dout + (size_t)(b * T_) * C_;
  float vals[3], s = 0.f, ss = 0.f;
  #pragma unroll
  for (int ii = 0; ii < 3; ++ii) {
    int c = threadIdx.x + ii * 256;
    float v = yc[c] + xr[c];
    vals[ii] = v; s += v; ss += v * v;
  }
  ln_row(vals, s, ss, g, bln, orow, red);
}

// ---------------------------------------------------------------------------
extern "C" void kernel_launch(void* const* d_in, const int* in_sizes, int n_in,
                              void* d_out, int out_size, void* d_ws, size_t ws_size,
                              hipStream_t stream) {
  (void)in_sizes; (void)n_in; (void)out_size;
  const float* x    = (const float*)d_in[0];
  const int*   mask = (const int*)d_in[1];
  const float* nrep = (const float*)d_in[2];
  const float* Wq = (const float*)d_in[3];  const float* bq = (const float*)d_in[4];
  const float* Wk = (const float*)d_in[5];  const float* bk = (const float*)d_in[6];
  const float* Wv = (const float*)d_in[7];  const float* bv = (const float*)d_in[8];
  const float* Wp = (const float*)d_in[9];  const float* bp = (const float*)d_in[10];
  const float* Wd = (const float*)d_in[11]; const float* bd = (const float*)d_in[12];
  const float* Wu = (const float*)d_in[13]; const float* bu = (const float*)d_in[14];
  const float* lng = (const float*)d_in[15];
  const float* lnb = (const float*)d_in[16];
  float* dout = (float*)d_out;
  const size_t OUT1 = (size_t)B_ * T_ * C_;

  char* ws = (char*)d_ws;
  size_t off = 0;
  auto alloc = [&](size_t bytes) -> void* {
    void* p = ws + off; off += (bytes + 255) & ~(size_t)255; return p;
  };
  const size_t NT = (size_t)B_ * T_;
  const size_t NR = (size_t)B_ * TM1 * KN_;
  const size_t YSROWS = (size_t)B_ * TM1;     // 4088

  bf16_t* xbf   = (bf16_t*)alloc(NT * C_ * 2);
  bf16_t* nrbf  = (bf16_t*)alloc(NR * C_ * 2);
  bf16_t* Wcat  = (bf16_t*)alloc((size_t)3 * C_ * C_ * 2);   // Q|K|V, [2304][768]
  bf16_t* Wtp   = (bf16_t*)alloc((size_t)C_ * C_ * 2);
  bf16_t* Wqp   = (bf16_t*)alloc((size_t)256 * C_ * 2);
  bf16_t* Wqbf  = (bf16_t*)alloc((size_t)C_ * C_ * 2);
  bf16_t* WfqT  = (bf16_t*)alloc((size_t)256 * C_ * 2);
  float*  WdT   = (float*)alloc((size_t)R_ * C_ * 4);
  float*  bcat  = (float*)alloc(2304 * 4);
  float*  bfq   = (float*)alloc(256 * 4);
  float*  zb768 = (float*)alloc(768 * 4);
  bf16_t* QKVc  = (bf16_t*)alloc(NT * LDQ * 2);
  bf16_t* Vtg   = (bf16_t*)alloc(NT * C_ * 2);   // [b][h][d][T]
  bf16_t* qpx   = (bf16_t*)alloc(NT * 256 * 2);
  float*  t1    = (float*)alloc(NT * R_ * 4);
  float*  ych   = (float*)alloc((size_t)B_ * C_ * 4);
  float*  ycp   = (float*)alloc((size_t)B_ * C_ * 4);
  const size_t fixed = off + 2 * (YSROWS * C_ * 2 + 256);   // + proj ys parts
  // per-b chunk: vn + qpn + t2 + proj_in/out outn parts
  const size_t perb = (size_t)TM1 * KN_ * C_ * 2 + (size_t)TM1 * KN_ * 256 * 2
                    + (size_t)TM1 * KN_ * R_ * 4
                    + (size_t)TM1 * KC5 * C_ * 2 * 2 + 6 * 256;
  int nb = 1;
  for (int cand : {8, 4, 2, 1}) {
    if (fixed + perb * (size_t)cand <= ws_size) { nb = cand; break; }
  }
  // proj_in: rows [0, YSROWS) = ysh; rows [YSROWS, ...) = outn chunk
  bf16_t* proj_in  = (bf16_t*)alloc((YSROWS + (size_t)nb * TM1 * KC5) * C_ * 2);
  bf16_t* proj_out = (bf16_t*)alloc((YSROWS + (size_t)nb * TM1 * KC5) * C_ * 2);
  bf16_t* vn   = (bf16_t*)alloc((size_t)nb * TM1 * KN_ * C_ * 2);
  bf16_t* qpn  = (bf16_t*)alloc((size_t)nb * TM1 * KN_ * 256 * 2);
  float*  t2   = (float*)alloc((size_t)nb * TM1 * KN_ * R_ * 4);
  bf16_t* ysh    = proj_in;
  bf16_t* outn   = proj_in + YSROWS * C_;
  bf16_t* yspb   = proj_out;
  bf16_t* poutnb = proj_out + YSROWS * C_;

  dim3 blk(256);
  dim3 tg(C_ / 32, C_ / 32);

  // ---- prep ----
  cvt_bf16<<<1024, blk, 0, stream>>>(x, xbf, (long)(NT * C_));
  cvt_bf16<<<2048, blk, 0, stream>>>(nrep, nrbf, (long)(NR * C_));
  cvt_bf16<<<576, blk, 0, stream>>>(Wq, Wqbf, (long)C_ * C_);
  wtrans<<<tg, blk, 0, stream>>>(Wq, Wcat);
  wtrans<<<tg, blk, 0, stream>>>(Wk, Wcat + (size_t)C_ * C_);
  wtrans<<<tg, blk, 0, stream>>>(Wv, Wcat + (size_t)2 * C_ * C_);
  wtrans<<<tg, blk, 0, stream>>>(Wp, Wtp);
  build_wqp<<<(256 * C_) / 256, blk, 0, stream>>>(Wu, bu, Wqp);
  build_bfq<<<1, blk, 0, stream>>>(Wu, bu, bq, bfq);
  build_wdt<<<24, blk, 0, stream>>>(Wd, WdT);
  cat3<<<9, blk, 0, stream>>>(bq, bk, bv, bcat);
  hipMemsetAsync(zb768, 0, 768 * 4, stream);
  // fused low-rank query weight: WfqT[256][768] = Wqp @ Wq^T (Bt = Wq rows)
  gemm_mfma<<<dim3(6, 2), blk, 0, stream>>>(Wqp, C_, Wqbf, zb768,
                                            WfqT, C_, nullptr, 0, 1,
                                            256, C_, C_);

  // ---- self path ----
  gemm_mfma<<<dim3(18, 32), blk, 0, stream>>>(xbf, C_, Wcat, bcat,
                                              QKVc, LDQ, Vtg, 1536, 3,
                                              (int)NT, C_, 2304);
  gemm_mfma<<<dim3(2, 32), blk, 0, stream>>>(xbf, C_, WfqT, bfq,
                                             qpx, 256, nullptr, 0, 1,
                                             (int)NT, C_, 256);
  gemv8<<<(int)(NT / 32), blk, 0, stream>>>(xbf, WdT, bd, t1, (int)NT);

  attn_mfma<<<dim3(8, H_, B_), blk, 0, stream>>>(QKVc, Vtg, mask, ysh);

  cls_attn<<<B_ * H_, 64, 0, stream>>>(QKVc, qpx, t1, mask, ych);
  gemv_cls<<<B_ * 3, blk, 0, stream>>>(ych, Wp, bp, ycp);
  combine_cls<<<B_, blk, 0, stream>>>(ycp, x, lng, lnb, dout);

  if (nb == 8) {
    // ---- full-batch neighbour pipeline + merged projection ----
    const int Mn = 8 * TM1 * KN_;    // 16352
    gemm_mfma<<<dim3(6, (Mn + 127) / 128), blk, 0, stream>>>(
        nrbf, C_, Wcat + (size_t)2 * C_ * C_, bv, vn, C_, nullptr, 0, 1,
        Mn, C_, C_);
    gemm_mfma<<<dim3(2, (Mn + 127) / 128), blk, 0, stream>>>(
        nrbf, C_, WfqT, bfq, qpn, 256, nullptr, 0, 1, Mn, C_, 256);
    gemv8<<<(Mn + 31) / 32, blk, 0, stream>>>(nrbf, WdT, bd, t2, Mn);
    neigh_attn<<<8 * TM1, blk, 0, stream>>>(QKVc, t1, qpx, vn, t2, qpn, 0, outn);
    const int Mp = (int)YSROWS + 8 * TM1 * KC5;   // 24528
    gemm_mfma<<<dim3(6, (Mp + 127) / 128), blk, 0, stream>>>(
        proj_in, C_, Wtp, bp, proj_out, C_, nullptr, 0, 1, Mp, C_, C_);
    combine_main<<<8 * TM1, blk, 0, stream>>>(yspb, poutnb, x, lng, lnb, 0, dout);
    combine_neigh<<<8 * TM1 * KN_, blk, 0, stream>>>(poutnb, nrep, lng, lnb, 0,
                                                     dout + OUT1);
  } else {
    // ---- chunked fallback ----
    gemm_mfma<<<dim3(6, 32), blk, 0, stream>>>(ysh, C_, Wtp, bp,
                                               yspb, C_, nullptr, 0, 1,
                                               (int)YSROWS, C_, C_);
    for (int b0 = 0; b0 < B_; b0 += nb) {
      const int Mn = nb * TM1 * KN_;
      const int Mo = nb * TM1 * KC5;
      const float*  nrc   = nrep + (size_t)b0 * TM1 * KN_ * C_;
      const bf16_t* nrcbf = nrbf + (size_t)b0 * TM1 * KN_ * C_;
      gemm_mfma<<<dim3(6, (Mn + 127) / 128), blk, 0, stream>>>(
          nrcbf, C_, Wcat + (size_t)2 * C_ * C_, bv, vn, C_, nullptr, 0, 1,
          Mn, C_, C_);
      gemm_mfma<<<dim3(2, (Mn + 127) / 128), blk, 0, stream>>>(
          nrcbf, C_, WfqT, bfq, qpn, 256, nullptr, 0, 1, Mn, C_, 256);
      gemv8<<<(Mn + 31) / 32, blk, 0, stream>>>(nrcbf, WdT, bd, t2, Mn);
      neigh_attn<<<nb * TM1, blk, 0, stream>>>(QKVc, t1, qpx, vn, t2, qpn, b0, outn);
      gemm_mfma<<<dim3(6, (Mo + 127) / 128), blk, 0, stream>>>(
          outn, C_, Wtp, bp, poutnb, C_, nullptr, 0, 1, Mo, C_, C_);
      combine_main<<<nb * TM1, blk, 0, stream>>>(yspb, poutnb, x, lng, lnb, b0, dout);
      combine_neigh<<<nb * TM1 * KN_, blk, 0, stream>>>(poutnb, nrc, lng, lnb, b0,
                                                        dout + OUT1);
    }
  }
}

// Round 7
// 435.338 us; speedup vs baseline: 4.3524x; 1.0533x over previous
//
#include <hip/hip_runtime.h>
#include <math.h>

#define C_    768
#define H_    12
#define D_    64
#define B_    8
#define T_    512
#define TM1   511
#define R_    8
#define KN_   4
#define KC5   5
#define SCALE_ 0.5f
#define EPS_  1e-12f
#define NEG_  -1000000000.0f
#define INV_  0.125f   /* 1/sqrt(64) */
#define LDQ   2560     /* row stride of fused Q|K|V|qp output */
#define QPOFF 2304

typedef __bf16 bf16_t;
typedef __bf16 bf16x4_t __attribute__((ext_vector_type(4)));
typedef __bf16 bf16x8_t __attribute__((ext_vector_type(8)));
typedef float  f32x4_t  __attribute__((ext_vector_type(4)));
typedef const void __attribute__((address_space(1)))* gas_t;
typedef void       __attribute__((address_space(3)))* las_t;

__device__ __forceinline__ void gl_lds16(const bf16_t* g, bf16_t* l) {
  __builtin_amdgcn_global_load_lds((gas_t)g, (las_t)l, 16, 0, 0);
}

// ---------------------------------------------------------------------------
__global__ __launch_bounds__(256) void cvt_bf16(const float* __restrict__ in,
                                                bf16_t* __restrict__ out, long n) {
  long i = ((long)blockIdx.x * 256 + threadIdx.x) * 4;
  const long stride = (long)gridDim.x * 256 * 4;
  for (; i < n; i += stride) {
    float4 v = *(const float4*)(in + i);
    bf16x4_t o = { (bf16_t)v.x, (bf16_t)v.y, (bf16_t)v.z, (bf16_t)v.w };
    *(bf16x4_t*)(out + i) = o;
  }
}

// ---------------------------------------------------------------------------
// Weight transpose + convert: Wt[n][k] = (bf16) W[k][n], 768x768.
// ---------------------------------------------------------------------------
__global__ __launch_bounds__(256) void wtrans(const float* __restrict__ W,
                                              bf16_t* __restrict__ Wt) {
  __shared__ float tile[32][33];
  const int n0 = blockIdx.x * 32, k0 = blockIdx.y * 32;
  const int tx = threadIdx.x & 31, ty = threadIdx.x >> 5;
  #pragma unroll
  for (int r = ty; r < 32; r += 8)
    tile[r][tx] = W[(size_t)(k0 + r) * C_ + n0 + tx];
  __syncthreads();
  #pragma unroll
  for (int r = ty; r < 32; r += 8)
    Wt[(size_t)(n0 + r) * C_ + k0 + tx] = (bf16_t)tile[tx][r];
}

// ---------------------------------------------------------------------------
// Wqp[n=256][k=768]: per-head low-rank projection weight.
// ---------------------------------------------------------------------------
__global__ __launch_bounds__(256) void build_wqp(
    const float* __restrict__ Wu, const float* __restrict__ bu,
    bf16_t* __restrict__ Wqp) {
  int idx = blockIdx.x * 256 + threadIdx.x;   // 256*768
  int n = idx / C_, k = idx % C_;
  int h = n >> 4, r = n & 15;
  float v = 0.f;
  if (h < H_ && (k >> 6) == h) {
    if (r < 8) v = Wu[r * C_ + k];
    else if (r == 8) v = bu[k];
  }
  Wqp[idx] = (bf16_t)v;
}

// bfq[n=h*16+r]
__global__ __launch_bounds__(256) void build_bfq(
    const float* __restrict__ Wu, const float* __restrict__ bu,
    const float* __restrict__ bq, float* __restrict__ bfq) {
  int n = threadIdx.x;
  int h = n >> 4, r = n & 15;
  float s = 0.f;
  if (h < H_) {
    if (r < 8) {
      for (int k = 0; k < 64; ++k) s += bq[h * 64 + k] * Wu[r * C_ + h * 64 + k];
    } else if (r == 8) {
      for (int k = 0; k < 64; ++k) s += bq[h * 64 + k] * bu[h * 64 + k];
    }
  }
  bfq[n] = s;
}

// WdT[r][k] = Wd[k][r]
__global__ __launch_bounds__(256) void build_wdt(const float* __restrict__ Wd,
                                                 float* __restrict__ WdT) {
  int idx = blockIdx.x * 256 + threadIdx.x;
  if (idx < R_ * C_) {
    int r = idx / C_, k = idx % C_;
    WdT[idx] = Wd[k * R_ + r];
  }
}

// bias concat bq|bk|bv|bfq (2560)
__global__ __launch_bounds__(256) void cat_qkvq(
    const float* __restrict__ bq, const float* __restrict__ bk,
    const float* __restrict__ bv, const float* __restrict__ bfq,
    float* __restrict__ o) {
  int i = blockIdx.x * 256 + threadIdx.x;
  if (i >= 2560) return;
  float v;
  if (i < 768) v = bq[i];
  else if (i < 1536) v = bk[i - 768];
  else if (i < 2304) v = bv[i - 1536];
  else v = bfq[i - 2304];
  o[i] = v;
}

// ---------------------------------------------------------------------------
// bf16 MFMA GEMM, XCD-swizzled, with LDS-staged coalesced bf16 epilogue.
// mode bit0: write bf16 Cbf (ldc stride); bit1: also write transposed copy of
// cols [trcol0, trcol0+768) into Ctr [b][h][d=64][T=512] (needs M%512==0).
// ---------------------------------------------------------------------------
__global__ __launch_bounds__(256) void gemm_mfma(
    const bf16_t* __restrict__ A, int lda,
    const bf16_t* __restrict__ Bt,
    const float* __restrict__ bias,
    bf16_t* __restrict__ Cbf, int ldc,
    bf16_t* __restrict__ Ctr, int trcol0, int mode,
    int M, int K, int N)
{
  __shared__ bf16_t As[128 * 32];
  __shared__ bf16_t Bs[128 * 32];
  __shared__ bf16_t Cs[64 * 136];     // epilogue staging, +8 pad (2-way free)
  const int gx = gridDim.x;
  int lid = blockIdx.y * gx + blockIdx.x;
  {
    const int nwg = gx * gridDim.y;
    const int q0 = nwg >> 3, r0 = nwg & 7;
    const int xcd = lid & 7, idx = lid >> 3;
    lid = (xcd < r0 ? xcd * (q0 + 1) : r0 * (q0 + 1) + (xcd - r0) * q0) + idx;
  }
  const int row0 = (lid / gx) * 128;
  const int col0 = (lid % gx) * 128;

  const int tid = threadIdx.x;
  const int lane = tid & 63;
  const int wv = tid >> 6;
  const int wr = (wv >> 1) * 64;
  const int wc = (wv & 1) * 64;
  const int sr = tid >> 2;
  const int sk = (tid & 3) * 8;

  int ra0 = row0 + sr;       if (ra0 > M - 1) ra0 = M - 1;
  int ra1 = row0 + 64 + sr;  if (ra1 > M - 1) ra1 = M - 1;
  const bf16_t* ga0 = A + (size_t)ra0 * lda + sk;
  const bf16_t* ga1 = A + (size_t)ra1 * lda + sk;
  const bf16_t* gb0 = Bt + (size_t)(col0 + sr) * K + sk;
  const bf16_t* gb1 = Bt + (size_t)(col0 + 64 + sr) * K + sk;
  bf16_t* lA = As + wv * 512;
  bf16_t* lB = Bs + wv * 512;

  f32x4_t acc[4][4];
  #pragma unroll
  for (int i = 0; i < 4; ++i)
    #pragma unroll
    for (int j = 0; j < 4; ++j) acc[i][j] = (f32x4_t){0.f, 0.f, 0.f, 0.f};

  const int fm = lane & 15;
  const int kb = (lane >> 4) * 8;

  for (int k0 = 0; k0 < K; k0 += 32) {
    gl_lds16(ga0 + k0, lA);
    gl_lds16(ga1 + k0, lA + 2048);
    gl_lds16(gb0 + k0, lB);
    gl_lds16(gb1 + k0, lB + 2048);
    __syncthreads();
    bf16x8_t af[4], bfr[4];
    #pragma unroll
    for (int mi = 0; mi < 4; ++mi)
      af[mi] = *(const bf16x8_t*)(As + (wr + mi * 16 + fm) * 32 + kb);
    #pragma unroll
    for (int ni = 0; ni < 4; ++ni)
      bfr[ni] = *(const bf16x8_t*)(Bs + (wc + ni * 16 + fm) * 32 + kb);
    #pragma unroll
    for (int mi = 0; mi < 4; ++mi)
      #pragma unroll
      for (int ni = 0; ni < 4; ++ni)
        acc[mi][ni] = __builtin_amdgcn_mfma_f32_16x16x32_bf16(af[mi], bfr[ni],
                                                              acc[mi][ni], 0, 0, 0);
    __syncthreads();
  }

  const int r4 = (lane >> 4) * 4;

  // transposed-V side output (QKV GEMM only): small bf16x4 stores from regs
  if (mode & 2) {
    #pragma unroll
    for (int ni = 0; ni < 4; ++ni) {
      const int col = col0 + wc + ni * 16 + fm;
      if ((unsigned)(col - trcol0) < 768u) {
        const int vcol = col - trcol0;
        const float bv = bias[col];
        #pragma unroll
        for (int mi = 0; mi < 4; ++mi) {
          const int rb = row0 + wr + mi * 16 + r4;
          bf16x4_t o4 = {(bf16_t)(acc[mi][ni][0] + bv), (bf16_t)(acc[mi][ni][1] + bv),
                         (bf16_t)(acc[mi][ni][2] + bv), (bf16_t)(acc[mi][ni][3] + bv)};
          size_t idx = ((size_t)(rb >> 9) * H_ + (size_t)(vcol >> 6)) * ((size_t)D_ * T_)
                     + (size_t)(vcol & 63) * T_ + (size_t)(rb & 511);
          *(bf16x4_t*)(Ctr + idx) = o4;
        }
      }
    }
  }

  // LDS-staged coalesced epilogue (two 64-row passes)
  #pragma unroll
  for (int p = 0; p < 2; ++p) {
    if (wr == p * 64) {
      #pragma unroll
      for (int ni = 0; ni < 4; ++ni) {
        const int col = wc + ni * 16 + fm;
        const float bv = bias[col0 + col];
        #pragma unroll
        for (int mi = 0; mi < 4; ++mi) {
          const int lrow = mi * 16 + r4;
          #pragma unroll
          for (int r = 0; r < 4; ++r)
            Cs[(lrow + r) * 136 + col] = (bf16_t)(acc[mi][ni][r] + bv);
        }
      }
    }
    __syncthreads();
    const int rrow = tid >> 2;
    const int cc = (tid & 3) * 32;
    const int grow = row0 + p * 64 + rrow;
    if ((mode & 1) && grow < M) {
      bf16_t* gp = Cbf + (size_t)grow * ldc + col0 + cc;
      const bf16_t* lp = Cs + rrow * 136 + cc;
      #pragma unroll
      for (int j = 0; j < 4; ++j)
        *(bf16x8_t*)(gp + j * 8) = *(const bf16x8_t*)(lp + j * 8);
    }
    __syncthreads();
  }
}

// ---------------------------------------------------------------------------
// Narrow GEMV: out[M][8] = A(bf16,[M][768]) @ WdT^T + bd.
// ---------------------------------------------------------------------------
__global__ __launch_bounds__(256) void gemv8(
    const bf16_t* __restrict__ A, const float* __restrict__ WdT,
    const float* __restrict__ bd, float* __restrict__ out, int M)
{
  int row = blockIdx.x * 32 + (threadIdx.x >> 3);
  int r = threadIdx.x & 7;
  if (row >= M) return;
  const bf16_t* ar = A + (size_t)row * C_;
  const float* wr = WdT + r * C_;
  float acc = 0.f;
  for (int k = 0; k < C_; k += 8) {
    bf16x8_t av = *(const bf16x8_t*)(ar + k);
    float4 w0 = *(const float4*)(wr + k);
    float4 w1 = *(const float4*)(wr + k + 4);
    acc += (float)av[0]*w0.x + (float)av[1]*w0.y + (float)av[2]*w0.z + (float)av[3]*w0.w
         + (float)av[4]*w1.x + (float)av[5]*w1.y + (float)av[6]*w1.z + (float)av[7]*w1.w;
  }
  out[(size_t)row * R_ + r] = acc + bd[r];
}

// ---------------------------------------------------------------------------
// Small dense projection for the 8 cls rows.
// ---------------------------------------------------------------------------
__global__ __launch_bounds__(256) void gemv_cls(
    const float* __restrict__ A, const float* __restrict__ W,
    const float* __restrict__ bias, float* __restrict__ out)
{
  __shared__ float as[C_];
  const int row = blockIdx.x / 3;
  const int c = (blockIdx.x % 3) * 256 + threadIdx.x;
  for (int i = threadIdx.x; i < C_; i += 256) as[i] = A[(size_t)row * C_ + i];
  __syncthreads();
  float acc = bias[c];
  for (int k = 0; k < C_; ++k) acc += as[k] * W[(size_t)k * C_ + c];
  out[(size_t)row * C_ + c] = acc;
}

// ---------------------------------------------------------------------------
// MFMA flash self-attention; Q/K from fused QKVc (stride LDQ).
// ---------------------------------------------------------------------------
__global__ __launch_bounds__(256) void attn_mfma(
    const bf16_t* __restrict__ QKVc, const bf16_t* __restrict__ Vtg,
    const int* __restrict__ mask, bf16_t* __restrict__ yout)
{
  __shared__ bf16_t Ks[64 * 64];
  __shared__ bf16_t Vs[64 * 64];
  __shared__ bf16_t Pl[4][16 * 64];
  __shared__ float  fac_s[4][16];
  __shared__ float  l_s[4][16];
  __shared__ int    msk_s[64];

  const int b = blockIdx.z, h = blockIdx.y;
  const int qt0 = blockIdx.x * 64;
  const int tid = threadIdx.x;
  const int lane = tid & 63;
  const int w = tid >> 6;
  const int lq = lane & 15;
  const int g = lane >> 4;

  const int qi_frag = qt0 + w * 16 + lq;
  const int qtok = (qi_frag < TM1 ? qi_frag : TM1 - 1) + 1;
  bf16x8_t qf[2];
  {
    const bf16_t* qp = QKVc + ((size_t)(b * T_) + qtok) * LDQ + h * D_ + 8 * g;
    qf[0] = *(const bf16x8_t*)qp;
    qf[1] = *(const bf16x8_t*)(qp + 32);
  }

  const bf16_t* kbase = QKVc + (size_t)(b * T_) * LDQ + 768 + h * D_;
  const bf16_t* vbase = Vtg + ((size_t)(b * H_) + h) * ((size_t)D_ * T_);

  f32x4_t o[4];
  #pragma unroll
  for (int i = 0; i < 4; ++i) o[i] = (f32x4_t){0.f, 0.f, 0.f, 0.f};
  float m = -INFINITY, l = 0.f;

  for (int kt = 0; kt < T_; kt += 64) {
    #pragma unroll
    for (int i = 0; i < 2; ++i) {
      const int tp = tid + i * 256;
      const int kr = tp >> 3;
      const int sl = tp & 7;
      const int ss = sl ^ (kr & 7);
      gl_lds16(kbase + (size_t)(kt + kr) * LDQ + 8 * ss,
               Ks + (size_t)(i * 4 + w) * 512);
      gl_lds16(vbase + (size_t)kr * T_ + kt + 8 * ss,
               Vs + (size_t)(i * 4 + w) * 512);
    }
    if (tid < 64) msk_s[tid] = mask[b * T_ + kt + tid];
    __syncthreads();

    f32x4_t st[4];
    #pragma unroll
    for (int t = 0; t < 4; ++t) {
      st[t] = (f32x4_t){0.f, 0.f, 0.f, 0.f};
      const int kk = t * 16 + lq;
      const bf16_t* krow = Ks + kk * 64;
      bf16x8_t kf0 = *(const bf16x8_t*)(krow + 8 * ((g)     ^ (kk & 7)));
      bf16x8_t kf1 = *(const bf16x8_t*)(krow + 8 * ((4 + g) ^ (kk & 7)));
      st[t] = __builtin_amdgcn_mfma_f32_16x16x32_bf16(kf0, qf[0], st[t], 0, 0, 0);
      st[t] = __builtin_amdgcn_mfma_f32_16x16x32_bf16(kf1, qf[1], st[t], 0, 0, 0);
    }

    float p[16];
    float mt = -INFINITY;
    #pragma unroll
    for (int t = 0; t < 4; ++t) {
      const int4 mk = *(const int4*)&msk_s[t * 16 + 4 * g];
      p[4*t+0] = mk.x ? st[t][0] * INV_ : NEG_;
      p[4*t+1] = mk.y ? st[t][1] * INV_ : NEG_;
      p[4*t+2] = mk.z ? st[t][2] * INV_ : NEG_;
      p[4*t+3] = mk.w ? st[t][3] * INV_ : NEG_;
      mt = fmaxf(mt, fmaxf(fmaxf(p[4*t], p[4*t+1]), fmaxf(p[4*t+2], p[4*t+3])));
    }
    mt = fmaxf(mt, __shfl_xor(mt, 16));
    mt = fmaxf(mt, __shfl_xor(mt, 32));
    const float mnew = fmaxf(m, mt);
    const float fac = __expf(m - mnew);
    float ps = 0.f;
    #pragma unroll
    for (int i = 0; i < 16; ++i) { p[i] = __expf(p[i] - mnew); ps += p[i]; }
    ps += __shfl_xor(ps, 16);
    ps += __shfl_xor(ps, 32);
    l = l * fac + ps;
    m = mnew;
    if (lane < 16) fac_s[w][lane] = fac;

    bf16_t* prow = Pl[w] + lq * 64;
    #pragma unroll
    for (int t = 0; t < 4; ++t) {
      bf16x4_t pb = {(bf16_t)p[4*t], (bf16_t)p[4*t+1],
                     (bf16_t)p[4*t+2], (bf16_t)p[4*t+3]};
      *(bf16x4_t*)(prow + 8 * ((2*t + (g >> 1)) ^ (lq & 7)) + 4 * (g & 1)) = pb;
    }
    bf16x8_t pa0 = *(const bf16x8_t*)(prow + 8 * ((g)     ^ (lq & 7)));
    bf16x8_t pa1 = *(const bf16x8_t*)(prow + 8 * ((4 + g) ^ (lq & 7)));

    const float4 fc = *(const float4*)&fac_s[w][4 * g];
    #pragma unroll
    for (int db = 0; db < 4; ++db) {
      const int dr = db * 16 + lq;
      const bf16_t* vrow = Vs + dr * 64;
      bf16x8_t vf0 = *(const bf16x8_t*)(vrow + 8 * ((g)     ^ (dr & 7)));
      bf16x8_t vf1 = *(const bf16x8_t*)(vrow + 8 * ((4 + g) ^ (dr & 7)));
      o[db][0] *= fc.x; o[db][1] *= fc.y; o[db][2] *= fc.z; o[db][3] *= fc.w;
      o[db] = __builtin_amdgcn_mfma_f32_16x16x32_bf16(pa0, vf0, o[db], 0, 0, 0);
      o[db] = __builtin_amdgcn_mfma_f32_16x16x32_bf16(pa1, vf1, o[db], 0, 0, 0);
    }
    __syncthreads();
  }

  if (lane < 16) l_s[w][lane] = l;
  const float4 lv = *(const float4*)&l_s[w][4 * g];
  const float rl0 = 1.f / lv.x, rl1 = 1.f / lv.y;
  const float rl2 = 1.f / lv.z, rl3 = 1.f / lv.w;
  const int qr0 = qt0 + w * 16 + 4 * g;
  #pragma unroll
  for (int db = 0; db < 4; ++db) {
    const int col = h * D_ + db * 16 + lq;
    bf16_t* yp = yout + ((size_t)(b * TM1) + qr0) * C_ + col;
    if (qr0 + 0 < TM1) yp[0 * (size_t)C_] = (bf16_t)(o[db][0] * rl0);
    if (qr0 + 1 < TM1) yp[1 * (size_t)C_] = (bf16_t)(o[db][1] * rl1);
    if (qr0 + 2 < TM1) yp[2 * (size_t)C_] = (bf16_t)(o[db][2] * rl2);
    if (qr0 + 3 < TM1) yp[3 * (size_t)C_] = (bf16_t)(o[db][3] * rl3);
  }
}

// ---------------------------------------------------------------------------
// cls attention via low-rank keys.
// ---------------------------------------------------------------------------
__global__ __launch_bounds__(64) void cls_attn(
    const bf16_t* __restrict__ QKVc, const float* __restrict__ t1,
    const int* __restrict__ mask, float* __restrict__ yout /* (B,768) */)
{
  __shared__ float qp_s[16];
  __shared__ float Vs[64][65];
  __shared__ float Ps[64];

  const int b = blockIdx.x / H_, h = blockIdx.x % H_;
  const int lane = threadIdx.x;

  if (lane < 16)
    qp_s[lane] = (float)QKVc[(size_t)(b * T_) * LDQ + QPOFF + h * 16 + lane];
  __syncthreads();

  float m = -INFINITY, l = 0.f, acc = 0.f;
  for (int kt = 0; kt < T_; kt += 64) {
    for (int rr = 0; rr < 64; ++rr)
      Vs[rr][lane] = (float)QKVc[((size_t)(b * T_) + kt + rr) * LDQ + 1536 + h * D_ + lane];
    __syncthreads();
    const float* t1r = t1 + ((size_t)(b * T_) + kt + lane) * R_;
    float sc = qp_s[8];
    #pragma unroll
    for (int r = 0; r < 8; ++r) sc += qp_s[r] * t1r[r];
    sc *= INV_;
    if (!mask[b * T_ + kt + lane]) sc = NEG_;
    float mt = sc;
    #pragma unroll
    for (int off = 32; off > 0; off >>= 1) mt = fmaxf(mt, __shfl_xor(mt, off));
    float mnew = fmaxf(m, mt);
    float e = __expf(sc - mnew);
    float ssum = e;
    #pragma unroll
    for (int off = 32; off > 0; off >>= 1) ssum += __shfl_xor(ssum, off);
    float fac = __expf(m - mnew);
    acc *= fac;
    l = l * fac + ssum;
    Ps[lane] = e;
    __syncthreads();
    #pragma unroll
    for (int j = 0; j < 64; ++j) acc += Ps[j] * Vs[j][lane];
    m = mnew;
    __syncthreads();
  }
  yout[(size_t)b * C_ + h * D_ + lane] = acc / l;
}

// ---------------------------------------------------------------------------
// Neighbour attention via low-rank keys.  vqn rows: [768 v | 256 qp].
// ---------------------------------------------------------------------------
__global__ __launch_bounds__(256) void neigh_attn(
    const bf16_t* __restrict__ QKVc, const float* __restrict__ t1,
    const bf16_t* __restrict__ vqn,  /* [rows][1024] */
    const float* __restrict__ t2,    /* [rows][8] */
    int b0, bf16_t* __restrict__ outn)
{
  __shared__ float vs[KC5 * C_];
  __shared__ float qp_s[KC5][200];
  __shared__ float t2_s[KC5][8];
  __shared__ float Ps[H_ * 25];

  const int bt = blockIdx.x;
  const int bb = bt / TM1, t = bt % TM1;
  const int b = b0 + bb;
  const int tid = threadIdx.x;
  const size_t tok = (size_t)(b * T_) + t + 1;
  const size_t nrow = ((size_t)(bb * TM1) + t) * KN_;

  for (int idx = tid; idx < KC5 * 96; idx += 256) {
    int i = idx / 96, d8 = (idx % 96) * 8;
    const bf16_t* vp = (i == 0) ? QKVc + tok * LDQ + 1536 + d8
                                : vqn + (nrow + i - 1) * 1024 + d8;
    bf16x8_t vv = *(const bf16x8_t*)vp;
    #pragma unroll
    for (int j = 0; j < 8; ++j) vs[i * C_ + d8 + j] = (float)vv[j];
  }
  for (int idx = tid; idx < KC5 * 24; idx += 256) {
    int i = idx / 24, c8 = (idx % 24) * 8;
    const bf16_t* qpp = (i == 0) ? QKVc + tok * LDQ + QPOFF + c8
                                 : vqn + (nrow + i - 1) * 1024 + 768 + c8;
    bf16x8_t qv = *(const bf16x8_t*)qpp;
    #pragma unroll
    for (int j = 0; j < 8; ++j) qp_s[i][c8 + j] = (float)qv[j];
  }
  if (tid < KC5 * 8) {
    int i = tid / 8, r = tid & 7;
    t2_s[i][r] = (i == 0) ? t1[tok * R_ + r] : t2[(nrow + i - 1) * R_ + r];
  }
  __syncthreads();

  if (tid < H_ * KC5) {
    int h = tid / KC5, i = tid % KC5;
    float sc[KC5];
    #pragma unroll
    for (int j = 0; j < KC5; ++j) {
      float s = qp_s[i][h * 16 + 8];
      #pragma unroll
      for (int r = 0; r < 8; ++r) s += qp_s[i][h * 16 + r] * t2_s[j][r];
      sc[j] = s * INV_;
    }
    float mt = sc[0];
    #pragma unroll
    for (int j = 1; j < KC5; ++j) mt = fmaxf(mt, sc[j]);
    float e[KC5], ssum = 0.f;
    #pragma unroll
    for (int j = 0; j < KC5; ++j) { e[j] = __expf(sc[j] - mt); ssum += e[j]; }
    float rs = 1.f / ssum;
    #pragma unroll
    for (int j = 0; j < KC5; ++j) Ps[h * 25 + i * KC5 + j] = e[j] * rs;
  }
  __syncthreads();

  for (int idx = tid; idx < KC5 * C_; idx += 256) {
    int i = idx / C_, c = idx % C_;
    int h = c / D_;
    float sum = 0.f;
    #pragma unroll
    for (int j = 0; j < KC5; ++j)
      sum += Ps[h * 25 + i * KC5 + j] * vs[j * C_ + c];
    outn[(((size_t)(bb * TM1) + t) * KC5 + i) * C_ + c] = (bf16_t)sum;
  }
}

// ---------------------------------------------------------------------------
// Residual + LayerNorm combine kernels
// ---------------------------------------------------------------------------
__device__ __forceinline__ void block_reduce2(float& s, float& ss, float* red) {
  #pragma unroll
  for (int off = 32; off > 0; off >>= 1) {
    s += __shfl_down(s, off);
    ss += __shfl_down(ss, off);
  }
  int wid = threadIdx.x >> 6;
  if ((threadIdx.x & 63) == 0) { red[wid * 2] = s; red[wid * 2 + 1] = ss; }
  __syncthreads();
  s  = red[0] + red[2] + red[4] + red[6];
  ss = red[1] + red[3] + red[5] + red[7];
}

__device__ __forceinline__ void ln_row(const float vals[3], float s, float ss,
                                       const float* __restrict__ g,
                                       const float* __restrict__ bb,
                                       float* __restrict__ orow, float* red) {
  block_reduce2(s, ss, red);
  float mean = s * (1.f / (float)C_);
  float var = ss * (1.f / (float)C_) - mean * mean;
  var = fmaxf(var, 0.f);
  float rs = rsqrtf(var + EPS_);
  #pragma unroll
  for (int ii = 0; ii < 3; ++ii) {
    int c = threadIdx.x + ii * 256;
    orow[c] = (vals[ii] - mean) * rs * g[c] + bb[c];
  }
}

__global__ __launch_bounds__(256) void combine_main(
    const bf16_t* __restrict__ yselfP, const bf16_t* __restrict__ poutn,
    const float* __restrict__ x, const float* __restrict__ g,
    const float* __restrict__ bln, int b0, float* __restrict__ dout)
{
  __shared__ float red[8];
  const int bt = blockIdx.x;
  const int bbb = bt / TM1, t = bt % TM1;
  const int b = b0 + bbb;
  const bf16_t* ys = yselfP + ((size_t)(b * TM1) + t) * C_;
  const bf16_t* pn = poutn + (((size_t)(bbb * TM1) + t) * KC5 + 0) * C_;
  const float* xr = x + ((size_t)(b * T_) + t + 1) * C_;
  float* orow = dout + ((size_t)(b * T_) + t + 1) * C_;
  float vals[3], s = 0.f, ss = 0.f;
  #pragma unroll
  for (int ii = 0; ii < 3; ++ii) {
    int c = threadIdx.x + ii * 256;
    float v = SCALE_ * (float)pn[c] + (1.f - SCALE_) * (float)ys[c] + xr[c];
    vals[ii] = v; s += v; ss += v * v;
  }
  ln_row(vals, s, ss, g, bln, orow, red);
}

__global__ __launch_bounds__(256) void combine_neigh(
    const bf16_t* __restrict__ poutn, const float* __restrict__ nrc,
    const float* __restrict__ g, const float* __restrict__ bln,
    int b0, float* __restrict__ dout)
{
  __shared__ float red[8];
  const int idx = blockIdx.x;
  const int i1 = idx % KN_;
  const int bt = idx / KN_;
  const int bbb = bt / TM1, t = bt % TM1;
  const int b = b0 + bbb;
  const bf16_t* pn = poutn + ((size_t)bt * KC5 + 1 + i1) * C_;
  const float* nr = nrc + ((size_t)bt * KN_ + i1) * C_;
  float* orow = dout + (((size_t)(b * TM1) + t) * KN_ + i1) * C_;
  float vals[3], s = 0.f, ss = 0.f;
  #pragma unroll
  for (int ii = 0; ii < 3; ++ii) {
    int c = threadIdx.x + ii * 256;
    float v = (float)pn[c] + nr[c];
    vals[ii] = v; s += v; ss += v * v;
  }
  ln_row(vals, s, ss, g, bln, orow, red);
}

__global__ __launch_bounds__(256) void combine_cls(
    const float* __restrict__ yclsP, const float* __restrict__ x,
    const float* __restrict__ g, const float* __restrict__ bln,
    float* __restrict__ dout)
{
  __shared__ float red[8];
  const int b = blockIdx.x;
  const float* yc = yclsP + (size_t)b * C_;
  const float* xr = x + (size_t)(b * T_) * C_;
  float* orow = dout + (size_t)(b * T_) * C_;
  float vals[3], s = 0.f, ss = 0.f;
  #pragma unroll
  for (int ii = 0; ii < 3; ++ii) {
    int c = threadIdx.x + ii * 256;
    float v = yc[c] + xr[c];
    vals[ii] = v; s += v; ss += v * v;
  }
  ln_row(vals, s, ss, g, bln, orow, red);
}

// ---------------------------------------------------------------------------
extern "C" void kernel_launch(void* const* d_in, const int* in_sizes, int n_in,
                              void* d_out, int out_size, void* d_ws, size_t ws_size,
                              hipStream_t stream) {
  (void)in_sizes; (void)n_in; (void)out_size;
  const float* x    = (const float*)d_in[0];
  const int*   mask = (const int*)d_in[1];
  const float* nrep = (const float*)d_in[2];
  const float* Wq = (const float*)d_in[3];  const float* bq = (const float*)d_in[4];
  const float* Wk = (const float*)d_in[5];  const float* bk = (const float*)d_in[6];
  const float* Wv = (const float*)d_in[7];  const float* bv = (const float*)d_in[8];
  const float* Wp = (const float*)d_in[9];  const float* bp = (const float*)d_in[10];
  const float* Wd = (const float*)d_in[11]; const float* bd = (const float*)d_in[12];
  const float* Wu = (const float*)d_in[13]; const float* bu = (const float*)d_in[14];
  const float* lng = (const float*)d_in[15];
  const float* lnb = (const float*)d_in[16];
  float* dout = (float*)d_out;
  const size_t OUT1 = (size_t)B_ * T_ * C_;

  char* ws = (char*)d_ws;
  size_t off = 0;
  auto alloc = [&](size_t bytes) -> void* {
    void* p = ws + off; off += (bytes + 255) & ~(size_t)255; return p;
  };
  const size_t NT = (size_t)B_ * T_;
  const size_t NR = (size_t)B_ * TM1 * KN_;
  const size_t YSROWS = (size_t)B_ * TM1;     // 4088

  bf16_t* xbf   = (bf16_t*)alloc(NT * C_ * 2);
  bf16_t* nrbf  = (bf16_t*)alloc(NR * C_ * 2);
  bf16_t* Wbig  = (bf16_t*)alloc((size_t)2560 * C_ * 2);   // WqT|WkT|WvT|WfqT
  bf16_t* Wtp   = (bf16_t*)alloc((size_t)C_ * C_ * 2);
  bf16_t* Wqp   = (bf16_t*)alloc((size_t)256 * C_ * 2);
  bf16_t* Wqbf  = (bf16_t*)alloc((size_t)C_ * C_ * 2);
  float*  WdT   = (float*)alloc((size_t)R_ * C_ * 4);
  float*  bbig  = (float*)alloc(2560 * 4);
  float*  bfq   = (float*)alloc(256 * 4);
  float*  zb768 = (float*)alloc(768 * 4);
  bf16_t* QKVc  = (bf16_t*)alloc(NT * LDQ * 2);
  bf16_t* Vtg   = (bf16_t*)alloc(NT * C_ * 2);   // [b][h][d][T]
  float*  t1    = (float*)alloc(NT * R_ * 4);
  float*  ych   = (float*)alloc((size_t)B_ * C_ * 4);
  float*  ycp   = (float*)alloc((size_t)B_ * C_ * 4);
  const size_t fixed = off + 2 * (YSROWS * C_ * 2 + 256);
  const size_t perb = (size_t)TM1 * KN_ * 1024 * 2
                    + (size_t)TM1 * KN_ * R_ * 4
                    + (size_t)TM1 * KC5 * C_ * 2 * 2 + 5 * 256;
  int nb = 1;
  for (int cand : {8, 4, 2, 1}) {
    if (fixed + perb * (size_t)cand <= ws_size) { nb = cand; break; }
  }
  bf16_t* proj_in  = (bf16_t*)alloc((YSROWS + (size_t)nb * TM1 * KC5) * C_ * 2);
  bf16_t* proj_out = (bf16_t*)alloc((YSROWS + (size_t)nb * TM1 * KC5) * C_ * 2);
  bf16_t* vqn  = (bf16_t*)alloc((size_t)nb * TM1 * KN_ * 1024 * 2);
  float*  t2   = (float*)alloc((size_t)nb * TM1 * KN_ * R_ * 4);
  bf16_t* ysh    = proj_in;
  bf16_t* outn   = proj_in + YSROWS * C_;
  bf16_t* yspb   = proj_out;
  bf16_t* poutnb = proj_out + YSROWS * C_;

  dim3 blk(256);
  dim3 tg(C_ / 32, C_ / 32);

  // ---- prep ----
  cvt_bf16<<<1024, blk, 0, stream>>>(x, xbf, (long)(NT * C_));
  cvt_bf16<<<2048, blk, 0, stream>>>(nrep, nrbf, (long)(NR * C_));
  cvt_bf16<<<576, blk, 0, stream>>>(Wq, Wqbf, (long)C_ * C_);
  wtrans<<<tg, blk, 0, stream>>>(Wq, Wbig);
  wtrans<<<tg, blk, 0, stream>>>(Wk, Wbig + (size_t)C_ * C_);
  wtrans<<<tg, blk, 0, stream>>>(Wv, Wbig + (size_t)2 * C_ * C_);
  wtrans<<<tg, blk, 0, stream>>>(Wp, Wtp);
  build_wqp<<<(256 * C_) / 256, blk, 0, stream>>>(Wu, bu, Wqp);
  build_bfq<<<1, blk, 0, stream>>>(Wu, bu, bq, bfq);
  build_wdt<<<24, blk, 0, stream>>>(Wd, WdT);
  cat_qkvq<<<10, blk, 0, stream>>>(bq, bk, bv, bfq, bbig);
  hipMemsetAsync(zb768, 0, 768 * 4, stream);
  // fused low-rank query weight into Wbig rows 2304..2559
  gemm_mfma<<<dim3(6, 2), blk, 0, stream>>>(Wqp, C_, Wqbf, zb768,
                                            Wbig + (size_t)QPOFF * C_, C_,
                                            nullptr, 0, 1, 256, C_, C_);

  // ---- self path: fused Q|K|V|qp projection ----
  gemm_mfma<<<dim3(20, 32), blk, 0, stream>>>(xbf, C_, Wbig, bbig,
                                              QKVc, LDQ, Vtg, 1536, 3,
                                              (int)NT, C_, 2560);
  gemv8<<<(int)(NT / 32), blk, 0, stream>>>(xbf, WdT, bd, t1, (int)NT);

  attn_mfma<<<dim3(8, H_, B_), blk, 0, stream>>>(QKVc, Vtg, mask, ysh);

  cls_attn<<<B_ * H_, 64, 0, stream>>>(QKVc, t1, mask, ych);
  gemv_cls<<<B_ * 3, blk, 0, stream>>>(ych, Wp, bp, ycp);
  combine_cls<<<B_, blk, 0, stream>>>(ycp, x, lng, lnb, dout);

  if (nb == 8) {
    const int Mn = 8 * TM1 * KN_;    // 16352
    gemm_mfma<<<dim3(8, (Mn + 127) / 128), blk, 0, stream>>>(
        nrbf, C_, Wbig + (size_t)1536 * C_, bbig + 1536,
        vqn, 1024, nullptr, 0, 1, Mn, C_, 1024);
    gemv8<<<(Mn + 31) / 32, blk, 0, stream>>>(nrbf, WdT, bd, t2, Mn);
    neigh_attn<<<8 * TM1, blk, 0, stream>>>(QKVc, t1, vqn, t2, 0, outn);
    const int Mp = (int)YSROWS + 8 * TM1 * KC5;   // 24528
    gemm_mfma<<<dim3(6, (Mp + 127) / 128), blk, 0, stream>>>(
        proj_in, C_, Wtp, bp, proj_out, C_, nullptr, 0, 1, Mp, C_, C_);
    combine_main<<<8 * TM1, blk, 0, stream>>>(yspb, poutnb, x, lng, lnb, 0, dout);
    combine_neigh<<<8 * TM1 * KN_, blk, 0, stream>>>(poutnb, nrep, lng, lnb, 0,
                                                     dout + OUT1);
  } else {
    gemm_mfma<<<dim3(6, 32), blk, 0, stream>>>(ysh, C_, Wtp, bp,
                                               yspb, C_, nullptr, 0, 1,
                                               (int)YSROWS, C_, C_);
    for (int b0 = 0; b0 < B_; b0 += nb) {
      const int Mn = nb * TM1 * KN_;
      const int Mo = nb * TM1 * KC5;
      const float*  nrc   = nrep + (size_t)b0 * TM1 * KN_ * C_;
      const bf16_t* nrcbf = nrbf + (size_t)b0 * TM1 * KN_ * C_;
      gemm_mfma<<<dim3(8, (Mn + 127) / 128), blk, 0, stream>>>(
          nrcbf, C_, Wbig + (size_t)1536 * C_, bbig + 1536,
          vqn, 1024, nullptr, 0, 1, Mn, C_, 1024);
      gemv8<<<(Mn + 31) / 32, blk, 0, stream>>>(nrcbf, WdT, bd, t2, Mn);
      neigh_attn<<<nb * TM1, blk, 0, stream>>>(QKVc, t1, vqn, t2, b0, outn);
      gemm_mfma<<<dim3(6, (Mo + 127) / 128), blk, 0, stream>>>(
          outn, C_, Wtp, bp, poutnb, C_, nullptr, 0, 1, Mo, C_, C_);
      combine_main<<<nb * TM1, blk, 0, stream>>>(yspb, poutnb, x, lng, lnb, b0, dout);
      combine_neigh<<<nb * TM1 * KN_, blk, 0, stream>>>(poutnb, nrc, lng, lnb, b0,
                                                        dout + OUT1);
    }
  }
}

// Round 8
// 427.862 us; speedup vs baseline: 4.4284x; 1.0175x over previous
//
#include <hip/hip_runtime.h>
#include <math.h>

#define C_    768
#define H_    12
#define D_    64
#define B_    8
#define T_    512
#define TM1   511
#define R_    8
#define KN_   4
#define KC5   5
#define SCALE_ 0.5f
#define EPS_  1e-12f
#define NEG_  -1000000000.0f
#define INV_  0.125f   /* 1/sqrt(64) */
#define LDQ   2560     /* row stride of fused Q|K|V|qp output */
#define QPOFF 2304

typedef __bf16 bf16_t;
typedef __bf16 bf16x4_t __attribute__((ext_vector_type(4)));
typedef __bf16 bf16x8_t __attribute__((ext_vector_type(8)));
typedef float  f32x4_t  __attribute__((ext_vector_type(4)));
typedef const void __attribute__((address_space(1)))* gas_t;
typedef void       __attribute__((address_space(3)))* las_t;

__device__ __forceinline__ void gl_lds16(const bf16_t* g, bf16_t* l) {
  __builtin_amdgcn_global_load_lds((gas_t)g, (las_t)l, 16, 0, 0);
}

// LDS slot swizzle for [row][32elem] tiles (64-B rows, 4x16-B slots):
// slot' = slot ^ ((row>>1)&3)  -> 2-way (free) bank pattern on frag reads.
__device__ __forceinline__ int swz(int row, int g) {
  return row * 32 + (((g ^ (row >> 1)) & 3) << 3);
}

// ---------------------------------------------------------------------------
__global__ __launch_bounds__(256) void cvt_bf16(const float* __restrict__ in,
                                                bf16_t* __restrict__ out, long n) {
  long i = ((long)blockIdx.x * 256 + threadIdx.x) * 4;
  const long stride = (long)gridDim.x * 256 * 4;
  for (; i < n; i += stride) {
    float4 v = *(const float4*)(in + i);
    bf16x4_t o = { (bf16_t)v.x, (bf16_t)v.y, (bf16_t)v.z, (bf16_t)v.w };
    *(bf16x4_t*)(out + i) = o;
  }
}

// ---------------------------------------------------------------------------
// Weight transpose + convert: Wt[n][k] = (bf16) W[k][n], 768x768.
// ---------------------------------------------------------------------------
__global__ __launch_bounds__(256) void wtrans(const float* __restrict__ W,
                                              bf16_t* __restrict__ Wt) {
  __shared__ float tile[32][33];
  const int n0 = blockIdx.x * 32, k0 = blockIdx.y * 32;
  const int tx = threadIdx.x & 31, ty = threadIdx.x >> 5;
  #pragma unroll
  for (int r = ty; r < 32; r += 8)
    tile[r][tx] = W[(size_t)(k0 + r) * C_ + n0 + tx];
  __syncthreads();
  #pragma unroll
  for (int r = ty; r < 32; r += 8)
    Wt[(size_t)(n0 + r) * C_ + k0 + tx] = (bf16_t)tile[tx][r];
}

// ---------------------------------------------------------------------------
// Wqp[n=256][k=768]: per-head low-rank projection weight.
// ---------------------------------------------------------------------------
__global__ __launch_bounds__(256) void build_wqp(
    const float* __restrict__ Wu, const float* __restrict__ bu,
    bf16_t* __restrict__ Wqp) {
  int idx = blockIdx.x * 256 + threadIdx.x;   // 256*768
  int n = idx / C_, k = idx % C_;
  int h = n >> 4, r = n & 15;
  float v = 0.f;
  if (h < H_ && (k >> 6) == h) {
    if (r < 8) v = Wu[r * C_ + k];
    else if (r == 8) v = bu[k];
  }
  Wqp[idx] = (bf16_t)v;
}

// bfq[n=h*16+r]
__global__ __launch_bounds__(256) void build_bfq(
    const float* __restrict__ Wu, const float* __restrict__ bu,
    const float* __restrict__ bq, float* __restrict__ bfq) {
  int n = threadIdx.x;
  int h = n >> 4, r = n & 15;
  float s = 0.f;
  if (h < H_) {
    if (r < 8) {
      for (int k = 0; k < 64; ++k) s += bq[h * 64 + k] * Wu[r * C_ + h * 64 + k];
    } else if (r == 8) {
      for (int k = 0; k < 64; ++k) s += bq[h * 64 + k] * bu[h * 64 + k];
    }
  }
  bfq[n] = s;
}

// WdT[r][k] = Wd[k][r]
__global__ __launch_bounds__(256) void build_wdt(const float* __restrict__ Wd,
                                                 float* __restrict__ WdT) {
  int idx = blockIdx.x * 256 + threadIdx.x;
  if (idx < R_ * C_) {
    int r = idx / C_, k = idx % C_;
    WdT[idx] = Wd[k * R_ + r];
  }
}

// bias concat bq|bk|bv|bfq (2560)
__global__ __launch_bounds__(256) void cat_qkvq(
    const float* __restrict__ bq, const float* __restrict__ bk,
    const float* __restrict__ bv, const float* __restrict__ bfq,
    float* __restrict__ o) {
  int i = blockIdx.x * 256 + threadIdx.x;
  if (i >= 2560) return;
  float v;
  if (i < 768) v = bq[i];
  else if (i < 1536) v = bk[i - 768];
  else if (i < 2304) v = bv[i - 1536];
  else v = bfq[i - 2304];
  o[i] = v;
}

// ---------------------------------------------------------------------------
// bf16 MFMA GEMM, XCD-swizzled, slot-swizzled LDS, LDS-staged coalesced
// epilogue.  mode bit0: write bf16 Cbf; bit1: + transposed copy of cols
// [trcol0,trcol0+768) into Ctr [b][h][d=64][T=512] (needs M%512==0).
// ---------------------------------------------------------------------------
__global__ __launch_bounds__(256) void gemm_mfma(
    const bf16_t* __restrict__ A, int lda,
    const bf16_t* __restrict__ Bt,
    const float* __restrict__ bias,
    bf16_t* __restrict__ Cbf, int ldc,
    bf16_t* __restrict__ Ctr, int trcol0, int mode,
    int M, int K, int N)
{
  __shared__ bf16_t As[128 * 32];
  __shared__ bf16_t Bs[128 * 32];
  __shared__ bf16_t Cs[64 * 136];
  const int gx = gridDim.x;
  int lid = blockIdx.y * gx + blockIdx.x;
  {
    const int nwg = gx * gridDim.y;
    const int q0 = nwg >> 3, r0 = nwg & 7;
    const int xcd = lid & 7, idx = lid >> 3;
    lid = (xcd < r0 ? xcd * (q0 + 1) : r0 * (q0 + 1) + (xcd - r0) * q0) + idx;
  }
  const int row0 = (lid / gx) * 128;
  const int col0 = (lid % gx) * 128;

  const int tid = threadIdx.x;
  const int lane = tid & 63;
  const int wv = tid >> 6;
  const int wr = (wv >> 1) * 64;
  const int wc = (wv & 1) * 64;
  const int sr = tid >> 2;                 // staging LDS row 0..63
  const int ssl = (tid & 3) ^ ((sr >> 1) & 3);   // pre-swizzled source slot
  const int sk = ssl * 8;

  int ra0 = row0 + sr;       if (ra0 > M - 1) ra0 = M - 1;
  int ra1 = row0 + 64 + sr;  if (ra1 > M - 1) ra1 = M - 1;
  const bf16_t* ga0 = A + (size_t)ra0 * lda + sk;
  const bf16_t* ga1 = A + (size_t)ra1 * lda + sk;
  const bf16_t* gb0 = Bt + (size_t)(col0 + sr) * K + sk;
  const bf16_t* gb1 = Bt + (size_t)(col0 + 64 + sr) * K + sk;
  bf16_t* lA = As + wv * 512;
  bf16_t* lB = Bs + wv * 512;

  f32x4_t acc[4][4];
  #pragma unroll
  for (int i = 0; i < 4; ++i)
    #pragma unroll
    for (int j = 0; j < 4; ++j) acc[i][j] = (f32x4_t){0.f, 0.f, 0.f, 0.f};

  const int fm = lane & 15;
  const int g = lane >> 4;

  for (int k0 = 0; k0 < K; k0 += 32) {
    gl_lds16(ga0 + k0, lA);
    gl_lds16(ga1 + k0, lA + 2048);
    gl_lds16(gb0 + k0, lB);
    gl_lds16(gb1 + k0, lB + 2048);
    __syncthreads();
    bf16x8_t af[4], bfr[4];
    #pragma unroll
    for (int mi = 0; mi < 4; ++mi)
      af[mi] = *(const bf16x8_t*)(As + swz(wr + mi * 16 + fm, g));
    #pragma unroll
    for (int ni = 0; ni < 4; ++ni)
      bfr[ni] = *(const bf16x8_t*)(Bs + swz(wc + ni * 16 + fm, g));
    #pragma unroll
    for (int mi = 0; mi < 4; ++mi)
      #pragma unroll
      for (int ni = 0; ni < 4; ++ni)
        acc[mi][ni] = __builtin_amdgcn_mfma_f32_16x16x32_bf16(af[mi], bfr[ni],
                                                              acc[mi][ni], 0, 0, 0);
    __syncthreads();
  }

  const int r4 = (lane >> 4) * 4;

  if (mode & 2) {
    #pragma unroll
    for (int ni = 0; ni < 4; ++ni) {
      const int col = col0 + wc + ni * 16 + fm;
      if ((unsigned)(col - trcol0) < 768u) {
        const int vcol = col - trcol0;
        const float bv = bias[col];
        #pragma unroll
        for (int mi = 0; mi < 4; ++mi) {
          const int rb = row0 + wr + mi * 16 + r4;
          bf16x4_t o4 = {(bf16_t)(acc[mi][ni][0] + bv), (bf16_t)(acc[mi][ni][1] + bv),
                         (bf16_t)(acc[mi][ni][2] + bv), (bf16_t)(acc[mi][ni][3] + bv)};
          size_t idx = ((size_t)(rb >> 9) * H_ + (size_t)(vcol >> 6)) * ((size_t)D_ * T_)
                     + (size_t)(vcol & 63) * T_ + (size_t)(rb & 511);
          *(bf16x4_t*)(Ctr + idx) = o4;
        }
      }
    }
  }

  #pragma unroll
  for (int p = 0; p < 2; ++p) {
    if (wr == p * 64) {
      #pragma unroll
      for (int ni = 0; ni < 4; ++ni) {
        const int col = wc + ni * 16 + fm;
        const float bv = bias[col0 + col];
        #pragma unroll
        for (int mi = 0; mi < 4; ++mi) {
          const int lrow = mi * 16 + r4;
          #pragma unroll
          for (int r = 0; r < 4; ++r)
            Cs[(lrow + r) * 136 + col] = (bf16_t)(acc[mi][ni][r] + bv);
        }
      }
    }
    __syncthreads();
    const int rrow = tid >> 2;
    const int cc = (tid & 3) * 32;
    const int grow = row0 + p * 64 + rrow;
    if ((mode & 1) && grow < M) {
      bf16_t* gp = Cbf + (size_t)grow * ldc + col0 + cc;
      const bf16_t* lp = Cs + rrow * 136 + cc;
      #pragma unroll
      for (int j = 0; j < 4; ++j)
        *(bf16x8_t*)(gp + j * 8) = *(const bf16x8_t*)(lp + j * 8);
    }
    __syncthreads();
  }
}

// ---------------------------------------------------------------------------
// Narrow GEMV: out[M][8] = A(bf16,[M][768]) @ WdT^T + bd.
// ---------------------------------------------------------------------------
__global__ __launch_bounds__(256) void gemv8(
    const bf16_t* __restrict__ A, const float* __restrict__ WdT,
    const float* __restrict__ bd, float* __restrict__ out, int M)
{
  int row = blockIdx.x * 32 + (threadIdx.x >> 3);
  int r = threadIdx.x & 7;
  if (row >= M) return;
  const bf16_t* ar = A + (size_t)row * C_;
  const float* wr = WdT + r * C_;
  float acc = 0.f;
  for (int k = 0; k < C_; k += 8) {
    bf16x8_t av = *(const bf16x8_t*)(ar + k);
    float4 w0 = *(const float4*)(wr + k);
    float4 w1 = *(const float4*)(wr + k + 4);
    acc += (float)av[0]*w0.x + (float)av[1]*w0.y + (float)av[2]*w0.z + (float)av[3]*w0.w
         + (float)av[4]*w1.x + (float)av[5]*w1.y + (float)av[6]*w1.z + (float)av[7]*w1.w;
  }
  out[(size_t)row * R_ + r] = acc + bd[r];
}

// ---------------------------------------------------------------------------
__global__ __launch_bounds__(256) void gemv_cls(
    const float* __restrict__ A, const float* __restrict__ W,
    const float* __restrict__ bias, float* __restrict__ out)
{
  __shared__ float as[C_];
  const int row = blockIdx.x / 3;
  const int c = (blockIdx.x % 3) * 256 + threadIdx.x;
  for (int i = threadIdx.x; i < C_; i += 256) as[i] = A[(size_t)row * C_ + i];
  __syncthreads();
  float acc = bias[c];
  for (int k = 0; k < C_; ++k) acc += as[k] * W[(size_t)k * C_ + c];
  out[(size_t)row * C_ + c] = acc;
}

// ---------------------------------------------------------------------------
// MFMA flash self-attention; Q/K from fused QKVc (stride LDQ).
// ---------------------------------------------------------------------------
__global__ __launch_bounds__(256) void attn_mfma(
    const bf16_t* __restrict__ QKVc, const bf16_t* __restrict__ Vtg,
    const int* __restrict__ mask, bf16_t* __restrict__ yout)
{
  __shared__ bf16_t Ks[64 * 64];
  __shared__ bf16_t Vs[64 * 64];
  __shared__ bf16_t Pl[4][16 * 64];
  __shared__ float  fac_s[4][16];
  __shared__ float  l_s[4][16];
  __shared__ int    msk_s[64];

  const int b = blockIdx.z, h = blockIdx.y;
  const int qt0 = blockIdx.x * 64;
  const int tid = threadIdx.x;
  const int lane = tid & 63;
  const int w = tid >> 6;
  const int lq = lane & 15;
  const int g = lane >> 4;

  const int qi_frag = qt0 + w * 16 + lq;
  const int qtok = (qi_frag < TM1 ? qi_frag : TM1 - 1) + 1;
  bf16x8_t qf[2];
  {
    const bf16_t* qp = QKVc + ((size_t)(b * T_) + qtok) * LDQ + h * D_ + 8 * g;
    qf[0] = *(const bf16x8_t*)qp;
    qf[1] = *(const bf16x8_t*)(qp + 32);
  }

  const bf16_t* kbase = QKVc + (size_t)(b * T_) * LDQ + 768 + h * D_;
  const bf16_t* vbase = Vtg + ((size_t)(b * H_) + h) * ((size_t)D_ * T_);

  f32x4_t o[4];
  #pragma unroll
  for (int i = 0; i < 4; ++i) o[i] = (f32x4_t){0.f, 0.f, 0.f, 0.f};
  float m = -INFINITY, l = 0.f;

  for (int kt = 0; kt < T_; kt += 64) {
    #pragma unroll
    for (int i = 0; i < 2; ++i) {
      const int tp = tid + i * 256;
      const int kr = tp >> 3;
      const int sl = tp & 7;
      const int ss = sl ^ (kr & 7);
      gl_lds16(kbase + (size_t)(kt + kr) * LDQ + 8 * ss,
               Ks + (size_t)(i * 4 + w) * 512);
      gl_lds16(vbase + (size_t)kr * T_ + kt + 8 * ss,
               Vs + (size_t)(i * 4 + w) * 512);
    }
    if (tid < 64) msk_s[tid] = mask[b * T_ + kt + tid];
    __syncthreads();

    f32x4_t st[4];
    #pragma unroll
    for (int t = 0; t < 4; ++t) {
      st[t] = (f32x4_t){0.f, 0.f, 0.f, 0.f};
      const int kk = t * 16 + lq;
      const bf16_t* krow = Ks + kk * 64;
      bf16x8_t kf0 = *(const bf16x8_t*)(krow + 8 * ((g)     ^ (kk & 7)));
      bf16x8_t kf1 = *(const bf16x8_t*)(krow + 8 * ((4 + g) ^ (kk & 7)));
      st[t] = __builtin_amdgcn_mfma_f32_16x16x32_bf16(kf0, qf[0], st[t], 0, 0, 0);
      st[t] = __builtin_amdgcn_mfma_f32_16x16x32_bf16(kf1, qf[1], st[t], 0, 0, 0);
    }

    float p[16];
    float mt = -INFINITY;
    #pragma unroll
    for (int t = 0; t < 4; ++t) {
      const int4 mk = *(const int4*)&msk_s[t * 16 + 4 * g];
      p[4*t+0] = mk.x ? st[t][0] * INV_ : NEG_;
      p[4*t+1] = mk.y ? st[t][1] * INV_ : NEG_;
      p[4*t+2] = mk.z ? st[t][2] * INV_ : NEG_;
      p[4*t+3] = mk.w ? st[t][3] * INV_ : NEG_;
      mt = fmaxf(mt, fmaxf(fmaxf(p[4*t], p[4*t+1]), fmaxf(p[4*t+2], p[4*t+3])));
    }
    mt = fmaxf(mt, __shfl_xor(mt, 16));
    mt = fmaxf(mt, __shfl_xor(mt, 32));
    const float mnew = fmaxf(m, mt);
    const float fac = __expf(m - mnew);
    float ps = 0.f;
    #pragma unroll
    for (int i = 0; i < 16; ++i) { p[i] = __expf(p[i] - mnew); ps += p[i]; }
    ps += __shfl_xor(ps, 16);
    ps += __shfl_xor(ps, 32);
    l = l * fac + ps;
    m = mnew;
    if (lane < 16) fac_s[w][lane] = fac;

    bf16_t* prow = Pl[w] + lq * 64;
    #pragma unroll
    for (int t = 0; t < 4; ++t) {
      bf16x4_t pb = {(bf16_t)p[4*t], (bf16_t)p[4*t+1],
                     (bf16_t)p[4*t+2], (bf16_t)p[4*t+3]};
      *(bf16x4_t*)(prow + 8 * ((2*t + (g >> 1)) ^ (lq & 7)) + 4 * (g & 1)) = pb;
    }
    bf16x8_t pa0 = *(const bf16x8_t*)(prow + 8 * ((g)     ^ (lq & 7)));
    bf16x8_t pa1 = *(const bf16x8_t*)(prow + 8 * ((4 + g) ^ (lq & 7)));

    const float4 fc = *(const float4*)&fac_s[w][4 * g];
    #pragma unroll
    for (int db = 0; db < 4; ++db) {
      const int dr = db * 16 + lq;
      const bf16_t* vrow = Vs + dr * 64;
      bf16x8_t vf0 = *(const bf16x8_t*)(vrow + 8 * ((g)     ^ (dr & 7)));
      bf16x8_t vf1 = *(const bf16x8_t*)(vrow + 8 * ((4 + g) ^ (dr & 7)));
      o[db][0] *= fc.x; o[db][1] *= fc.y; o[db][2] *= fc.z; o[db][3] *= fc.w;
      o[db] = __builtin_amdgcn_mfma_f32_16x16x32_bf16(pa0, vf0, o[db], 0, 0, 0);
      o[db] = __builtin_amdgcn_mfma_f32_16x16x32_bf16(pa1, vf1, o[db], 0, 0, 0);
    }
    __syncthreads();
  }

  if (lane < 16) l_s[w][lane] = l;
  const float4 lv = *(const float4*)&l_s[w][4 * g];
  const float rl0 = 1.f / lv.x, rl1 = 1.f / lv.y;
  const float rl2 = 1.f / lv.z, rl3 = 1.f / lv.w;
  const int qr0 = qt0 + w * 16 + 4 * g;
  #pragma unroll
  for (int db = 0; db < 4; ++db) {
    const int col = h * D_ + db * 16 + lq;
    bf16_t* yp = yout + ((size_t)(b * TM1) + qr0) * C_ + col;
    if (qr0 + 0 < TM1) yp[0 * (size_t)C_] = (bf16_t)(o[db][0] * rl0);
    if (qr0 + 1 < TM1) yp[1 * (size_t)C_] = (bf16_t)(o[db][1] * rl1);
    if (qr0 + 2 < TM1) yp[2 * (size_t)C_] = (bf16_t)(o[db][2] * rl2);
    if (qr0 + 3 < TM1) yp[3 * (size_t)C_] = (bf16_t)(o[db][3] * rl3);
  }
}

// ---------------------------------------------------------------------------
// cls attention via low-rank keys.
// ---------------------------------------------------------------------------
__global__ __launch_bounds__(64) void cls_attn(
    const bf16_t* __restrict__ QKVc, const float* __restrict__ t1,
    const int* __restrict__ mask, float* __restrict__ yout /* (B,768) */)
{
  __shared__ float qp_s[16];
  __shared__ float Vs[64][65];
  __shared__ float Ps[64];

  const int b = blockIdx.x / H_, h = blockIdx.x % H_;
  const int lane = threadIdx.x;

  if (lane < 16)
    qp_s[lane] = (float)QKVc[(size_t)(b * T_) * LDQ + QPOFF + h * 16 + lane];
  __syncthreads();

  float m = -INFINITY, l = 0.f, acc = 0.f;
  for (int kt = 0; kt < T_; kt += 64) {
    for (int rr = 0; rr < 64; ++rr)
      Vs[rr][lane] = (float)QKVc[((size_t)(b * T_) + kt + rr) * LDQ + 1536 + h * D_ + lane];
    __syncthreads();
    const float* t1r = t1 + ((size_t)(b * T_) + kt + lane) * R_;
    float sc = qp_s[8];
    #pragma unroll
    for (int r = 0; r < 8; ++r) sc += qp_s[r] * t1r[r];
    sc *= INV_;
    if (!mask[b * T_ + kt + lane]) sc = NEG_;
    float mt = sc;
    #pragma unroll
    for (int off = 32; off > 0; off >>= 1) mt = fmaxf(mt, __shfl_xor(mt, off));
    float mnew = fmaxf(m, mt);
    float e = __expf(sc - mnew);
    float ssum = e;
    #pragma unroll
    for (int off = 32; off > 0; off >>= 1) ssum += __shfl_xor(ssum, off);
    float fac = __expf(m - mnew);
    acc *= fac;
    l = l * fac + ssum;
    Ps[lane] = e;
    __syncthreads();
    #pragma unroll
    for (int j = 0; j < 64; ++j) acc += Ps[j] * Vs[j][lane];
    m = mnew;
    __syncthreads();
  }
  yout[(size_t)b * C_ + h * D_ + lane] = acc / l;
}

// ---------------------------------------------------------------------------
// Neighbour attention via low-rank keys.  vqn rows: [768 v | 256 qp].
// i==0 output row is pre-blended with y_self: 0.5*out + 0.5*ysh.
// ---------------------------------------------------------------------------
__global__ __launch_bounds__(256) void neigh_attn(
    const bf16_t* __restrict__ QKVc, const float* __restrict__ t1,
    const bf16_t* __restrict__ vqn,  /* [rows][1024] */
    const float* __restrict__ t2,    /* [rows][8] */
    const bf16_t* __restrict__ ysh,  /* (B*511,768) */
    int b0, bf16_t* __restrict__ outn)
{
  __shared__ float vs[KC5 * C_];
  __shared__ float qp_s[KC5][200];
  __shared__ float t2_s[KC5][8];
  __shared__ float Ps[H_ * 25];

  const int bt = blockIdx.x;
  const int bb = bt / TM1, t = bt % TM1;
  const int b = b0 + bb;
  const int tid = threadIdx.x;
  const size_t tok = (size_t)(b * T_) + t + 1;
  const size_t nrow = ((size_t)(bb * TM1) + t) * KN_;

  for (int idx = tid; idx < KC5 * 96; idx += 256) {
    int i = idx / 96, d8 = (idx % 96) * 8;
    const bf16_t* vp = (i == 0) ? QKVc + tok * LDQ + 1536 + d8
                                : vqn + (nrow + i - 1) * 1024 + d8;
    bf16x8_t vv = *(const bf16x8_t*)vp;
    #pragma unroll
    for (int j = 0; j < 8; ++j) vs[i * C_ + d8 + j] = (float)vv[j];
  }
  for (int idx = tid; idx < KC5 * 24; idx += 256) {
    int i = idx / 24, c8 = (idx % 24) * 8;
    const bf16_t* qpp = (i == 0) ? QKVc + tok * LDQ + QPOFF + c8
                                 : vqn + (nrow + i - 1) * 1024 + 768 + c8;
    bf16x8_t qv = *(const bf16x8_t*)qpp;
    #pragma unroll
    for (int j = 0; j < 8; ++j) qp_s[i][c8 + j] = (float)qv[j];
  }
  if (tid < KC5 * 8) {
    int i = tid / 8, r = tid & 7;
    t2_s[i][r] = (i == 0) ? t1[tok * R_ + r] : t2[(nrow + i - 1) * R_ + r];
  }
  __syncthreads();

  if (tid < H_ * KC5) {
    int h = tid / KC5, i = tid % KC5;
    float sc[KC5];
    #pragma unroll
    for (int j = 0; j < KC5; ++j) {
      float s = qp_s[i][h * 16 + 8];
      #pragma unroll
      for (int r = 0; r < 8; ++r) s += qp_s[i][h * 16 + r] * t2_s[j][r];
      sc[j] = s * INV_;
    }
    float mt = sc[0];
    #pragma unroll
    for (int j = 1; j < KC5; ++j) mt = fmaxf(mt, sc[j]);
    float e[KC5], ssum = 0.f;
    #pragma unroll
    for (int j = 0; j < KC5; ++j) { e[j] = __expf(sc[j] - mt); ssum += e[j]; }
    float rs = 1.f / ssum;
    #pragma unroll
    for (int j = 0; j < KC5; ++j) Ps[h * 25 + i * KC5 + j] = e[j] * rs;
  }
  __syncthreads();

  const bf16_t* ysrow = ysh + ((size_t)(b * TM1) + t) * C_;
  for (int idx = tid; idx < KC5 * C_; idx += 256) {
    int i = idx / C_, c = idx % C_;
    int h = c / D_;
    float sum = 0.f;
    #pragma unroll
    for (int j = 0; j < KC5; ++j)
      sum += Ps[h * 25 + i * KC5 + j] * vs[j * C_ + c];
    if (i == 0) sum = SCALE_ * sum + (1.f - SCALE_) * (float)ysrow[c];
    outn[(((size_t)(bb * TM1) + t) * KC5 + i) * C_ + c] = (bf16_t)sum;
  }
}

// ---------------------------------------------------------------------------
// Residual + LayerNorm combine kernels
// ---------------------------------------------------------------------------
__device__ __forceinline__ void block_reduce2(float& s, float& ss, float* red) {
  #pragma unroll
  for (int off = 32; off > 0; off >>= 1) {
    s += __shfl_down(s, off);
    ss += __shfl_down(ss, off);
  }
  int wid = threadIdx.x >> 6;
  if ((threadIdx.x & 63) == 0) { red[wid * 2] = s; red[wid * 2 + 1] = ss; }
  __syncthreads();
  s  = red[0] + red[2] + red[4] + red[6];
  ss = red[1] + red[3] + red[5] + red[7];
}

__device__ __forceinline__ void ln_row(const float vals[3], float s, float ss,
                                       const float* __restrict__ g,
                                       const float* __restrict__ bb,
                                       float* __restrict__ orow, float* red) {
  block_reduce2(s, ss, red);
  float mean = s * (1.f / (float)C_);
  float var = ss * (1.f / (float)C_) - mean * mean;
  var = fmaxf(var, 0.f);
  float rs = rsqrtf(var + EPS_);
  #pragma unroll
  for (int ii = 0; ii < 3; ++ii) {
    int c = threadIdx.x + ii * 256;
    orow[c] = (vals[ii] - mean) * rs * g[c] + bb[c];
  }
}

__global__ __launch_bounds__(256) void combine_main(
    const bf16_t* __restrict__ poutn,
    const float* __restrict__ x, const float* __restrict__ g,
    const float* __restrict__ bln, int b0, float* __restrict__ dout)
{
  __shared__ float red[8];
  const int bt = blockIdx.x;
  const int bbb = bt / TM1, t = bt % TM1;
  const int b = b0 + bbb;
  const bf16_t* pn = poutn + (((size_t)(bbb * TM1) + t) * KC5 + 0) * C_;
  const float* xr = x + ((size_t)(b * T_) + t + 1) * C_;
  float* orow = dout + ((size_t)(b * T_) + t + 1) * C_;
  float vals[3], s = 0.f, ss = 0.f;
  #pragma unroll
  for (int ii = 0; ii < 3; ++ii) {
    int c = threadIdx.x + ii * 256;
    float v = (float)pn[c] + xr[c];
    vals[ii] = v; s += v; ss += v * v;
  }
  ln_row(vals, s, ss, g, bln, orow, red);
}

__global__ __launch_bounds__(256) void combine_neigh(
    const bf16_t* __restrict__ poutn, const bf16_t* __restrict__ nrc,
    const float* __restrict__ g, const float* __restrict__ bln,
    int b0, float* __restrict__ dout)
{
  __shared__ float red[8];
  const int idx = blockIdx.x;
  const int i1 = idx % KN_;
  const int bt = idx / KN_;
  const int bbb = bt / TM1, t = bt % TM1;
  const int b = b0 + bbb;
  const bf16_t* pn = poutn + ((size_t)bt * KC5 + 1 + i1) * C_;
  const bf16_t* nr = nrc + ((size_t)bt * KN_ + i1) * C_;
  float* orow = dout + (((size_t)(b * TM1) + t) * KN_ + i1) * C_;
  float vals[3], s = 0.f, ss = 0.f;
  #pragma unroll
  for (int ii = 0; ii < 3; ++ii) {
    int c = threadIdx.x + ii * 256;
    float v = (float)pn[c] + (float)nr[c];
    vals[ii] = v; s += v; ss += v * v;
  }
  ln_row(vals, s, ss, g, bln, orow, red);
}

__global__ __launch_bounds__(256) void combine_cls(
    const float* __restrict__ yclsP, const float* __restrict__ x,
    const float* __restrict__ g, const float* __restrict__ bln,
    float* __restrict__ dout)
{
  __shared__ float red[8];
  const int b = blockIdx.x;
  const float* yc = yclsP + (size_t)b * C_;
  const float* xr = x + (size_t)(b * T_) * C_;
  float* orow = dout + (size_t)(b * T_) * C_;
  float vals[3], s = 0.f, ss = 0.f;
  #pragma unroll
  for (int ii = 0; ii < 3; ++ii) {
    int c = threadIdx.x + ii * 256;
    float v = yc[c] + xr[c];
    vals[ii] = v; s += v; ss += v * v;
  }
  ln_row(vals, s, ss, g, bln, orow, red);
}

// ---------------------------------------------------------------------------
extern "C" void kernel_launch(void* const* d_in, const int* in_sizes, int n_in,
                              void* d_out, int out_size, void* d_ws, size_t ws_size,
                              hipStream_t stream) {
  (void)in_sizes; (void)n_in; (void)out_size;
  const float* x    = (const float*)d_in[0];
  const int*   mask = (const int*)d_in[1];
  const float* nrep = (const float*)d_in[2];
  const float* Wq = (const float*)d_in[3];  const float* bq = (const float*)d_in[4];
  const float* Wk = (const float*)d_in[5];  const float* bk = (const float*)d_in[6];
  const float* Wv = (const float*)d_in[7];  const float* bv = (const float*)d_in[8];
  const float* Wp = (const float*)d_in[9];  const float* bp = (const float*)d_in[10];
  const float* Wd = (const float*)d_in[11]; const float* bd = (const float*)d_in[12];
  const float* Wu = (const float*)d_in[13]; const float* bu = (const float*)d_in[14];
  const float* lng = (const float*)d_in[15];
  const float* lnb = (const float*)d_in[16];
  float* dout = (float*)d_out;
  const size_t OUT1 = (size_t)B_ * T_ * C_;

  char* ws = (char*)d_ws;
  size_t off = 0;
  auto alloc = [&](size_t bytes) -> void* {
    void* p = ws + off; off += (bytes + 255) & ~(size_t)255; return p;
  };
  const size_t NT = (size_t)B_ * T_;
  const size_t NR = (size_t)B_ * TM1 * KN_;
  const size_t YSROWS = (size_t)B_ * TM1;     // 4088

  bf16_t* xbf   = (bf16_t*)alloc(NT * C_ * 2);
  bf16_t* nrbf  = (bf16_t*)alloc(NR * C_ * 2);
  bf16_t* Wbig  = (bf16_t*)alloc((size_t)2560 * C_ * 2);   // WqT|WkT|WvT|WfqT
  bf16_t* Wtp   = (bf16_t*)alloc((size_t)C_ * C_ * 2);
  bf16_t* Wqp   = (bf16_t*)alloc((size_t)256 * C_ * 2);
  bf16_t* Wqbf  = (bf16_t*)alloc((size_t)C_ * C_ * 2);
  float*  WdT   = (float*)alloc((size_t)R_ * C_ * 4);
  float*  bbig  = (float*)alloc(2560 * 4);
  float*  bfq   = (float*)alloc(256 * 4);
  float*  zb768 = (float*)alloc(768 * 4);
  bf16_t* QKVc  = (bf16_t*)alloc(NT * LDQ * 2);
  bf16_t* Vtg   = (bf16_t*)alloc(NT * C_ * 2);   // [b][h][d][T]
  float*  t1    = (float*)alloc(NT * R_ * 4);
  bf16_t* ysh   = (bf16_t*)alloc(YSROWS * C_ * 2);
  float*  ych   = (float*)alloc((size_t)B_ * C_ * 4);
  float*  ycp   = (float*)alloc((size_t)B_ * C_ * 4);
  const size_t fixed = off;
  const size_t perb = (size_t)TM1 * KN_ * 1024 * 2
                    + (size_t)TM1 * KN_ * R_ * 4
                    + (size_t)TM1 * KC5 * C_ * 2 * 2 + 5 * 256;
  int nb = 1;
  for (int cand : {8, 4, 2, 1}) {
    if (fixed + perb * (size_t)cand <= ws_size) { nb = cand; break; }
  }
  bf16_t* outn   = (bf16_t*)alloc((size_t)nb * TM1 * KC5 * C_ * 2);
  bf16_t* poutnb = (bf16_t*)alloc((size_t)nb * TM1 * KC5 * C_ * 2);
  bf16_t* vqn  = (bf16_t*)alloc((size_t)nb * TM1 * KN_ * 1024 * 2);
  float*  t2   = (float*)alloc((size_t)nb * TM1 * KN_ * R_ * 4);

  dim3 blk(256);
  dim3 tg(C_ / 32, C_ / 32);

  // ---- prep ----
  cvt_bf16<<<1024, blk, 0, stream>>>(x, xbf, (long)(NT * C_));
  cvt_bf16<<<2048, blk, 0, stream>>>(nrep, nrbf, (long)(NR * C_));
  cvt_bf16<<<576, blk, 0, stream>>>(Wq, Wqbf, (long)C_ * C_);
  wtrans<<<tg, blk, 0, stream>>>(Wq, Wbig);
  wtrans<<<tg, blk, 0, stream>>>(Wk, Wbig + (size_t)C_ * C_);
  wtrans<<<tg, blk, 0, stream>>>(Wv, Wbig + (size_t)2 * C_ * C_);
  wtrans<<<tg, blk, 0, stream>>>(Wp, Wtp);
  build_wqp<<<(256 * C_) / 256, blk, 0, stream>>>(Wu, bu, Wqp);
  build_bfq<<<1, blk, 0, stream>>>(Wu, bu, bq, bfq);
  build_wdt<<<24, blk, 0, stream>>>(Wd, WdT);
  cat_qkvq<<<10, blk, 0, stream>>>(bq, bk, bv, bfq, bbig);
  hipMemsetAsync(zb768, 0, 768 * 4, stream);
  gemm_mfma<<<dim3(6, 2), blk, 0, stream>>>(Wqp, C_, Wqbf, zb768,
                                            Wbig + (size_t)QPOFF * C_, C_,
                                            nullptr, 0, 1, 256, C_, C_);

  // ---- self path: fused Q|K|V|qp projection ----
  gemm_mfma<<<dim3(20, 32), blk, 0, stream>>>(xbf, C_, Wbig, bbig,
                                              QKVc, LDQ, Vtg, 1536, 3,
                                              (int)NT, C_, 2560);
  gemv8<<<(int)(NT / 32), blk, 0, stream>>>(xbf, WdT, bd, t1, (int)NT);

  attn_mfma<<<dim3(8, H_, B_), blk, 0, stream>>>(QKVc, Vtg, mask, ysh);

  cls_attn<<<B_ * H_, 64, 0, stream>>>(QKVc, t1, mask, ych);
  gemv_cls<<<B_ * 3, blk, 0, stream>>>(ych, Wp, bp, ycp);
  combine_cls<<<B_, blk, 0, stream>>>(ycp, x, lng, lnb, dout);

  for (int b0 = 0; b0 < B_; b0 += nb) {
    const int Mn = nb * TM1 * KN_;
    const int Mo = nb * TM1 * KC5;
    const bf16_t* nrcbf = nrbf + (size_t)b0 * TM1 * KN_ * C_;
    gemm_mfma<<<dim3(8, (Mn + 127) / 128), blk, 0, stream>>>(
        nrcbf, C_, Wbig + (size_t)1536 * C_, bbig + 1536,
        vqn, 1024, nullptr, 0, 1, Mn, C_, 1024);
    gemv8<<<(Mn + 31) / 32, blk, 0, stream>>>(nrcbf, WdT, bd, t2, Mn);
    neigh_attn<<<nb * TM1, blk, 0, stream>>>(QKVc, t1, vqn, t2, ysh, b0, outn);
    gemm_mfma<<<dim3(6, (Mo + 127) / 128), blk, 0, stream>>>(
        outn, C_, Wtp, bp, poutnb, C_, nullptr, 0, 1, Mo, C_, C_);
    combine_main<<<nb * TM1, blk, 0, stream>>>(poutnb, x, lng, lnb, b0, dout);
    combine_neigh<<<nb * TM1 * KN_, blk, 0, stream>>>(poutnb, nrcbf, lng, lnb, b0,
                                                      dout + OUT1);
  }
}

// Round 9
// 304.907 us; speedup vs baseline: 6.2142x; 1.4033x over previous
//
#include <hip/hip_runtime.h>
#include <math.h>

#define C_    768
#define H_    12
#define D_    64
#define B_    8
#define T_    512
#define TM1   511
#define R_    8
#define KN_   4
#define KC5   5
#define SCALE_ 0.5f
#define EPS_  1e-12f
#define NEG_  -1000000000.0f
#define INV_  0.125f
#define LDQ   2560
#define QPOFF 2304
#define NT_   4096        /* B_*T_ */
#define NRR_  16352       /* B_*TM1*KN_ */

typedef __bf16 bf16_t;
typedef __bf16 bf16x4_t __attribute__((ext_vector_type(4)));
typedef __bf16 bf16x8_t __attribute__((ext_vector_type(8)));
typedef float  f32x4_t  __attribute__((ext_vector_type(4)));
typedef const void __attribute__((address_space(1)))* gas_t;
typedef void       __attribute__((address_space(3)))* las_t;

__device__ __forceinline__ void gl_lds16(const bf16_t* g, bf16_t* l) {
  __builtin_amdgcn_global_load_lds((gas_t)g, (las_t)l, 16, 0, 0);
}

__device__ __forceinline__ int swz(int row, int g) {
  return row * 32 + (((g ^ (row >> 1)) & 3) << 3);
}

struct GemmDesc {
  const bf16_t* A; int lda;
  const bf16_t* Bt;
  const float* bias;
  bf16_t* Cbf; int ldc;
  bf16_t* Ctr; int trcol0; int mode;
  int M, K, N, gx, nwg;
};

// ---------------------------------------------------------------------------
// PREP: all conversions + weight prep in one kernel (block-range dispatch).
// ---------------------------------------------------------------------------
__global__ __launch_bounds__(256) void prep(
    const float* __restrict__ x, const float* __restrict__ nrep,
    const float* __restrict__ Wq, const float* __restrict__ Wk,
    const float* __restrict__ Wv, const float* __restrict__ Wp,
    const float* __restrict__ Wd, const float* __restrict__ Wu,
    const float* __restrict__ bq, const float* __restrict__ bk,
    const float* __restrict__ bv, const float* __restrict__ bu,
    bf16_t* __restrict__ xbf, bf16_t* __restrict__ nrbf,
    bf16_t* __restrict__ Wbig, bf16_t* __restrict__ Wtp,
    float* __restrict__ WdT, float* __restrict__ bbig)
{
  __shared__ float tile[32][33];
  const int bid = blockIdx.x, tid = threadIdx.x;
  if (bid < 1024) {
    const long n = (long)NT_ * C_;
    for (long i = ((long)bid * 256 + tid) * 4; i < n; i += (long)1024 * 256 * 4) {
      float4 v = *(const float4*)(x + i);
      bf16x4_t o = {(bf16_t)v.x, (bf16_t)v.y, (bf16_t)v.z, (bf16_t)v.w};
      *(bf16x4_t*)(xbf + i) = o;
    }
  } else if (bid < 3072) {
    const long n = (long)NRR_ * C_;
    for (long i = ((long)(bid - 1024) * 256 + tid) * 4; i < n;
         i += (long)2048 * 256 * 4) {
      float4 v = *(const float4*)(nrep + i);
      bf16x4_t o = {(bf16_t)v.x, (bf16_t)v.y, (bf16_t)v.z, (bf16_t)v.w};
      *(bf16x4_t*)(nrbf + i) = o;
    }
  } else if (bid < 5376) {
    int sub = bid - 3072;
    const int which = sub / 576; sub %= 576;
    const float* W = which == 0 ? Wq : which == 1 ? Wk : which == 2 ? Wv : Wp;
    bf16_t* Wt = (which == 3) ? Wtp : Wbig + (size_t)which * C_ * C_;
    const int n0 = (sub % 24) * 32, k0 = (sub / 24) * 32;
    const int tx = tid & 31, ty = tid >> 5;
    #pragma unroll
    for (int r = ty; r < 32; r += 8)
      tile[r][tx] = W[(size_t)(k0 + r) * C_ + n0 + tx];
    __syncthreads();
    #pragma unroll
    for (int r = ty; r < 32; r += 8)
      Wt[(size_t)(n0 + r) * C_ + k0 + tx] = (bf16_t)tile[tx][r];
  } else if (bid < 6144) {
    // fused low-rank query weight WfqT -> Wbig rows QPOFF..QPOFF+255 (fp32 acc)
    const int idx = (bid - 5376) * 256 + tid;     // < 256*768
    const int n = idx / C_, k = idx % C_;
    const int h = n >> 4, r = n & 15;
    float s = 0.f;
    if (h < H_) {
      if (r < 8) {
        #pragma unroll 8
        for (int j = 0; j < 64; ++j)
          s += Wu[r * C_ + h * 64 + j] * Wq[(size_t)k * C_ + h * 64 + j];
      } else if (r == 8) {
        #pragma unroll 8
        for (int j = 0; j < 64; ++j)
          s += bu[h * 64 + j] * Wq[(size_t)k * C_ + h * 64 + j];
      }
    }
    Wbig[(size_t)(QPOFF + n) * C_ + k] = (bf16_t)s;
  } else if (bid < 6168) {
    const int idx = (bid - 6144) * 256 + tid;
    if (idx < R_ * C_) {
      const int r = idx / C_, k = idx % C_;
      WdT[idx] = Wd[(size_t)k * R_ + r];
    }
  } else {
    const int i = (bid - 6168) * 256 + tid;
    if (i < 2560) {
      float v;
      if (i < 768) v = bq[i];
      else if (i < 1536) v = bk[i - 768];
      else if (i < 2304) v = bv[i - 1536];
      else {
        const int n = i - 2304, h = n >> 4, r = n & 15;
        v = 0.f;
        if (h < H_) {
          if (r < 8) {
            float s = 0.f;
            for (int j = 0; j < 64; ++j) s += bq[h * 64 + j] * Wu[r * C_ + h * 64 + j];
            v = s;
          } else if (r == 8) {
            float s = 0.f;
            for (int j = 0; j < 64; ++j) s += bq[h * 64 + j] * bu[h * 64 + j];
            v = s;
          }
        }
      }
      bbig[i] = v;
    }
  }
}

// ---------------------------------------------------------------------------
// GEMM body (verified round-8 structure: XCD swizzle, slot-swizzled LDS,
// coalesced LDS-staged epilogue).
// ---------------------------------------------------------------------------
__device__ __forceinline__ void gemm_body(
    const GemmDesc& d, int bid0, bf16_t* As, bf16_t* Bs, bf16_t* Cs)
{
  int lid = bid0;
  {
    const int nwg = d.nwg;
    const int q0 = nwg >> 3, r0 = nwg & 7;
    const int xcd = lid & 7, idx = lid >> 3;
    lid = (xcd < r0 ? xcd * (q0 + 1) : r0 * (q0 + 1) + (xcd - r0) * q0) + idx;
  }
  const int row0 = (lid / d.gx) * 128;
  const int col0 = (lid % d.gx) * 128;

  const int tid = threadIdx.x;
  const int lane = tid & 63;
  const int wv = tid >> 6;
  const int wr = (wv >> 1) * 64;
  const int wc = (wv & 1) * 64;
  const int sr = tid >> 2;
  const int ssl = (tid & 3) ^ ((sr >> 1) & 3);
  const int sk = ssl * 8;

  int ra0 = row0 + sr;       if (ra0 > d.M - 1) ra0 = d.M - 1;
  int ra1 = row0 + 64 + sr;  if (ra1 > d.M - 1) ra1 = d.M - 1;
  const bf16_t* ga0 = d.A + (size_t)ra0 * d.lda + sk;
  const bf16_t* ga1 = d.A + (size_t)ra1 * d.lda + sk;
  const bf16_t* gb0 = d.Bt + (size_t)(col0 + sr) * d.K + sk;
  const bf16_t* gb1 = d.Bt + (size_t)(col0 + 64 + sr) * d.K + sk;
  bf16_t* lA = As + wv * 512;
  bf16_t* lB = Bs + wv * 512;

  f32x4_t acc[4][4];
  #pragma unroll
  for (int i = 0; i < 4; ++i)
    #pragma unroll
    for (int j = 0; j < 4; ++j) acc[i][j] = (f32x4_t){0.f, 0.f, 0.f, 0.f};

  const int fm = lane & 15;
  const int g = lane >> 4;

  for (int k0 = 0; k0 < d.K; k0 += 32) {
    gl_lds16(ga0 + k0, lA);
    gl_lds16(ga1 + k0, lA + 2048);
    gl_lds16(gb0 + k0, lB);
    gl_lds16(gb1 + k0, lB + 2048);
    __syncthreads();
    bf16x8_t af[4], bfr[4];
    #pragma unroll
    for (int mi = 0; mi < 4; ++mi)
      af[mi] = *(const bf16x8_t*)(As + swz(wr + mi * 16 + fm, g));
    #pragma unroll
    for (int ni = 0; ni < 4; ++ni)
      bfr[ni] = *(const bf16x8_t*)(Bs + swz(wc + ni * 16 + fm, g));
    __builtin_amdgcn_s_setprio(1);
    #pragma unroll
    for (int mi = 0; mi < 4; ++mi)
      #pragma unroll
      for (int ni = 0; ni < 4; ++ni)
        acc[mi][ni] = __builtin_amdgcn_mfma_f32_16x16x32_bf16(af[mi], bfr[ni],
                                                              acc[mi][ni], 0, 0, 0);
    __builtin_amdgcn_s_setprio(0);
    __syncthreads();
  }

  const int r4 = (lane >> 4) * 4;

  if (d.mode & 2) {
    #pragma unroll
    for (int ni = 0; ni < 4; ++ni) {
      const int col = col0 + wc + ni * 16 + fm;
      if ((unsigned)(col - d.trcol0) < 768u) {
        const int vcol = col - d.trcol0;
        const float bv = d.bias[col];
        #pragma unroll
        for (int mi = 0; mi < 4; ++mi) {
          const int rb = row0 + wr + mi * 16 + r4;
          bf16x4_t o4 = {(bf16_t)(acc[mi][ni][0] + bv), (bf16_t)(acc[mi][ni][1] + bv),
                         (bf16_t)(acc[mi][ni][2] + bv), (bf16_t)(acc[mi][ni][3] + bv)};
          size_t idx = ((size_t)(rb >> 9) * H_ + (size_t)(vcol >> 6)) * ((size_t)D_ * T_)
                     + (size_t)(vcol & 63) * T_ + (size_t)(rb & 511);
          *(bf16x4_t*)(d.Ctr + idx) = o4;
        }
      }
    }
  }

  #pragma unroll
  for (int p = 0; p < 2; ++p) {
    if (wr == p * 64) {
      #pragma unroll
      for (int ni = 0; ni < 4; ++ni) {
        const int col = wc + ni * 16 + fm;
        const float bv = d.bias[col0 + col];
        #pragma unroll
        for (int mi = 0; mi < 4; ++mi) {
          const int lrow = mi * 16 + r4;
          #pragma unroll
          for (int r = 0; r < 4; ++r)
            Cs[(lrow + r) * 136 + col] = (bf16_t)(acc[mi][ni][r] + bv);
        }
      }
    }
    __syncthreads();
    const int rrow = tid >> 2;
    const int cc = (tid & 3) * 32;
    const int grow = row0 + p * 64 + rrow;
    if ((d.mode & 1) && grow < d.M) {
      bf16_t* gp = d.Cbf + (size_t)grow * d.ldc + col0 + cc;
      const bf16_t* lp = Cs + rrow * 136 + cc;
      #pragma unroll
      for (int j = 0; j < 4; ++j)
        *(bf16x8_t*)(gp + j * 8) = *(const bf16x8_t*)(lp + j * 8);
    }
    __syncthreads();
  }
}

__device__ __forceinline__ void gemv8_body(
    const bf16_t* __restrict__ A, const float* __restrict__ WdT,
    const float* __restrict__ bd, float* __restrict__ out, int M, int bid)
{
  const int row = bid * 32 + ((int)threadIdx.x >> 3);
  const int r = threadIdx.x & 7;
  if (row >= M) return;
  const bf16_t* ar = A + (size_t)row * C_;
  const float* wr = WdT + r * C_;
  float acc = 0.f;
  for (int k = 0; k < C_; k += 8) {
    bf16x8_t av = *(const bf16x8_t*)(ar + k);
    float4 w0 = *(const float4*)(wr + k);
    float4 w1 = *(const float4*)(wr + k + 4);
    acc += (float)av[0]*w0.x + (float)av[1]*w0.y + (float)av[2]*w0.z + (float)av[3]*w0.w
         + (float)av[4]*w1.x + (float)av[5]*w1.y + (float)av[6]*w1.z + (float)av[7]*w1.w;
  }
  out[(size_t)row * R_ + r] = acc + bd[r];
}

// MEGA1: QKV-GEMM | vqn-GEMM | gemv8(t1) | gemv8(t2) in one dispatch.
__global__ __launch_bounds__(256) void mega1(
    GemmDesc d0, int n0, GemmDesc d1, int n1,
    const bf16_t* Ag1, const bf16_t* Ag2,
    const float* WdT, const float* bd,
    float* o1, int M1, float* o2, int M2)
{
  __shared__ bf16_t As[128 * 32];
  __shared__ bf16_t Bs[128 * 32];
  __shared__ bf16_t Cs[64 * 136];
  int bid = blockIdx.x;
  if (bid < n0) { gemm_body(d0, bid, As, Bs, Cs); return; }
  bid -= n0;
  if (bid < n1) { gemm_body(d1, bid, As, Bs, Cs); return; }
  bid -= n1;
  const int ng1 = (M1 + 31) / 32;
  if (bid < ng1) { gemv8_body(Ag1, WdT, bd, o1, M1, bid); return; }
  bid -= ng1;
  gemv8_body(Ag2, WdT, bd, o2, M2, bid);
}

// standalone GEMM (proj)
__global__ __launch_bounds__(256) void gemm_mfma_k(GemmDesc d) {
  __shared__ bf16_t As[128 * 32];
  __shared__ bf16_t Bs[128 * 32];
  __shared__ bf16_t Cs[64 * 136];
  gemm_body(d, blockIdx.x, As, Bs, Cs);
}

// ---------------------------------------------------------------------------
// ATTN + CLS fused dispatch (LDS pooled).
// ---------------------------------------------------------------------------
__device__ void attn_body(
    const bf16_t* __restrict__ QKVc, const bf16_t* __restrict__ Vtg,
    const int* __restrict__ mask, bf16_t* __restrict__ yout,
    char* pool, int bid)
{
  bf16_t* Ks   = (bf16_t*)pool;
  bf16_t* Vs   = (bf16_t*)(pool + 8192);
  bf16_t* Pl   = (bf16_t*)(pool + 16384);    // [4][1024]
  float* fac_s = (float*)(pool + 24576);     // [4][16]
  float* l_s   = (float*)(pool + 24832);
  int*   msk_s = (int*)(pool + 25088);

  const int qt0 = (bid & 7) * 64;
  const int h = (bid >> 3) % H_;
  const int b = bid / 96;
  const int tid = threadIdx.x;
  const int lane = tid & 63;
  const int w = tid >> 6;
  const int lq = lane & 15;
  const int g = lane >> 4;

  const int qi_frag = qt0 + w * 16 + lq;
  const int qtok = (qi_frag < TM1 ? qi_frag : TM1 - 1) + 1;
  bf16x8_t qf[2];
  {
    const bf16_t* qp = QKVc + ((size_t)(b * T_) + qtok) * LDQ + h * D_ + 8 * g;
    qf[0] = *(const bf16x8_t*)qp;
    qf[1] = *(const bf16x8_t*)(qp + 32);
  }

  const bf16_t* kbase = QKVc + (size_t)(b * T_) * LDQ + 768 + h * D_;
  const bf16_t* vbase = Vtg + ((size_t)(b * H_) + h) * ((size_t)D_ * T_);

  f32x4_t o[4];
  #pragma unroll
  for (int i = 0; i < 4; ++i) o[i] = (f32x4_t){0.f, 0.f, 0.f, 0.f};
  float m = -INFINITY, l = 0.f;

  for (int kt = 0; kt < T_; kt += 64) {
    #pragma unroll
    for (int i = 0; i < 2; ++i) {
      const int tp = tid + i * 256;
      const int kr = tp >> 3;
      const int sl = tp & 7;
      const int ss = sl ^ (kr & 7);
      gl_lds16(kbase + (size_t)(kt + kr) * LDQ + 8 * ss,
               Ks + (size_t)(i * 4 + w) * 512);
      gl_lds16(vbase + (size_t)kr * T_ + kt + 8 * ss,
               Vs + (size_t)(i * 4 + w) * 512);
    }
    if (tid < 64) msk_s[tid] = mask[b * T_ + kt + tid];
    __syncthreads();

    f32x4_t st[4];
    __builtin_amdgcn_s_setprio(1);
    #pragma unroll
    for (int t = 0; t < 4; ++t) {
      st[t] = (f32x4_t){0.f, 0.f, 0.f, 0.f};
      const int kk = t * 16 + lq;
      const bf16_t* krow = Ks + kk * 64;
      bf16x8_t kf0 = *(const bf16x8_t*)(krow + 8 * ((g)     ^ (kk & 7)));
      bf16x8_t kf1 = *(const bf16x8_t*)(krow + 8 * ((4 + g) ^ (kk & 7)));
      st[t] = __builtin_amdgcn_mfma_f32_16x16x32_bf16(kf0, qf[0], st[t], 0, 0, 0);
      st[t] = __builtin_amdgcn_mfma_f32_16x16x32_bf16(kf1, qf[1], st[t], 0, 0, 0);
    }
    __builtin_amdgcn_s_setprio(0);

    float p[16];
    float mt = -INFINITY;
    #pragma unroll
    for (int t = 0; t < 4; ++t) {
      const int4 mk = *(const int4*)&msk_s[t * 16 + 4 * g];
      p[4*t+0] = mk.x ? st[t][0] * INV_ : NEG_;
      p[4*t+1] = mk.y ? st[t][1] * INV_ : NEG_;
      p[4*t+2] = mk.z ? st[t][2] * INV_ : NEG_;
      p[4*t+3] = mk.w ? st[t][3] * INV_ : NEG_;
      mt = fmaxf(mt, fmaxf(fmaxf(p[4*t], p[4*t+1]), fmaxf(p[4*t+2], p[4*t+3])));
    }
    mt = fmaxf(mt, __shfl_xor(mt, 16));
    mt = fmaxf(mt, __shfl_xor(mt, 32));
    const float mnew = fmaxf(m, mt);
    const float fac = __expf(m - mnew);
    float ps = 0.f;
    #pragma unroll
    for (int i = 0; i < 16; ++i) { p[i] = __expf(p[i] - mnew); ps += p[i]; }
    ps += __shfl_xor(ps, 16);
    ps += __shfl_xor(ps, 32);
    l = l * fac + ps;
    m = mnew;
    if (lane < 16) fac_s[w * 16 + lane] = fac;

    bf16_t* prow = Pl + w * 1024 + lq * 64;
    #pragma unroll
    for (int t = 0; t < 4; ++t) {
      bf16x4_t pb = {(bf16_t)p[4*t], (bf16_t)p[4*t+1],
                     (bf16_t)p[4*t+2], (bf16_t)p[4*t+3]};
      *(bf16x4_t*)(prow + 8 * ((2*t + (g >> 1)) ^ (lq & 7)) + 4 * (g & 1)) = pb;
    }
    bf16x8_t pa0 = *(const bf16x8_t*)(prow + 8 * ((g)     ^ (lq & 7)));
    bf16x8_t pa1 = *(const bf16x8_t*)(prow + 8 * ((4 + g) ^ (lq & 7)));

    const float4 fc = *(const float4*)&fac_s[w * 16 + 4 * g];
    __builtin_amdgcn_s_setprio(1);
    #pragma unroll
    for (int db = 0; db < 4; ++db) {
      const int dr = db * 16 + lq;
      const bf16_t* vrow = Vs + dr * 64;
      bf16x8_t vf0 = *(const bf16x8_t*)(vrow + 8 * ((g)     ^ (dr & 7)));
      bf16x8_t vf1 = *(const bf16x8_t*)(vrow + 8 * ((4 + g) ^ (dr & 7)));
      o[db][0] *= fc.x; o[db][1] *= fc.y; o[db][2] *= fc.z; o[db][3] *= fc.w;
      o[db] = __builtin_amdgcn_mfma_f32_16x16x32_bf16(pa0, vf0, o[db], 0, 0, 0);
      o[db] = __builtin_amdgcn_mfma_f32_16x16x32_bf16(pa1, vf1, o[db], 0, 0, 0);
    }
    __builtin_amdgcn_s_setprio(0);
    __syncthreads();
  }

  if (lane < 16) l_s[w * 16 + lane] = l;
  const float4 lv = *(const float4*)&l_s[w * 16 + 4 * g];
  const float rl0 = 1.f / lv.x, rl1 = 1.f / lv.y;
  const float rl2 = 1.f / lv.z, rl3 = 1.f / lv.w;
  const int qr0 = qt0 + w * 16 + 4 * g;
  #pragma unroll
  for (int db = 0; db < 4; ++db) {
    const int col = h * D_ + db * 16 + lq;
    bf16_t* yp = yout + ((size_t)(b * TM1) + qr0) * C_ + col;
    if (qr0 + 0 < TM1) yp[0 * (size_t)C_] = (bf16_t)(o[db][0] * rl0);
    if (qr0 + 1 < TM1) yp[1 * (size_t)C_] = (bf16_t)(o[db][1] * rl1);
    if (qr0 + 2 < TM1) yp[2 * (size_t)C_] = (bf16_t)(o[db][2] * rl2);
    if (qr0 + 3 < TM1) yp[3 * (size_t)C_] = (bf16_t)(o[db][3] * rl3);
  }
}

__device__ void cls_body(
    const bf16_t* __restrict__ QKVc, const float* __restrict__ t1,
    const int* __restrict__ mask, float* __restrict__ yout,
    char* pool, int cbid)
{
  float* Vs   = (float*)pool;              // [64][65]
  float* Ps   = (float*)(pool + 16640);
  float* qp_s = (float*)(pool + 16960);

  const int b = cbid / H_, h = cbid % H_;
  const int tid = threadIdx.x;
  const int lane = tid & 63;

  if (tid < 16)
    qp_s[tid] = (float)QKVc[(size_t)(b * T_) * LDQ + QPOFF + h * 16 + tid];
  __syncthreads();

  float m = -INFINITY, l = 0.f, acc = 0.f, mnew = 0.f;
  for (int kt = 0; kt < T_; kt += 64) {
    for (int rr = tid >> 6; rr < 64; rr += 4)
      Vs[rr * 65 + lane] =
          (float)QKVc[((size_t)(b * T_) + kt + rr) * LDQ + 1536 + h * D_ + lane];
    __syncthreads();
    if (tid < 64) {
      const float* t1r = t1 + ((size_t)(b * T_) + kt + tid) * R_;
      float sc = qp_s[8];
      #pragma unroll
      for (int r = 0; r < 8; ++r) sc += qp_s[r] * t1r[r];
      sc *= INV_;
      if (!mask[b * T_ + kt + tid]) sc = NEG_;
      float mt = sc;
      #pragma unroll
      for (int off = 32; off > 0; off >>= 1) mt = fmaxf(mt, __shfl_xor(mt, off));
      mnew = fmaxf(m, mt);
      float e = __expf(sc - mnew);
      float ssum = e;
      #pragma unroll
      for (int off = 32; off > 0; off >>= 1) ssum += __shfl_xor(ssum, off);
      float fac = __expf(m - mnew);
      acc *= fac;
      l = l * fac + ssum;
      Ps[tid] = e;
    }
    __syncthreads();
    if (tid < 64) {
      #pragma unroll
      for (int j = 0; j < 64; ++j) acc += Ps[j] * Vs[j * 65 + tid];
      m = mnew;
    }
    __syncthreads();
  }
  if (tid < 64) yout[(size_t)b * C_ + h * D_ + tid] = acc / l;
}

__global__ __launch_bounds__(256) void attn_cls(
    const bf16_t* __restrict__ QKVc, const bf16_t* __restrict__ Vtg,
    const int* __restrict__ mask, bf16_t* __restrict__ yout,
    const float* __restrict__ t1, float* __restrict__ ych)
{
  __shared__ __align__(16) char pool[25344];
  const int bid = blockIdx.x;
  if (bid < 768) attn_body(QKVc, Vtg, mask, yout, pool, bid);
  else           cls_body(QKVc, t1, mask, ych, pool, bid - 768);
}

// ---------------------------------------------------------------------------
// NEIGH + gemv_cls fused dispatch.
// ---------------------------------------------------------------------------
__global__ __launch_bounds__(256) void neigh_clsp(
    const bf16_t* __restrict__ QKVc, const float* __restrict__ t1,
    const bf16_t* __restrict__ vqn, const float* __restrict__ t2,
    const bf16_t* __restrict__ ysh, int b0, bf16_t* __restrict__ outn,
    int nNeigh, const float* __restrict__ ych, const float* __restrict__ Wp,
    const float* __restrict__ bp, float* __restrict__ ycp)
{
  __shared__ float vs[KC5 * C_];
  __shared__ float qp_s[KC5][200];
  __shared__ float t2_s[KC5][8];
  __shared__ float Ps[H_ * 25];
  __shared__ float as_[C_];

  const int tid = threadIdx.x;
  int bid = blockIdx.x;
  if (bid >= nNeigh) {
    // gemv_cls: 24 blocks
    const int cbid = bid - nNeigh;
    const int row = cbid / 3;
    const int c = (cbid % 3) * 256 + tid;
    for (int i = tid; i < C_; i += 256) as_[i] = ych[(size_t)row * C_ + i];
    __syncthreads();
    float acc = bp[c];
    for (int k = 0; k < C_; ++k) acc += as_[k] * Wp[(size_t)k * C_ + c];
    ycp[(size_t)row * C_ + c] = acc;
    return;
  }

  const int bt = bid;
  const int bb = bt / TM1, t = bt % TM1;
  const int b = b0 + bb;
  const size_t tok = (size_t)(b * T_) + t + 1;
  const size_t nrow = ((size_t)(bb * TM1) + t) * KN_;

  for (int idx = tid; idx < KC5 * 96; idx += 256) {
    int i = idx / 96, d8 = (idx % 96) * 8;
    const bf16_t* vp = (i == 0) ? QKVc + tok * LDQ + 1536 + d8
                                : vqn + (nrow + i - 1) * 1024 + d8;
    bf16x8_t vv = *(const bf16x8_t*)vp;
    #pragma unroll
    for (int j = 0; j < 8; ++j) vs[i * C_ + d8 + j] = (float)vv[j];
  }
  for (int idx = tid; idx < KC5 * 24; idx += 256) {
    int i = idx / 24, c8 = (idx % 24) * 8;
    const bf16_t* qpp = (i == 0) ? QKVc + tok * LDQ + QPOFF + c8
                                 : vqn + (nrow + i - 1) * 1024 + 768 + c8;
    bf16x8_t qv = *(const bf16x8_t*)qpp;
    #pragma unroll
    for (int j = 0; j < 8; ++j) qp_s[i][c8 + j] = (float)qv[j];
  }
  if (tid < KC5 * 8) {
    int i = tid / 8, r = tid & 7;
    t2_s[i][r] = (i == 0) ? t1[tok * R_ + r] : t2[(nrow + i - 1) * R_ + r];
  }
  __syncthreads();

  if (tid < H_ * KC5) {
    int h = tid / KC5, i = tid % KC5;
    float sc[KC5];
    #pragma unroll
    for (int j = 0; j < KC5; ++j) {
      float s = qp_s[i][h * 16 + 8];
      #pragma unroll
      for (int r = 0; r < 8; ++r) s += qp_s[i][h * 16 + r] * t2_s[j][r];
      sc[j] = s * INV_;
    }
    float mt = sc[0];
    #pragma unroll
    for (int j = 1; j < KC5; ++j) mt = fmaxf(mt, sc[j]);
    float e[KC5], ssum = 0.f;
    #pragma unroll
    for (int j = 0; j < KC5; ++j) { e[j] = __expf(sc[j] - mt); ssum += e[j]; }
    float rs = 1.f / ssum;
    #pragma unroll
    for (int j = 0; j < KC5; ++j) Ps[h * 25 + i * KC5 + j] = e[j] * rs;
  }
  __syncthreads();

  const bf16_t* ysrow = ysh + ((size_t)(b * TM1) + t) * C_;
  for (int idx = tid; idx < KC5 * C_; idx += 256) {
    int i = idx / C_, c = idx % C_;
    int h = c / D_;
    float sum = 0.f;
    #pragma unroll
    for (int j = 0; j < KC5; ++j)
      sum += Ps[h * 25 + i * KC5 + j] * vs[j * C_ + c];
    if (i == 0) sum = SCALE_ * sum + (1.f - SCALE_) * (float)ysrow[c];
    outn[(((size_t)(bb * TM1) + t) * KC5 + i) * C_ + c] = (bf16_t)sum;
  }
}

// ---------------------------------------------------------------------------
// COMBINE: main + neigh + cls residual-LN in one dispatch.
// ---------------------------------------------------------------------------
__device__ __forceinline__ void block_reduce2(float& s, float& ss, float* red) {
  #pragma unroll
  for (int off = 32; off > 0; off >>= 1) {
    s += __shfl_down(s, off);
    ss += __shfl_down(ss, off);
  }
  int wid = threadIdx.x >> 6;
  if ((threadIdx.x & 63) == 0) { red[wid * 2] = s; red[wid * 2 + 1] = ss; }
  __syncthreads();
  s  = red[0] + red[2] + red[4] + red[6];
  ss = red[1] + red[3] + red[5] + red[7];
}

__device__ __forceinline__ void ln_row(const float vals[3], float s, float ss,
                                       const float* __restrict__ g,
                                       const float* __restrict__ bb,
                                       float* __restrict__ orow, float* red) {
  block_reduce2(s, ss, red);
  float mean = s * (1.f / (float)C_);
  float var = ss * (1.f / (float)C_) - mean * mean;
  var = fmaxf(var, 0.f);
  float rs = rsqrtf(var + EPS_);
  #pragma unroll
  for (int ii = 0; ii < 3; ++ii) {
    int c = threadIdx.x + ii * 256;
    orow[c] = (vals[ii] - mean) * rs * g[c] + bb[c];
  }
}

__global__ __launch_bounds__(256) void combine_all(
    const bf16_t* __restrict__ poutnb, const float* __restrict__ x,
    const float* __restrict__ g, const float* __restrict__ bln,
    int b0, float* __restrict__ dout, float* __restrict__ dout1,
    const bf16_t* __restrict__ nrcbf, int nMain,
    const float* __restrict__ ycp, int withCls)
{
  __shared__ float red[8];
  int bid = blockIdx.x;
  float vals[3], s = 0.f, ss = 0.f;
  if (bid < nMain) {
    const int bbb = bid / TM1, t = bid % TM1;
    const int b = b0 + bbb;
    const bf16_t* pn = poutnb + (((size_t)(bbb * TM1) + t) * KC5 + 0) * C_;
    const float* xr = x + ((size_t)(b * T_) + t + 1) * C_;
    float* orow = dout + ((size_t)(b * T_) + t + 1) * C_;
    #pragma unroll
    for (int ii = 0; ii < 3; ++ii) {
      int c = threadIdx.x + ii * 256;
      float v = (float)pn[c] + xr[c];
      vals[ii] = v; s += v; ss += v * v;
    }
    ln_row(vals, s, ss, g, bln, orow, red);
    return;
  }
  bid -= nMain;
  if (bid < nMain * KN_) {
    const int i1 = bid % KN_;
    const int bt = bid / KN_;
    const int bbb = bt / TM1, t = bt % TM1;
    const int b = b0 + bbb;
    const bf16_t* pn = poutnb + ((size_t)bt * KC5 + 1 + i1) * C_;
    const bf16_t* nr = nrcbf + ((size_t)bt * KN_ + i1) * C_;
    float* orow = dout1 + (((size_t)(b * TM1) + t) * KN_ + i1) * C_;
    #pragma unroll
    for (int ii = 0; ii < 3; ++ii) {
      int c = threadIdx.x + ii * 256;
      float v = (float)pn[c] + (float)nr[c];
      vals[ii] = v; s += v; ss += v * v;
    }
    ln_row(vals, s, ss, g, bln, orow, red);
    return;
  }
  bid -= nMain * KN_;
  (void)withCls;
  const int b = bid;
  const float* yc = ycp + (size_t)b * C_;
  const float* xr = x + (size_t)(b * T_) * C_;
  float* orow = dout + (size_t)(b * T_) * C_;
  #pragma unroll
  for (int ii = 0; ii < 3; ++ii) {
    int c = threadIdx.x + ii * 256;
    float v = yc[c] + xr[c];
    vals[ii] = v; s += v; ss += v * v;
  }
  ln_row(vals, s, ss, g, bln, orow, red);
}

// ---------------------------------------------------------------------------
extern "C" void kernel_launch(void* const* d_in, const int* in_sizes, int n_in,
                              void* d_out, int out_size, void* d_ws, size_t ws_size,
                              hipStream_t stream) {
  (void)in_sizes; (void)n_in; (void)out_size;
  const float* x    = (const float*)d_in[0];
  const int*   mask = (const int*)d_in[1];
  const float* nrep = (const float*)d_in[2];
  const float* Wq = (const float*)d_in[3];  const float* bq = (const float*)d_in[4];
  const float* Wk = (const float*)d_in[5];  const float* bk = (const float*)d_in[6];
  const float* Wv = (const float*)d_in[7];  const float* bv = (const float*)d_in[8];
  const float* Wp = (const float*)d_in[9];  const float* bp = (const float*)d_in[10];
  const float* Wd = (const float*)d_in[11]; const float* bd = (const float*)d_in[12];
  const float* Wu = (const float*)d_in[13]; const float* bu = (const float*)d_in[14];
  const float* lng = (const float*)d_in[15];
  const float* lnb = (const float*)d_in[16];
  float* dout = (float*)d_out;
  const size_t OUT1 = (size_t)B_ * T_ * C_;

  char* ws = (char*)d_ws;
  size_t off = 0;
  auto alloc = [&](size_t bytes) -> void* {
    void* p = ws + off; off += (bytes + 255) & ~(size_t)255; return p;
  };
  const size_t NT = (size_t)NT_;
  const size_t NR = (size_t)NRR_;
  const size_t YSROWS = (size_t)B_ * TM1;

  bf16_t* xbf   = (bf16_t*)alloc(NT * C_ * 2);
  bf16_t* nrbf  = (bf16_t*)alloc(NR * C_ * 2);
  bf16_t* Wbig  = (bf16_t*)alloc((size_t)2560 * C_ * 2);
  bf16_t* Wtp   = (bf16_t*)alloc((size_t)C_ * C_ * 2);
  float*  WdT   = (float*)alloc((size_t)R_ * C_ * 4);
  float*  bbig  = (float*)alloc(2560 * 4);
  bf16_t* QKVc  = (bf16_t*)alloc(NT * LDQ * 2);
  bf16_t* Vtg   = (bf16_t*)alloc(NT * C_ * 2);
  float*  t1    = (float*)alloc(NT * R_ * 4);
  bf16_t* ysh   = (bf16_t*)alloc(YSROWS * C_ * 2);
  float*  ych   = (float*)alloc((size_t)B_ * C_ * 4);
  float*  ycp   = (float*)alloc((size_t)B_ * C_ * 4);
  const size_t fixed = off;
  const size_t perb = (size_t)TM1 * KN_ * 1024 * 2
                    + (size_t)TM1 * KN_ * R_ * 4
                    + (size_t)TM1 * KC5 * C_ * 2 * 2 + 5 * 256;
  int nb = 1;
  for (int cand : {8, 4, 2, 1}) {
    if (fixed + perb * (size_t)cand <= ws_size) { nb = cand; break; }
  }
  bf16_t* outn   = (bf16_t*)alloc((size_t)nb * TM1 * KC5 * C_ * 2);
  bf16_t* poutnb = (bf16_t*)alloc((size_t)nb * TM1 * KC5 * C_ * 2);
  bf16_t* vqn  = (bf16_t*)alloc((size_t)nb * TM1 * KN_ * 1024 * 2);
  float*  t2   = (float*)alloc((size_t)nb * TM1 * KN_ * R_ * 4);

  dim3 blk(256);

  // 1. PREP
  prep<<<6178, blk, 0, stream>>>(x, nrep, Wq, Wk, Wv, Wp, Wd, Wu,
                                 bq, bk, bv, bu,
                                 xbf, nrbf, Wbig, Wtp, WdT, bbig);

  GemmDesc dqkv;
  dqkv.A = xbf; dqkv.lda = C_; dqkv.Bt = Wbig; dqkv.bias = bbig;
  dqkv.Cbf = QKVc; dqkv.ldc = LDQ; dqkv.Ctr = Vtg; dqkv.trcol0 = 1536;
  dqkv.mode = 3; dqkv.M = (int)NT; dqkv.K = C_; dqkv.N = 2560;
  dqkv.gx = 20; dqkv.nwg = 640;

  bool first = true;
  for (int b0 = 0; b0 < B_; b0 += nb) {
    const int Mn = nb * TM1 * KN_;
    const int Mo = nb * TM1 * KC5;
    const bf16_t* nrcbf = nrbf + (size_t)b0 * TM1 * KN_ * C_;

    GemmDesc dvqn;
    dvqn.A = nrcbf; dvqn.lda = C_; dvqn.Bt = Wbig + (size_t)1536 * C_;
    dvqn.bias = bbig + 1536; dvqn.Cbf = vqn; dvqn.ldc = 1024;
    dvqn.Ctr = nullptr; dvqn.trcol0 = 0; dvqn.mode = 1;
    dvqn.M = Mn; dvqn.K = C_; dvqn.N = 1024;
    dvqn.gx = 8; dvqn.nwg = 8 * ((Mn + 127) / 128);

    const int n0 = first ? 640 : 0;
    const int M1 = first ? (int)NT : 0;
    const int ng1 = (M1 + 31) / 32;
    const int ng2 = (Mn + 31) / 32;

    // 2. MEGA1: QKV + vqn + gemv8(t1) + gemv8(t2)
    mega1<<<n0 + dvqn.nwg + ng1 + ng2, blk, 0, stream>>>(
        dqkv, n0, dvqn, dvqn.nwg, xbf, nrcbf, WdT, bd, t1, M1, t2, Mn);

    if (first) {
      // 3. ATTN + CLS
      attn_cls<<<768 + 96, blk, 0, stream>>>(QKVc, Vtg, mask, ysh, t1, ych);
    }

    // 4. NEIGH (+ gemv_cls on first chunk)
    neigh_clsp<<<nb * TM1 + (first ? 24 : 0), blk, 0, stream>>>(
        QKVc, t1, vqn, t2, ysh, b0, outn, nb * TM1, ych, Wp, bp, ycp);

    // 5. PROJ
    GemmDesc dproj;
    dproj.A = outn; dproj.lda = C_; dproj.Bt = Wtp; dproj.bias = bp;
    dproj.Cbf = poutnb; dproj.ldc = C_; dproj.Ctr = nullptr; dproj.trcol0 = 0;
    dproj.mode = 1; dproj.M = Mo; dproj.K = C_; dproj.N = C_;
    dproj.gx = 6; dproj.nwg = 6 * ((Mo + 127) / 128);
    gemm_mfma_k<<<dproj.nwg, blk, 0, stream>>>(dproj);

    // 6. COMBINE (main + neigh + cls on first chunk)
    combine_all<<<nb * TM1 * (1 + KN_) + (first ? 8 : 0), blk, 0, stream>>>(
        poutnb, x, lng, lnb, b0, dout, dout + OUT1, nrcbf, nb * TM1,
        ycp, first ? 1 : 0);

    first = false;
  }
}